// Round 1
// baseline (2557.282 us; speedup 1.0000x reference)
//
#include <hip/hip_runtime.h>

#define NNODES 4096
#define NEDGES 65536
#define CH 128

// ---------------- tiled f32 GEMM: C[M,NCOLS] = A[M,K](lda) @ X[K,NCOLS] ----------------
// MODE 0: plain store
// MODE 1: store + ln partials (sum, sumsq) per block
// MODE 2: += w[col]*(U[row,I[col]] + V[row,J[col]]), store + ln partials
// MODE 3: += bias[row], elu, store
// MODE 4: += bias[row], transposed store C[col*Mrows + row]
// MODE 5: resid[row,col] += Hc * val (no C store)
template<int MODE>
__global__ __launch_bounds__(256) void gemm_k(
    const float* __restrict__ A, int lda,
    const float* __restrict__ X,
    float* __restrict__ C,
    int K, int NCOLS,
    double* __restrict__ partials,
    const float* __restrict__ Ug, const float* __restrict__ Vg,
    const float* __restrict__ wg, const int* __restrict__ iIe, const int* __restrict__ jIe,
    const float* __restrict__ bias, float* __restrict__ resid, float Hc, int Mrows)
{
  __shared__ float As[16][65];
  __shared__ float Xs[16][65];
  const int tid = threadIdx.x;
  const int tx = tid & 15, ty = tid >> 4;
  const int n0 = blockIdx.x * 64;
  const int m0 = blockIdx.y * 64;
  float acc[4][4] = {};
  for (int k0 = 0; k0 < K; k0 += 16) {
#pragma unroll
    for (int l = 0; l < 4; ++l) {
      int idx = tid + l * 256;
      int mm = idx & 63, kk = idx >> 6;
      As[kk][mm] = A[(size_t)(m0 + mm) * lda + (k0 + kk)];
      Xs[kk][mm] = X[(size_t)(k0 + kk) * NCOLS + (n0 + mm)];
    }
    __syncthreads();
#pragma unroll
    for (int k = 0; k < 16; ++k) {
      float ra[4], rx[4];
#pragma unroll
      for (int a = 0; a < 4; ++a) ra[a] = As[k][ty + 16 * a];
#pragma unroll
      for (int b = 0; b < 4; ++b) rx[b] = Xs[k][tx + 16 * b];
#pragma unroll
      for (int a = 0; a < 4; ++a)
#pragma unroll
        for (int b = 0; b < 4; ++b) acc[a][b] = fmaf(ra[a], rx[b], acc[a][b]);
    }
    __syncthreads();
  }
  double psum = 0.0, psq = 0.0;
#pragma unroll
  for (int a = 0; a < 4; ++a) {
    const int row = m0 + ty + 16 * a;
#pragma unroll
    for (int b = 0; b < 4; ++b) {
      const int col = n0 + tx + 16 * b;
      float val = acc[a][b];
      if (MODE == 2) {
        val += wg[col] * (Ug[(size_t)row * NNODES + iIe[col]] +
                          Vg[(size_t)row * NNODES + jIe[col]]);
      }
      if (MODE == 3) { val += bias[row]; val = val > 0.f ? val : expm1f(val); }
      if (MODE == 4) { val += bias[row]; }
      if (MODE == 1 || MODE == 2) { psum += (double)val; psq += (double)val * (double)val; }
      if (MODE == 5) {
        resid[(size_t)row * NCOLS + col] += Hc * val;
      } else if (MODE == 4) {
        C[(size_t)col * Mrows + row] = val;
      } else {
        C[(size_t)row * NCOLS + col] = val;
      }
    }
  }
  if (MODE == 1 || MODE == 2) {
    __shared__ double red[256];
    const int pid = blockIdx.y * gridDim.x + blockIdx.x;
    red[tid] = psum; __syncthreads();
    for (int s = 128; s > 0; s >>= 1) { if (tid < s) red[tid] += red[tid + s]; __syncthreads(); }
    if (tid == 0) partials[2 * pid] = red[0];
    __syncthreads();
    red[tid] = psq; __syncthreads();
    for (int s = 128; s > 0; s >>= 1) { if (tid < s) red[tid] += red[tid + s]; __syncthreads(); }
    if (tid == 0) partials[2 * pid + 1] = red[0];
  }
}

// ---------------- D-statistics GEMM: sum/sumsq of relu(s_i+s_j-2*f^T f) over N*N ----------------
__global__ __launch_bounds__(256) void dstat_k(
    const float* __restrict__ f, const float* __restrict__ s,
    double* __restrict__ partials)
{
  __shared__ float As[16][65];
  __shared__ float Xs[16][65];
  const int tid = threadIdx.x;
  const int tx = tid & 15, ty = tid >> 4;
  const int j0 = blockIdx.x * 64;
  const int i0 = blockIdx.y * 64;
  float acc[4][4] = {};
  for (int k0 = 0; k0 < CH; k0 += 16) {
#pragma unroll
    for (int l = 0; l < 4; ++l) {
      int idx = tid + l * 256;
      int mm = idx & 63, kk = idx >> 6;
      As[kk][mm] = f[(size_t)(k0 + kk) * NNODES + (i0 + mm)];
      Xs[kk][mm] = f[(size_t)(k0 + kk) * NNODES + (j0 + mm)];
    }
    __syncthreads();
#pragma unroll
    for (int k = 0; k < 16; ++k) {
      float ra[4], rx[4];
#pragma unroll
      for (int a = 0; a < 4; ++a) ra[a] = As[k][ty + 16 * a];
#pragma unroll
      for (int b = 0; b < 4; ++b) rx[b] = Xs[k][tx + 16 * b];
#pragma unroll
      for (int a = 0; a < 4; ++a)
#pragma unroll
        for (int b = 0; b < 4; ++b) acc[a][b] = fmaf(ra[a], rx[b], acc[a][b]);
    }
    __syncthreads();
  }
  double psum = 0.0, psq = 0.0;
#pragma unroll
  for (int a = 0; a < 4; ++a) {
    float si = s[i0 + ty + 16 * a];
#pragma unroll
    for (int b = 0; b < 4; ++b) {
      float d = si + s[j0 + tx + 16 * b] - 2.f * acc[a][b];
      d = d > 0.f ? d : 0.f;
      psum += (double)d; psq += (double)d * (double)d;
    }
  }
  __shared__ double red[256];
  const int pid = blockIdx.y * gridDim.x + blockIdx.x;
  red[tid] = psum; __syncthreads();
  for (int s2 = 128; s2 > 0; s2 >>= 1) { if (tid < s2) red[tid] += red[tid + s2]; __syncthreads(); }
  if (tid == 0) partials[2 * pid] = red[0];
  __syncthreads();
  red[tid] = psq; __syncthreads();
  for (int s2 = 128; s2 > 0; s2 >>= 1) { if (tid < s2) red[tid] += red[tid + s2]; __syncthreads(); }
  if (tid == 0) partials[2 * pid + 1] = red[0];
}

// ---------------- finalize reduction: partials -> params ----------------
// type 0: params = {mean, rstd = 1/sqrt(var_biased + 1e-5)}
// type 1: params = {-2/std_unbiased}
__global__ __launch_bounds__(256) void finalize_k(const double* __restrict__ partials, int nblk,
                                                  float* __restrict__ params, double M, int type)
{
  __shared__ double rs[256], rq[256];
  const int tid = threadIdx.x;
  double s = 0.0, q = 0.0;
  for (int i = tid; i < nblk; i += 256) { s += partials[2 * i]; q += partials[2 * i + 1]; }
  rs[tid] = s; rq[tid] = q; __syncthreads();
  for (int st = 128; st > 0; st >>= 1) {
    if (tid < st) { rs[tid] += rs[tid + st]; rq[tid] += rq[tid + st]; }
    __syncthreads();
  }
  if (tid == 0) {
    double S = rs[0], Q = rq[0];
    if (type == 0) {
      double mean = S / M;
      double var = Q / M - mean * mean;
      if (var < 0.0) var = 0.0;
      params[0] = (float)mean;
      params[1] = (float)(1.0 / sqrt(var + 1e-5));
    } else {
      double var = (Q - S * S / M) / (M - 1.0);
      if (var < 1e-30) var = 1e-30;
      params[0] = (float)(-2.0 / sqrt(var));
    }
  }
}

// ---------------- per-node squared norm ----------------
__global__ void node_s_k(const float* __restrict__ xn, float* __restrict__ s)
{
  int n = blockIdx.x * 256 + threadIdx.x;
  float acc = 0.f;
  for (int c = 0; c < CH; ++c) { float v = xn[(size_t)c * NNODES + n]; acc = fmaf(v, v, acc); }
  s[n] = acc;
}

// ---------------- per-edge weight w = exp(factor * relu(s_I + s_J - 2<f_I,f_J>)) ----------------
__global__ void edge_w_k(const float* __restrict__ xn, const float* __restrict__ s,
                         const int* __restrict__ iI, const int* __restrict__ jJ,
                         const float* __restrict__ params, float* __restrict__ w)
{
  int e = blockIdx.x * 256 + threadIdx.x;
  int a = iI[e], b = jJ[e];
  float g = 0.f;
  for (int c = 0; c < CH; ++c)
    g = fmaf(xn[(size_t)c * NNODES + a], xn[(size_t)c * NNODES + b], g);
  float d = s[a] + s[b] - 2.f * g;
  d = d > 0.f ? d : 0.f;
  w[e] = expf(params[0] * d);
}

// ---------------- build A1/A2 = 0.5*KE1[:, :128] +/- KE1[:, 256:384] ----------------
__global__ void prep_k(const float* __restrict__ KE1i, float* __restrict__ a1a2)
{
  int id = blockIdx.x * 256 + threadIdx.x;   // 0..32767
  int r = id >> 7, c = id & 127;
  int o = r & 127;
  float k1 = KE1i[o * 384 + c], k3 = KE1i[o * 384 + 256 + c];
  a1a2[id] = (r < 128) ? (0.5f * k1 + k3) : (0.5f * k1 - k3);
}

// ---------------- elementwise: x = tanh((x - mean) * rstd) ----------------
__global__ void tanh_ln_k(float* __restrict__ x, const float* __restrict__ p)
{
  size_t i = (size_t)blockIdx.x * 256 + threadIdx.x;
  x[i] = tanhf((x[i] - p[0]) * p[1]);
}

// ---------------- elementwise: xe += 0.1 * ((dx - mean) * rstd) ----------------
__global__ void lnres_k(float* __restrict__ xe, const float* __restrict__ dx,
                        const float* __restrict__ p)
{
  size_t i = (size_t)blockIdx.x * 256 + threadIdx.x;
  xe[i] += 0.1f * ((dx[i] - p[0]) * p[1]);
}

// ---------------- scatter: aveE / divE into cat[0:256,:] via LDS accumulators ----------------
__global__ __launch_bounds__(256) void scatter_k(
    const float* __restrict__ xe, const float* __restrict__ w,
    const int* __restrict__ iI, const int* __restrict__ jJ,
    float* __restrict__ cat)
{
  __shared__ float ave[NNODES];
  __shared__ float dv[NNODES];
  const int c = blockIdx.x;          // channel 0..127
  const int half = blockIdx.y;       // 0..1
  for (int t = threadIdx.x; t < NNODES; t += 256) { ave[t] = 0.f; dv[t] = 0.f; }
  __syncthreads();
  const int e0 = half * (NEDGES / 2);
  const float* xer = xe + (size_t)c * NEDGES;
  for (int t = threadIdx.x; t < NEDGES / 2; t += 256) {
    int e = e0 + t;
    float wgv = w[e] * xer[e];
    int a = iI[e], b = jJ[e];
    atomicAdd(&ave[a], 0.5f * wgv);
    atomicAdd(&ave[b], 0.5f * wgv);
    atomicAdd(&dv[a], wgv);
    atomicAdd(&dv[b], -wgv);
  }
  __syncthreads();
  float* cav = cat + (size_t)c * NNODES;
  float* cdv = cat + (size_t)(CH + c) * NNODES;
  for (int t = threadIdx.x; t < NNODES; t += 256) {
    atomicAdd(&cav[t], ave[t]);
    atomicAdd(&cdv[t], dv[t]);
  }
}

// ---------------- in-place log_softmax over rows of [NNODES, 1024] ----------------
__global__ __launch_bounds__(256) void logsoftmax_k(float* __restrict__ out)
{
  __shared__ float red[256];
  const int n = blockIdx.x, tid = threadIdx.x;
  float* row = out + (size_t)n * 1024;
  float v[4];
  float mx = -1e30f;
#pragma unroll
  for (int l = 0; l < 4; ++l) { v[l] = row[tid + 256 * l]; mx = fmaxf(mx, v[l]); }
  red[tid] = mx; __syncthreads();
  for (int s = 128; s > 0; s >>= 1) { if (tid < s) red[tid] = fmaxf(red[tid], red[tid + s]); __syncthreads(); }
  float m = red[0]; __syncthreads();
  float se = 0.f;
#pragma unroll
  for (int l = 0; l < 4; ++l) se += expf(v[l] - m);
  red[tid] = se; __syncthreads();
  for (int s = 128; s > 0; s >>= 1) { if (tid < s) red[tid] += red[tid + s]; __syncthreads(); }
  float L = m + logf(red[0]);
#pragma unroll
  for (int l = 0; l < 4; ++l) row[tid + 256 * l] = v[l] - L;
}

extern "C" void kernel_launch(void* const* d_in, const int* in_sizes, int n_in,
                              void* d_out, int out_size, void* d_ws, size_t ws_size,
                              hipStream_t stream)
{
  (void)in_sizes; (void)n_in; (void)out_size; (void)ws_size;
  const float* xn_in = (const float*)d_in[0];
  const float* xe_in = (const float*)d_in[1];
  const int*   iI    = (const int*)d_in[2];
  const int*   jJ    = (const int*)d_in[3];
  const float* K1N   = (const float*)d_in[4];
  const float* K2N   = (const float*)d_in[5];
  const float* K1E   = (const float*)d_in[6];
  const float* K2E   = (const float*)d_in[7];
  const float* KNc   = (const float*)d_in[8];
  const float* KE1   = (const float*)d_in[9];
  const float* KE2   = (const float*)d_in[10];
  const float* KN1   = (const float*)d_in[11];
  const float* KN2   = (const float*)d_in[12];
  const float* W1    = (const float*)d_in[13];
  const float* b1    = (const float*)d_in[14];
  const float* W2    = (const float*)d_in[15];
  const float* b2    = (const float*)d_in[16];
  float* out = (float*)d_out;

  float* ws = (float*)d_ws;
  size_t off = 0;
  auto alloc = [&](size_t n) { size_t o = off; off += (n + 63) & ~(size_t)63; return o; };
  float* xn   = ws + alloc((size_t)CH * NNODES);
  float* xe   = ws + alloc((size_t)CH * NEDGES);
  float* nA   = ws + alloc((size_t)CH * NNODES);
  float* nB   = ws + alloc((size_t)CH * NNODES);
  float* eA   = ws + alloc((size_t)CH * NEDGES);
  float* eB   = ws + alloc((size_t)CH * NEDGES);
  float* sbuf = ws + alloc(NNODES);
  float* wbuf = ws + alloc(NEDGES);
  float* uv   = ws + alloc((size_t)256 * NNODES);
  float* a1a2 = ws + alloc((size_t)256 * 128);
  float* cat  = ws + alloc((size_t)384 * NNODES);
  float* l1b  = ws + alloc((size_t)256 * NNODES);
  double* partials = (double*)(ws + alloc((size_t)4096 * 2 * 2));
  float* params = ws + alloc(64);

  const float* NUL = nullptr;
  const int* NULI = nullptr;
  const float Hc = 0.1f;

  // ---- opening: node double layer ----
  gemm_k<1><<<dim3(NNODES / 64, 2), 256, 0, stream>>>(K1N, 64, xn_in, nA, 64, NNODES,
      partials, NUL, NUL, NUL, NULI, NULI, NUL, nullptr, 0.f, CH);
  finalize_k<<<1, 256, 0, stream>>>(partials, (NNODES / 64) * 2, params, (double)CH * NNODES, 0);
  tanh_ln_k<<<(CH * NNODES) / 256, 256, 0, stream>>>(nA, params);
  gemm_k<0><<<dim3(NNODES / 64, 2), 256, 0, stream>>>(K2N, 128, nA, xn, 128, NNODES,
      nullptr, NUL, NUL, NUL, NULI, NULI, NUL, nullptr, 0.f, CH);

  // ---- opening: edge double layer ----
  gemm_k<1><<<dim3(NEDGES / 64, 2), 256, 0, stream>>>(K1E, 64, xe_in, eA, 64, NEDGES,
      partials, NUL, NUL, NUL, NULI, NULI, NUL, nullptr, 0.f, CH);
  finalize_k<<<1, 256, 0, stream>>>(partials, (NEDGES / 64) * 2, params, (double)CH * NEDGES, 0);
  tanh_ln_k<<<(CH * NEDGES) / 256, 256, 0, stream>>>(eA, params);
  gemm_k<0><<<dim3(NEDGES / 64, 2), 256, 0, stream>>>(K2E, 128, eA, xe, 128, NEDGES,
      nullptr, NUL, NUL, NUL, NULI, NULI, NUL, nullptr, 0.f, CH);

  for (int i = 0; i < 4; ++i) {
    const float* KE1i = KE1 + (size_t)i * 128 * 384;
    const float* KE2i = KE2 + (size_t)i * 128 * 128;
    const float* KN1i = KN1 + (size_t)i * 128 * 384;
    const float* KN2i = KN2 + (size_t)i * 128 * 128;

    // D statistics -> factor = -2/std
    node_s_k<<<NNODES / 256, 256, 0, stream>>>(xn, sbuf);
    dstat_k<<<dim3(64, 64), 256, 0, stream>>>(xn, sbuf, partials);
    finalize_k<<<1, 256, 0, stream>>>(partials, 4096, params, (double)NNODES * (double)NNODES, 1);
    edge_w_k<<<NEDGES / 256, 256, 0, stream>>>(xn, sbuf, iI, jJ, params, wbuf);

    // edge update: hid = w*(U[I]+V[J]) + B@xe ; tanh(ln) ; KE2@hid ; xe += H*ln(.)
    prep_k<<<128, 256, 0, stream>>>(KE1i, a1a2);
    gemm_k<0><<<dim3(NNODES / 64, 4), 256, 0, stream>>>(a1a2, 128, xn, uv, 128, NNODES,
        nullptr, NUL, NUL, NUL, NULI, NULI, NUL, nullptr, 0.f, 256);
    gemm_k<2><<<dim3(NEDGES / 64, 2), 256, 0, stream>>>(KE1i + 128, 384, xe, eA, 128, NEDGES,
        partials, uv, uv + (size_t)128 * NNODES, wbuf, iI, jJ, NUL, nullptr, 0.f, CH);
    finalize_k<<<1, 256, 0, stream>>>(partials, (NEDGES / 64) * 2, params, (double)CH * NEDGES, 0);
    tanh_ln_k<<<(CH * NEDGES) / 256, 256, 0, stream>>>(eA, params);
    gemm_k<1><<<dim3(NEDGES / 64, 2), 256, 0, stream>>>(KE2i, 128, eA, eB, 128, NEDGES,
        partials, NUL, NUL, NUL, NULI, NULI, NUL, nullptr, 0.f, CH);
    finalize_k<<<1, 256, 0, stream>>>(partials, (NEDGES / 64) * 2, params, (double)CH * NEDGES, 0);
    lnres_k<<<(CH * NEDGES) / 256, 256, 0, stream>>>(xe, eB, params);

    // node update: cat = [aveE; divE; xn]; KN1@cat -> tanh(ln) -> xn += H*(KN2@hid)
    hipMemsetAsync(cat, 0, (size_t)256 * NNODES * sizeof(float), stream);
    scatter_k<<<dim3(128, 2), 256, 0, stream>>>(xe, wbuf, iI, jJ, cat);
    hipMemcpyAsync(cat + (size_t)256 * NNODES, xn, (size_t)CH * NNODES * sizeof(float),
                   hipMemcpyDeviceToDevice, stream);
    gemm_k<1><<<dim3(NNODES / 64, 2), 256, 0, stream>>>(KN1i, 384, cat, nA, 384, NNODES,
        partials, NUL, NUL, NUL, NULI, NULI, NUL, nullptr, 0.f, CH);
    finalize_k<<<1, 256, 0, stream>>>(partials, (NNODES / 64) * 2, params, (double)CH * NNODES, 0);
    tanh_ln_k<<<(CH * NNODES) / 256, 256, 0, stream>>>(nA, params);
    gemm_k<5><<<dim3(NNODES / 64, 2), 256, 0, stream>>>(KN2i, 128, nA, nB, 128, NNODES,
        nullptr, NUL, NUL, NUL, NULI, NULI, NUL, xn, Hc, CH);
  }

  // ---- close + MLP head ----
  gemm_k<0><<<dim3(NNODES / 64, 2), 256, 0, stream>>>(KNc, 128, xn, nB, 128, NNODES,
      nullptr, NUL, NUL, NUL, NULI, NULI, NUL, nullptr, 0.f, CH);
  gemm_k<3><<<dim3(NNODES / 64, 4), 256, 0, stream>>>(W1, 128, nB, l1b, 128, NNODES,
      nullptr, NUL, NUL, NUL, NULI, NULI, b1, nullptr, 0.f, 256);
  gemm_k<4><<<dim3(NNODES / 64, 16), 256, 0, stream>>>(W2, 256, l1b, out, 256, NNODES,
      nullptr, NUL, NUL, NUL, NULI, NULI, b2, nullptr, 0.f, 1024);
  logsoftmax_k<<<NNODES, 256, 0, stream>>>(out);
}

// Round 2
// 1621.361 us; speedup vs baseline: 1.5772x; 1.5772x over previous
//
#include <hip/hip_runtime.h>

#define NNODES 4096
#define NEDGES 65536
#define CH 128

// ---------------- tiled f32 GEMM: C[M,NCOLS] = A[M,K](lda) @ X[K,NCOLS] ----------------
// MODE 0: plain store
// MODE 1: store + ln partials (sum, sumsq) per block
// MODE 2: += w[col]*(U[row,I[col]] + V[row,J[col]]), store + ln partials
// MODE 3: += bias[row], elu, store
// MODE 4: += bias[row], transposed store C[col*Mrows + row]
// MODE 5: resid[row,col] += Hc * val (no C store)
// XT: transform X on load: x = tanh((x - xprm[0]) * xprm[1])
template<int MODE, bool XT>
__global__ __launch_bounds__(256) void gemm_k(
    const float* __restrict__ A, int lda,
    const float* __restrict__ X,
    float* __restrict__ C,
    int K, int NCOLS,
    double* __restrict__ partials,
    const float* __restrict__ Ug, const float* __restrict__ Vg,
    const float* __restrict__ wg, const int* __restrict__ iIe, const int* __restrict__ jIe,
    const float* __restrict__ bias, float* __restrict__ resid, float Hc, int Mrows,
    const float* __restrict__ xprm)
{
  __shared__ float As[16][64];
  __shared__ float Xs[16][64];
  const int tid = threadIdx.x;
  const int tx = tid & 15, ty = tid >> 4;
  const int n0 = blockIdx.x * 64;
  const int m0 = blockIdx.y * 64;
  // staging-load indices
  const int lm  = tid & 63;          // A: row within tile
  const int lk4 = (tid >> 6) * 4;    // A: k quad
  const int lxk = tid >> 4;          // X: k row
  const int lxm = (tid & 15) * 4;    // X: col quad
  float p0 = 0.f, p1 = 0.f;
  if constexpr (XT) { p0 = xprm[0]; p1 = xprm[1]; }
  float acc[4][4] = {};
  for (int k0 = 0; k0 < K; k0 += 16) {
    float4 av = *(const float4*)&A[(size_t)(m0 + lm) * lda + (k0 + lk4)];
    float4 xv = *(const float4*)&X[(size_t)(k0 + lxk) * NCOLS + (n0 + lxm)];
    if constexpr (XT) {
      xv.x = tanhf((xv.x - p0) * p1);
      xv.y = tanhf((xv.y - p0) * p1);
      xv.z = tanhf((xv.z - p0) * p1);
      xv.w = tanhf((xv.w - p0) * p1);
    }
    __syncthreads();
    As[lk4 + 0][lm] = av.x;
    As[lk4 + 1][lm] = av.y;
    As[lk4 + 2][lm] = av.z;
    As[lk4 + 3][lm] = av.w;
    *(float4*)&Xs[lxk][lxm] = xv;
    __syncthreads();
#pragma unroll
    for (int k = 0; k < 16; ++k) {
      float4 ra = *(const float4*)&As[k][ty * 4];
      float4 rx = *(const float4*)&Xs[k][tx * 4];
      float rav[4] = {ra.x, ra.y, ra.z, ra.w};
      float rxv[4] = {rx.x, rx.y, rx.z, rx.w};
#pragma unroll
      for (int a = 0; a < 4; ++a)
#pragma unroll
        for (int b = 0; b < 4; ++b) acc[a][b] = fmaf(rav[a], rxv[b], acc[a][b]);
    }
  }
  double psum = 0.0, psq = 0.0;
  if constexpr (MODE == 4) {
#pragma unroll
    for (int b = 0; b < 4; ++b) {
      const int col = n0 + tx * 4 + b;
      float4 v;
      v.x = acc[0][b] + bias[m0 + ty * 4 + 0];
      v.y = acc[1][b] + bias[m0 + ty * 4 + 1];
      v.z = acc[2][b] + bias[m0 + ty * 4 + 2];
      v.w = acc[3][b] + bias[m0 + ty * 4 + 3];
      *(float4*)&C[(size_t)col * Mrows + (m0 + ty * 4)] = v;
    }
  } else {
#pragma unroll
    for (int a = 0; a < 4; ++a) {
      const int row = m0 + ty * 4 + a;
      const int col = n0 + tx * 4;
      float v[4] = {acc[a][0], acc[a][1], acc[a][2], acc[a][3]};
      if constexpr (MODE == 2) {
#pragma unroll
        for (int b = 0; b < 4; ++b)
          v[b] += wg[col + b] * (Ug[(size_t)row * NNODES + iIe[col + b]] +
                                 Vg[(size_t)row * NNODES + jIe[col + b]]);
      }
      if constexpr (MODE == 3) {
        float bb = bias[row];
#pragma unroll
        for (int b = 0; b < 4; ++b) { v[b] += bb; v[b] = v[b] > 0.f ? v[b] : expm1f(v[b]); }
      }
      if constexpr (MODE == 1 || MODE == 2) {
#pragma unroll
        for (int b = 0; b < 4; ++b) { psum += (double)v[b]; psq += (double)v[b] * (double)v[b]; }
      }
      if constexpr (MODE == 5) {
        float4* rp = (float4*)&resid[(size_t)row * NCOLS + col];
        float4 r = *rp;
        r.x += Hc * v[0]; r.y += Hc * v[1]; r.z += Hc * v[2]; r.w += Hc * v[3];
        *rp = r;
      } else {
        float4 sv = {v[0], v[1], v[2], v[3]};
        *(float4*)&C[(size_t)row * NCOLS + col] = sv;
      }
    }
  }
  if constexpr (MODE == 1 || MODE == 2) {
    __shared__ double red[256];
    const int pid = blockIdx.y * gridDim.x + blockIdx.x;
    red[tid] = psum; __syncthreads();
    for (int s = 128; s > 0; s >>= 1) { if (tid < s) red[tid] += red[tid + s]; __syncthreads(); }
    if (tid == 0) partials[2 * pid] = red[0];
    __syncthreads();
    red[tid] = psq; __syncthreads();
    for (int s = 128; s > 0; s >>= 1) { if (tid < s) red[tid] += red[tid + s]; __syncthreads(); }
    if (tid == 0) partials[2 * pid + 1] = red[0];
  }
}

// ---------------- D-statistics: sum/sumsq of relu(s_i+s_j-2*f^T f), upper-triangle only ----------------
__global__ __launch_bounds__(256) void dstat_k(
    const float* __restrict__ f, const float* __restrict__ s,
    double* __restrict__ partials)
{
  const int tid = threadIdx.x;
  const int pid = blockIdx.y * gridDim.x + blockIdx.x;
  const int j0 = blockIdx.x * 64;
  const int i0 = blockIdx.y * 64;
  if (j0 < i0) {           // symmetric: lower triangle skipped
    if (tid == 0) { partials[2 * pid] = 0.0; partials[2 * pid + 1] = 0.0; }
    return;
  }
  const double wgt = (j0 > i0) ? 2.0 : 1.0;
  __shared__ float As[16][64];
  __shared__ float Xs[16][64];
  const int tx = tid & 15, ty = tid >> 4;
  const int lxk = tid >> 4;
  const int lxm = (tid & 15) * 4;
  float acc[4][4] = {};
  for (int k0 = 0; k0 < CH; k0 += 16) {
    float4 av = *(const float4*)&f[(size_t)(k0 + lxk) * NNODES + (i0 + lxm)];
    float4 xv = *(const float4*)&f[(size_t)(k0 + lxk) * NNODES + (j0 + lxm)];
    __syncthreads();
    *(float4*)&As[lxk][lxm] = av;
    *(float4*)&Xs[lxk][lxm] = xv;
    __syncthreads();
#pragma unroll
    for (int k = 0; k < 16; ++k) {
      float4 ra = *(const float4*)&As[k][ty * 4];
      float4 rx = *(const float4*)&Xs[k][tx * 4];
      float rav[4] = {ra.x, ra.y, ra.z, ra.w};
      float rxv[4] = {rx.x, rx.y, rx.z, rx.w};
#pragma unroll
      for (int a = 0; a < 4; ++a)
#pragma unroll
        for (int b = 0; b < 4; ++b) acc[a][b] = fmaf(rav[a], rxv[b], acc[a][b]);
    }
  }
  double psum = 0.0, psq = 0.0;
#pragma unroll
  for (int a = 0; a < 4; ++a) {
    float si = s[i0 + ty * 4 + a];
#pragma unroll
    for (int b = 0; b < 4; ++b) {
      float d = si + s[j0 + tx * 4 + b] - 2.f * acc[a][b];
      d = d > 0.f ? d : 0.f;
      psum += (double)d; psq += (double)d * (double)d;
    }
  }
  psum *= wgt; psq *= wgt;
  __shared__ double red[256];
  red[tid] = psum; __syncthreads();
  for (int s2 = 128; s2 > 0; s2 >>= 1) { if (tid < s2) red[tid] += red[tid + s2]; __syncthreads(); }
  if (tid == 0) partials[2 * pid] = red[0];
  __syncthreads();
  red[tid] = psq; __syncthreads();
  for (int s2 = 128; s2 > 0; s2 >>= 1) { if (tid < s2) red[tid] += red[tid + s2]; __syncthreads(); }
  if (tid == 0) partials[2 * pid + 1] = red[0];
}

// ---------------- finalize reduction: partials -> params ----------------
__global__ __launch_bounds__(256) void finalize_k(const double* __restrict__ partials, int nblk,
                                                  float* __restrict__ params, double M, int type)
{
  __shared__ double rs[256], rq[256];
  const int tid = threadIdx.x;
  double s = 0.0, q = 0.0;
  for (int i = tid; i < nblk; i += 256) { s += partials[2 * i]; q += partials[2 * i + 1]; }
  rs[tid] = s; rq[tid] = q; __syncthreads();
  for (int st = 128; st > 0; st >>= 1) {
    if (tid < st) { rs[tid] += rs[tid + st]; rq[tid] += rq[tid + st]; }
    __syncthreads();
  }
  if (tid == 0) {
    double S = rs[0], Q = rq[0];
    if (type == 0) {
      double mean = S / M;
      double var = Q / M - mean * mean;
      if (var < 0.0) var = 0.0;
      params[0] = (float)mean;
      params[1] = (float)(1.0 / sqrt(var + 1e-5));
    } else {
      double var = (Q - S * S / M) / (M - 1.0);
      if (var < 1e-30) var = 1e-30;
      params[0] = (float)(-2.0 / sqrt(var));
    }
  }
}

// ---------------- per-node squared norm ----------------
__global__ void node_s_k(const float* __restrict__ xn, float* __restrict__ s)
{
  int n = blockIdx.x * 256 + threadIdx.x;
  float acc = 0.f;
  for (int c = 0; c < CH; ++c) { float v = xn[(size_t)c * NNODES + n]; acc = fmaf(v, v, acc); }
  s[n] = acc;
}

// ---------------- transpose xn [CH][N] -> xnT [N][CH] ----------------
__global__ __launch_bounds__(256) void trans_k(const float* __restrict__ xn,
                                               float* __restrict__ xnT)
{
  __shared__ float t[64][129];
  const int n0 = blockIdx.x * 64;
  const int tx = threadIdx.x & 63, tw = threadIdx.x >> 6;
  for (int c = tw; c < CH; c += 4)
    t[tx][c] = xn[(size_t)c * NNODES + n0 + tx];
  __syncthreads();
  for (int it = 0; it < 8; ++it) {
    int idx = threadIdx.x + it * 256;          // 0..2047
    int n = idx >> 5, cq = (idx & 31) * 4;
    float4 v = { t[n][cq], t[n][cq + 1], t[n][cq + 2], t[n][cq + 3] };
    *(float4*)&xnT[(size_t)(n0 + n) * CH + cq] = v;
  }
}

// ---------------- per-edge weight from xnT ----------------
__global__ void edge_w_k(const float* __restrict__ xnT, const float* __restrict__ s,
                         const int* __restrict__ iI, const int* __restrict__ jJ,
                         const float* __restrict__ params, float* __restrict__ w)
{
  int e = blockIdx.x * 256 + threadIdx.x;
  int a = iI[e], b = jJ[e];
  const float4* pa = (const float4*)(xnT + (size_t)a * CH);
  const float4* pb = (const float4*)(xnT + (size_t)b * CH);
  float g = 0.f;
#pragma unroll
  for (int q = 0; q < CH / 4; ++q) {
    float4 u = pa[q], v = pb[q];
    g = fmaf(u.x, v.x, g); g = fmaf(u.y, v.y, g);
    g = fmaf(u.z, v.z, g); g = fmaf(u.w, v.w, g);
  }
  float d = s[a] + s[b] - 2.f * g;
  d = d > 0.f ? d : 0.f;
  w[e] = expf(params[0] * d);
}

// ---------------- build A1/A2 = 0.5*KE1[:, :128] +/- KE1[:, 256:384] ----------------
__global__ void prep_k(const float* __restrict__ KE1i, float* __restrict__ a1a2)
{
  int id = blockIdx.x * 256 + threadIdx.x;   // 0..32767
  int r = id >> 7, c = id & 127;
  int o = r & 127;
  float k1 = KE1i[o * 384 + c], k3 = KE1i[o * 384 + 256 + c];
  a1a2[id] = (r < 128) ? (0.5f * k1 + k3) : (0.5f * k1 - k3);
}

// ---------------- elementwise: xe += 0.1 * ((dx - mean) * rstd), float4 ----------------
__global__ void lnres_k(float* __restrict__ xe, const float* __restrict__ dx,
                        const float* __restrict__ p)
{
  size_t i = (size_t)blockIdx.x * 256 + threadIdx.x;
  float m = p[0], r = p[1];
  float4 d = ((const float4*)dx)[i];
  float4 x = ((float4*)xe)[i];
  x.x += 0.1f * ((d.x - m) * r);
  x.y += 0.1f * ((d.y - m) * r);
  x.z += 0.1f * ((d.z - m) * r);
  x.w += 0.1f * ((d.w - m) * r);
  ((float4*)xe)[i] = x;
}

// ---------------- scatter via s1/s2 decomposition ----------------
// s1[n] = sum_{e: I=n} w*xe,  s2[n] = sum_{e: J=n} w*xe
// ave = 0.5*(s1+s2), div = s1-s2
__global__ __launch_bounds__(1024) void scatter_k(
    const float* __restrict__ xe, const float* __restrict__ w,
    const int* __restrict__ iI, const int* __restrict__ jJ,
    float* __restrict__ cat)
{
  __shared__ float s1[NNODES];
  __shared__ float s2[NNODES];
  const int c = blockIdx.x;          // channel 0..127
  const int half = blockIdx.y;       // 0..1
  for (int t = threadIdx.x; t < NNODES; t += 1024) { s1[t] = 0.f; s2[t] = 0.f; }
  __syncthreads();
  const int e0 = half * (NEDGES / 2);
  const float* xer = xe + (size_t)c * NEDGES;
  for (int t = threadIdx.x; t < NEDGES / 2; t += 1024) {
    int e = e0 + t;
    float wgv = w[e] * xer[e];
    atomicAdd(&s1[iI[e]], wgv);
    atomicAdd(&s2[jJ[e]], wgv);
  }
  __syncthreads();
  float* cav = cat + (size_t)c * NNODES;
  float* cdv = cat + (size_t)(CH + c) * NNODES;
  for (int t = threadIdx.x; t < NNODES; t += 1024) {
    float a = s1[t], b = s2[t];
    atomicAdd(&cav[t], 0.5f * (a + b));
    atomicAdd(&cdv[t], a - b);
  }
}

// ---------------- in-place log_softmax over rows of [NNODES, 1024] ----------------
__global__ __launch_bounds__(256) void logsoftmax_k(float* __restrict__ out)
{
  __shared__ float red[256];
  const int n = blockIdx.x, tid = threadIdx.x;
  float* row = out + (size_t)n * 1024;
  float v[4];
  float mx = -1e30f;
#pragma unroll
  for (int l = 0; l < 4; ++l) { v[l] = row[tid + 256 * l]; mx = fmaxf(mx, v[l]); }
  red[tid] = mx; __syncthreads();
  for (int s = 128; s > 0; s >>= 1) { if (tid < s) red[tid] = fmaxf(red[tid], red[tid + s]); __syncthreads(); }
  float m = red[0]; __syncthreads();
  float se = 0.f;
#pragma unroll
  for (int l = 0; l < 4; ++l) se += expf(v[l] - m);
  red[tid] = se; __syncthreads();
  for (int s = 128; s > 0; s >>= 1) { if (tid < s) red[tid] += red[tid + s]; __syncthreads(); }
  float L = m + logf(red[0]);
#pragma unroll
  for (int l = 0; l < 4; ++l) row[tid + 256 * l] = v[l] - L;
}

extern "C" void kernel_launch(void* const* d_in, const int* in_sizes, int n_in,
                              void* d_out, int out_size, void* d_ws, size_t ws_size,
                              hipStream_t stream)
{
  (void)in_sizes; (void)n_in; (void)out_size; (void)ws_size;
  const float* xn_in = (const float*)d_in[0];
  const float* xe_in = (const float*)d_in[1];
  const int*   iI    = (const int*)d_in[2];
  const int*   jJ    = (const int*)d_in[3];
  const float* K1N   = (const float*)d_in[4];
  const float* K2N   = (const float*)d_in[5];
  const float* K1E   = (const float*)d_in[6];
  const float* K2E   = (const float*)d_in[7];
  const float* KNc   = (const float*)d_in[8];
  const float* KE1   = (const float*)d_in[9];
  const float* KE2   = (const float*)d_in[10];
  const float* KN1   = (const float*)d_in[11];
  const float* KN2   = (const float*)d_in[12];
  const float* W1    = (const float*)d_in[13];
  const float* b1    = (const float*)d_in[14];
  const float* W2    = (const float*)d_in[15];
  const float* b2    = (const float*)d_in[16];
  float* out = (float*)d_out;

  float* ws = (float*)d_ws;
  size_t off = 0;
  auto alloc = [&](size_t n) { size_t o = off; off += (n + 63) & ~(size_t)63; return o; };
  float* xn   = ws + alloc((size_t)CH * NNODES);
  float* xe   = ws + alloc((size_t)CH * NEDGES);
  float* nA   = ws + alloc((size_t)CH * NNODES);
  float* nB   = ws + alloc((size_t)CH * NNODES);
  float* eA   = ws + alloc((size_t)CH * NEDGES);
  float* eB   = ws + alloc((size_t)CH * NEDGES);
  float* sbuf = ws + alloc(NNODES);
  float* wbuf = ws + alloc(NEDGES);
  float* uv   = ws + alloc((size_t)256 * NNODES);
  float* a1a2 = ws + alloc((size_t)256 * 128);
  float* cat  = ws + alloc((size_t)384 * NNODES);
  float* l1b  = ws + alloc((size_t)256 * NNODES);
  float* xnT  = ws + alloc((size_t)NNODES * CH);
  double* partials = (double*)(ws + alloc((size_t)4096 * 2 * 2));
  float* params = ws + alloc(64);

  const float* NUL = nullptr;
  const int* NULI = nullptr;
  const float Hc = 0.1f;

  // ---- opening: node double layer ----
  gemm_k<1, false><<<dim3(NNODES / 64, 2), 256, 0, stream>>>(K1N, 64, xn_in, nA, 64, NNODES,
      partials, NUL, NUL, NUL, NULI, NULI, NUL, nullptr, 0.f, CH, NUL);
  finalize_k<<<1, 256, 0, stream>>>(partials, (NNODES / 64) * 2, params, (double)CH * NNODES, 0);
  gemm_k<0, true><<<dim3(NNODES / 64, 2), 256, 0, stream>>>(K2N, 128, nA, xn, 128, NNODES,
      nullptr, NUL, NUL, NUL, NULI, NULI, NUL, nullptr, 0.f, CH, params);

  // ---- opening: edge double layer ----
  gemm_k<1, false><<<dim3(NEDGES / 64, 2), 256, 0, stream>>>(K1E, 64, xe_in, eA, 64, NEDGES,
      partials, NUL, NUL, NUL, NULI, NULI, NUL, nullptr, 0.f, CH, NUL);
  finalize_k<<<1, 256, 0, stream>>>(partials, (NEDGES / 64) * 2, params, (double)CH * NEDGES, 0);
  gemm_k<0, true><<<dim3(NEDGES / 64, 2), 256, 0, stream>>>(K2E, 128, eA, xe, 128, NEDGES,
      nullptr, NUL, NUL, NUL, NULI, NULI, NUL, nullptr, 0.f, CH, params);

  for (int i = 0; i < 4; ++i) {
    const float* KE1i = KE1 + (size_t)i * 128 * 384;
    const float* KE2i = KE2 + (size_t)i * 128 * 128;
    const float* KN1i = KN1 + (size_t)i * 128 * 384;
    const float* KN2i = KN2 + (size_t)i * 128 * 128;

    // D statistics -> factor = -2/std ; edge weights
    node_s_k<<<NNODES / 256, 256, 0, stream>>>(xn, sbuf);
    trans_k<<<NNODES / 64, 256, 0, stream>>>(xn, xnT);
    dstat_k<<<dim3(64, 64), 256, 0, stream>>>(xn, sbuf, partials);
    finalize_k<<<1, 256, 0, stream>>>(partials, 4096, params, (double)NNODES * (double)NNODES, 1);
    edge_w_k<<<NEDGES / 256, 256, 0, stream>>>(xnT, sbuf, iI, jJ, params, wbuf);

    // edge update: hid = w*(U[I]+V[J]) + B@xe ; tanh(ln) ; KE2@hid ; xe += H*ln(.)
    prep_k<<<128, 256, 0, stream>>>(KE1i, a1a2);
    gemm_k<0, false><<<dim3(NNODES / 64, 4), 256, 0, stream>>>(a1a2, 128, xn, uv, 128, NNODES,
        nullptr, NUL, NUL, NUL, NULI, NULI, NUL, nullptr, 0.f, 256, NUL);
    gemm_k<2, false><<<dim3(NEDGES / 64, 2), 256, 0, stream>>>(KE1i + 128, 384, xe, eA, 128, NEDGES,
        partials, uv, uv + (size_t)128 * NNODES, wbuf, iI, jJ, NUL, nullptr, 0.f, CH, NUL);
    finalize_k<<<1, 256, 0, stream>>>(partials, (NEDGES / 64) * 2, params, (double)CH * NEDGES, 0);
    gemm_k<1, true><<<dim3(NEDGES / 64, 2), 256, 0, stream>>>(KE2i, 128, eA, eB, 128, NEDGES,
        partials, NUL, NUL, NUL, NULI, NULI, NUL, nullptr, 0.f, CH, params);
    finalize_k<<<1, 256, 0, stream>>>(partials, (NEDGES / 64) * 2, params, (double)CH * NEDGES, 0);
    lnres_k<<<(CH * NEDGES) / 1024, 256, 0, stream>>>(xe, eB, params);

    // node update: cat = [aveE; divE; xn]; KN1@cat -> tanh(ln) -> xn += H*(KN2@hid)
    hipMemsetAsync(cat, 0, (size_t)256 * NNODES * sizeof(float), stream);
    scatter_k<<<dim3(128, 2), 1024, 0, stream>>>(xe, wbuf, iI, jJ, cat);
    hipMemcpyAsync(cat + (size_t)256 * NNODES, xn, (size_t)CH * NNODES * sizeof(float),
                   hipMemcpyDeviceToDevice, stream);
    gemm_k<1, false><<<dim3(NNODES / 64, 2), 256, 0, stream>>>(KN1i, 384, cat, nA, 384, NNODES,
        partials, NUL, NUL, NUL, NULI, NULI, NUL, nullptr, 0.f, CH, NUL);
    finalize_k<<<1, 256, 0, stream>>>(partials, (NNODES / 64) * 2, params, (double)CH * NNODES, 0);
    gemm_k<5, true><<<dim3(NNODES / 64, 2), 256, 0, stream>>>(KN2i, 128, nA, nB, 128, NNODES,
        nullptr, NUL, NUL, NUL, NULI, NULI, NUL, xn, Hc, CH, params);
  }

  // ---- close + MLP head ----
  gemm_k<0, false><<<dim3(NNODES / 64, 2), 256, 0, stream>>>(KNc, 128, xn, nB, 128, NNODES,
      nullptr, NUL, NUL, NUL, NULI, NULI, NUL, nullptr, 0.f, CH, NUL);
  gemm_k<3, false><<<dim3(NNODES / 64, 4), 256, 0, stream>>>(W1, 128, nB, l1b, 128, NNODES,
      nullptr, NUL, NUL, NUL, NULI, NULI, b1, nullptr, 0.f, 256, NUL);
  gemm_k<4, false><<<dim3(NNODES / 64, 16), 256, 0, stream>>>(W2, 256, l1b, out, 256, NNODES,
      nullptr, NUL, NUL, NUL, NULI, NULI, b2, nullptr, 0.f, 1024, NUL);
  logsoftmax_k<<<NNODES, 256, 0, stream>>>(out);
}

// Round 3
// 1324.325 us; speedup vs baseline: 1.9310x; 1.2243x over previous
//
#include <hip/hip_runtime.h>

#define NNODES 4096
#define NEDGES 65536
#define CH 128

typedef __bf16 bf16x8_t __attribute__((ext_vector_type(8)));
typedef __bf16 bf16x4_t __attribute__((ext_vector_type(4)));
typedef float f32x4_t __attribute__((ext_vector_type(4)));

// ================= f32 tiled GEMM (node-side, small NCOLS) =================
// MODE 0: plain store            MODE 1: store + ln partials
// MODE 3: += bias, elu, store    MODE 4: += bias, transposed store C[col*Mrows+row]
// MODE 5: resid += Hc * val      MODE 6: transposed store, no bias
// XT: x = tanh((x - xprm[0]) * xprm[1]) on X load
// APREP: A is virtual [256][128] from KE1i: r<128: 0.5*K1[r][c]+K1[r][256+c]; else 0.5*K1-K3
// X2F: K-rows >= 256 come from X2 (KN1 reading xn tail)
template<int MODE, bool XT, bool APREP, bool X2F>
__global__ __launch_bounds__(256) void gemm_k(
    const float* __restrict__ A, int lda,
    const float* __restrict__ X, const float* __restrict__ X2,
    float* __restrict__ C,
    int K, int NCOLS,
    double* __restrict__ partials,
    const float* __restrict__ bias, float* __restrict__ resid, float Hc, int Mrows,
    const float* __restrict__ xprm)
{
  __shared__ float As[16][64];
  __shared__ float Xs[16][64];
  const int tid = threadIdx.x;
  const int tx = tid & 15, ty = tid >> 4;
  const int n0 = blockIdx.x * 64;
  const int m0 = blockIdx.y * 64;
  const int lm  = tid & 63;
  const int lk4 = (tid >> 6) * 4;
  const int lxk = tid >> 4;
  const int lxm = (tid & 15) * 4;
  float p0 = 0.f, p1 = 0.f;
  if constexpr (XT) { p0 = xprm[0]; p1 = xprm[1]; }
  float acc[4][4] = {};
  for (int k0 = 0; k0 < K; k0 += 16) {
    float4 av;
    if constexpr (APREP) {
      int r = m0 + lm; int o = r & 127; float sg = (r < 128) ? 1.f : -1.f;
      float4 k1 = *(const float4*)&A[(size_t)o * 384 + (k0 + lk4)];
      float4 k3 = *(const float4*)&A[(size_t)o * 384 + 256 + (k0 + lk4)];
      av.x = 0.5f * k1.x + sg * k3.x;
      av.y = 0.5f * k1.y + sg * k3.y;
      av.z = 0.5f * k1.z + sg * k3.z;
      av.w = 0.5f * k1.w + sg * k3.w;
    } else {
      av = *(const float4*)&A[(size_t)(m0 + lm) * lda + (k0 + lk4)];
    }
    const int xk = k0 + lxk;
    float4 xv;
    if constexpr (X2F) {
      xv = (xk >= 256) ? *(const float4*)&X2[(size_t)(xk - 256) * NCOLS + (n0 + lxm)]
                       : *(const float4*)&X[(size_t)xk * NCOLS + (n0 + lxm)];
    } else {
      xv = *(const float4*)&X[(size_t)xk * NCOLS + (n0 + lxm)];
    }
    if constexpr (XT) {
      xv.x = tanhf((xv.x - p0) * p1);
      xv.y = tanhf((xv.y - p0) * p1);
      xv.z = tanhf((xv.z - p0) * p1);
      xv.w = tanhf((xv.w - p0) * p1);
    }
    __syncthreads();
    As[lk4 + 0][lm] = av.x;
    As[lk4 + 1][lm] = av.y;
    As[lk4 + 2][lm] = av.z;
    As[lk4 + 3][lm] = av.w;
    *(float4*)&Xs[lxk][lxm] = xv;
    __syncthreads();
#pragma unroll
    for (int k = 0; k < 16; ++k) {
      float4 ra = *(const float4*)&As[k][ty * 4];
      float4 rx = *(const float4*)&Xs[k][tx * 4];
      float rav[4] = {ra.x, ra.y, ra.z, ra.w};
      float rxv[4] = {rx.x, rx.y, rx.z, rx.w};
#pragma unroll
      for (int a = 0; a < 4; ++a)
#pragma unroll
        for (int b = 0; b < 4; ++b) acc[a][b] = fmaf(rav[a], rxv[b], acc[a][b]);
    }
  }
  double psum = 0.0, psq = 0.0;
  if constexpr (MODE == 4 || MODE == 6) {
#pragma unroll
    for (int b = 0; b < 4; ++b) {
      const int col = n0 + tx * 4 + b;
      float4 v;
      float b0 = 0.f, b1v = 0.f, b2v = 0.f, b3 = 0.f;
      if constexpr (MODE == 4) {
        b0 = bias[m0 + ty * 4 + 0]; b1v = bias[m0 + ty * 4 + 1];
        b2v = bias[m0 + ty * 4 + 2]; b3 = bias[m0 + ty * 4 + 3];
      }
      v.x = acc[0][b] + b0; v.y = acc[1][b] + b1v;
      v.z = acc[2][b] + b2v; v.w = acc[3][b] + b3;
      *(float4*)&C[(size_t)col * Mrows + (m0 + ty * 4)] = v;
    }
  } else {
#pragma unroll
    for (int a = 0; a < 4; ++a) {
      const int row = m0 + ty * 4 + a;
      const int col = n0 + tx * 4;
      float v[4] = {acc[a][0], acc[a][1], acc[a][2], acc[a][3]};
      if constexpr (MODE == 3) {
        float bb = bias[row];
#pragma unroll
        for (int b = 0; b < 4; ++b) { v[b] += bb; v[b] = v[b] > 0.f ? v[b] : expm1f(v[b]); }
      }
      if constexpr (MODE == 1) {
#pragma unroll
        for (int b = 0; b < 4; ++b) { psum += (double)v[b]; psq += (double)v[b] * (double)v[b]; }
      }
      if constexpr (MODE == 5) {
        float4* rp = (float4*)&resid[(size_t)row * NCOLS + col];
        float4 r = *rp;
        r.x += Hc * v[0]; r.y += Hc * v[1]; r.z += Hc * v[2]; r.w += Hc * v[3];
        *rp = r;
      } else {
        float4 sv = {v[0], v[1], v[2], v[3]};
        *(float4*)&C[(size_t)row * NCOLS + col] = sv;
      }
    }
  }
  if constexpr (MODE == 1) {
    __shared__ double red[256];
    const int pid = blockIdx.y * gridDim.x + blockIdx.x;
    red[tid] = psum; __syncthreads();
    for (int s = 128; s > 0; s >>= 1) { if (tid < s) red[tid] += red[tid + s]; __syncthreads(); }
    if (tid == 0) partials[2 * pid] = red[0];
    __syncthreads();
    red[tid] = psq; __syncthreads();
    for (int s = 128; s > 0; s >>= 1) { if (tid < s) red[tid] += red[tid + s]; __syncthreads(); }
    if (tid == 0) partials[2 * pid + 1] = red[0];
  }
}

// ================= bf16 MFMA edge GEMM: C[E][128] = X[E][K] @ A[128][K]^T =================
// EM 0: plain, stats           (opening pass A)
// EM 2: + w*(U[I]+V[J]), stats (layer pass 1)
// EM 1: tanh-on-load, stats    (layer pass 2)
// EM 3: tanh-on-load, no stats, dual store bf16 + f32 (opening pass B)
template<int EM, int K>
__global__ __launch_bounds__(256) void emfma_k(
    const __bf16* __restrict__ A, const __bf16* __restrict__ X,
    __bf16* __restrict__ Cb, float* __restrict__ Cf,
    double* __restrict__ partials,
    const float* __restrict__ UV, const float* __restrict__ wg,
    const int* __restrict__ iIe, const int* __restrict__ jIe,
    const float* __restrict__ xprm)
{
  const int tid = threadIdx.x;
  const int wv = tid >> 6, lane = tid & 63;
  const int l15 = lane & 15, ks = lane >> 4;
  const int e = blockIdx.x * 64 + wv * 16 + l15;
  constexpr int KK = K / 32;
  float p0 = 0.f, p1 = 0.f;
  if constexpr (EM == 1 || EM == 3) { p0 = xprm[0]; p1 = xprm[1]; }
  bf16x8_t bq[KK];
  {
    const __bf16* xr = X + (size_t)e * K + ks * 8;
#pragma unroll
    for (int kk = 0; kk < KK; ++kk) {
      bf16x8_t v = *(const bf16x8_t*)(xr + kk * 32);
      if constexpr (EM == 1 || EM == 3) {
#pragma unroll
        for (int j = 0; j < 8; ++j) v[j] = (__bf16)tanhf(((float)v[j] - p0) * p1);
      }
      bq[kk] = v;
    }
  }
  float we = 0.f; int ie = 0, je = 0;
  if constexpr (EM == 2) { we = wg[e]; ie = iIe[e]; je = jIe[e]; }
  double dsum = 0.0, dsq = 0.0;
#pragma unroll
  for (int ob = 0; ob < 8; ++ob) {
    f32x4_t acc = {0.f, 0.f, 0.f, 0.f};
    const __bf16* ar = A + (size_t)(ob * 16 + l15) * K + ks * 8;
#pragma unroll
    for (int kk = 0; kk < KK; ++kk) {
      bf16x8_t a = *(const bf16x8_t*)(ar + kk * 32);
      acc = __builtin_amdgcn_mfma_f32_16x16x32_bf16(a, bq[kk], acc, 0, 0, 0);
    }
    const int ro = ob * 16 + ks * 4;
    float v0 = acc[0], v1 = acc[1], v2 = acc[2], v3 = acc[3];
    if constexpr (EM == 2) {
      float4 u4 = *(const float4*)&UV[(size_t)ie * 256 + ro];
      float4 w4 = *(const float4*)&UV[(size_t)je * 256 + 128 + ro];
      v0 += we * (u4.x + w4.x); v1 += we * (u4.y + w4.y);
      v2 += we * (u4.z + w4.z); v3 += we * (u4.w + w4.w);
    }
    if constexpr (EM != 3) {
      dsum += (double)v0 + (double)v1 + (double)v2 + (double)v3;
      dsq  += (double)v0 * v0 + (double)v1 * v1 + (double)v2 * v2 + (double)v3 * v3;
    }
    bf16x4_t bv;
    bv[0] = (__bf16)v0; bv[1] = (__bf16)v1; bv[2] = (__bf16)v2; bv[3] = (__bf16)v3;
    *(bf16x4_t*)(Cb + (size_t)e * 128 + ro) = bv;
    if constexpr (EM == 3) {
      float4 fv = {v0, v1, v2, v3};
      *(float4*)(Cf + (size_t)e * 128 + ro) = fv;
    }
  }
  if constexpr (EM != 3) {
    __shared__ double red[256];
    red[tid] = dsum; __syncthreads();
    for (int s = 128; s > 0; s >>= 1) { if (tid < s) red[tid] += red[tid + s]; __syncthreads(); }
    if (tid == 0) partials[2 * blockIdx.x] = red[0];
    __syncthreads();
    red[tid] = dsq; __syncthreads();
    for (int s = 128; s > 0; s >>= 1) { if (tid < s) red[tid] += red[tid + s]; __syncthreads(); }
    if (tid == 0) partials[2 * blockIdx.x + 1] = red[0];
  }
}

// ================= dstat via MFMA Gram matrix, upper triangle =================
__global__ __launch_bounds__(256) void dstat_k(
    const __bf16* __restrict__ fT, const float* __restrict__ s,
    double* __restrict__ partials)
{
  const int tid = threadIdx.x;
  const int pid = blockIdx.y * gridDim.x + blockIdx.x;
  const int j0 = blockIdx.x * 64, i0 = blockIdx.y * 64;
  if (j0 < i0) { if (tid < 2) partials[2 * pid + tid] = 0.0; return; }
  const double wgt = (j0 > i0) ? 2.0 : 1.0;
  const int wv = tid >> 6, lane = tid & 63, l15 = lane & 15, ks = lane >> 4;
  const int irow = i0 + wv * 16 + l15;
  bf16x8_t aq[4];
  const __bf16* ar = fT + (size_t)irow * 128 + ks * 8;
#pragma unroll
  for (int kk = 0; kk < 4; ++kk) aq[kk] = *(const bf16x8_t*)(ar + kk * 32);
  float si[4];
#pragma unroll
  for (int r = 0; r < 4; ++r) si[r] = s[i0 + wv * 16 + ks * 4 + r];
  double dsum = 0.0, dsq = 0.0;
#pragma unroll
  for (int jb = 0; jb < 4; ++jb) {
    const int jcol = j0 + jb * 16 + l15;
    const __bf16* br = fT + (size_t)jcol * 128 + ks * 8;
    f32x4_t acc = {0.f, 0.f, 0.f, 0.f};
#pragma unroll
    for (int kk = 0; kk < 4; ++kk) {
      bf16x8_t b = *(const bf16x8_t*)(br + kk * 32);
      acc = __builtin_amdgcn_mfma_f32_16x16x32_bf16(aq[kk], b, acc, 0, 0, 0);
    }
    const float sj = s[jcol];
#pragma unroll
    for (int r = 0; r < 4; ++r) {
      float d = si[r] + sj - 2.f * acc[r];
      d = d > 0.f ? d : 0.f;
      dsum += (double)d; dsq += (double)d * (double)d;
    }
  }
  dsum *= wgt; dsq *= wgt;
  __shared__ double red[256];
  red[tid] = dsum; __syncthreads();
  for (int s2 = 128; s2 > 0; s2 >>= 1) { if (tid < s2) red[tid] += red[tid + s2]; __syncthreads(); }
  if (tid == 0) partials[2 * pid] = red[0];
  __syncthreads();
  red[tid] = dsq; __syncthreads();
  for (int s2 = 128; s2 > 0; s2 >>= 1) { if (tid < s2) red[tid] += red[tid + s2]; __syncthreads(); }
  if (tid == 0) partials[2 * pid + 1] = red[0];
}

// ================= finalize: partials -> params =================
__global__ __launch_bounds__(256) void finalize_k(const double* __restrict__ partials, int nblk,
                                                  float* __restrict__ params, double M, int type)
{
  __shared__ double rs[256], rq[256];
  const int tid = threadIdx.x;
  double s = 0.0, q = 0.0;
  for (int i = tid; i < nblk; i += 256) { s += partials[2 * i]; q += partials[2 * i + 1]; }
  rs[tid] = s; rq[tid] = q; __syncthreads();
  for (int st = 128; st > 0; st >>= 1) {
    if (tid < st) { rs[tid] += rs[tid + st]; rq[tid] += rq[tid + st]; }
    __syncthreads();
  }
  if (tid == 0) {
    double S = rs[0], Q = rq[0];
    if (type == 0) {
      double mean = S / M;
      double var = Q / M - mean * mean;
      if (var < 0.0) var = 0.0;
      params[0] = (float)mean;
      params[1] = (float)(1.0 / sqrt(var + 1e-5));
    } else {
      double var = (Q - S * S / M) / (M - 1.0);
      if (var < 1e-30) var = 1e-30;
      params[0] = (float)(-2.0 / sqrt(var));
    }
  }
}

// ================= transpose xn [128][N] -> xnT f32 [N][128] + bf16 + s =================
__global__ __launch_bounds__(256) void trans_k(const float* __restrict__ xn,
    float* __restrict__ xnT, __bf16* __restrict__ xnTb, float* __restrict__ sbuf)
{
  __shared__ float t[64][129];
  const int n0 = blockIdx.x * 64;
  const int tx = threadIdx.x & 63, tw = threadIdx.x >> 6;
  for (int c = tw; c < CH; c += 4)
    t[tx][c] = xn[(size_t)c * NNODES + n0 + tx];
  __syncthreads();
  for (int it = 0; it < 8; ++it) {
    int idx = threadIdx.x + it * 256;
    int n = idx >> 5, cq = (idx & 31) * 4;
    float4 v = {t[n][cq], t[n][cq + 1], t[n][cq + 2], t[n][cq + 3]};
    *(float4*)&xnT[(size_t)(n0 + n) * CH + cq] = v;
    bf16x4_t b;
    b[0] = (__bf16)v.x; b[1] = (__bf16)v.y; b[2] = (__bf16)v.z; b[3] = (__bf16)v.w;
    *(bf16x4_t*)&xnTb[(size_t)(n0 + n) * CH + cq] = b;
  }
  if (threadIdx.x < 64) {
    float a = 0.f;
    for (int c = 0; c < CH; ++c) { float x = t[threadIdx.x][c]; a = fmaf(x, x, a); }
    sbuf[n0 + threadIdx.x] = a;
  }
}

// ================= transpose xe_in [64][E] f32 -> [E][64] bf16 =================
__global__ __launch_bounds__(256) void etrans_k(const float* __restrict__ xe_in,
                                                __bf16* __restrict__ xeT64)
{
  __shared__ float t[64][65];
  const int e0 = blockIdx.x * 64;
  const int tx = threadIdx.x & 63, tw = threadIdx.x >> 6;
  for (int c = tw; c < 64; c += 4)
    t[tx][c] = xe_in[(size_t)c * NEDGES + e0 + tx];
  __syncthreads();
  const int el = threadIdx.x >> 2, c0 = (threadIdx.x & 3) * 16;
  for (int q = 0; q < 4; ++q) {
    int c = c0 + q * 4;
    bf16x4_t b;
    b[0] = (__bf16)t[el][c];     b[1] = (__bf16)t[el][c + 1];
    b[2] = (__bf16)t[el][c + 2]; b[3] = (__bf16)t[el][c + 3];
    *(bf16x4_t*)&xeT64[(size_t)(e0 + el) * 64 + c] = b;
  }
}

// ================= per-edge weight from xnT f32 =================
__global__ void edge_w_k(const float* __restrict__ xnT, const float* __restrict__ s,
                         const int* __restrict__ iI, const int* __restrict__ jJ,
                         const float* __restrict__ params, float* __restrict__ w)
{
  int e = blockIdx.x * 256 + threadIdx.x;
  int a = iI[e], b = jJ[e];
  const float4* pa = (const float4*)(xnT + (size_t)a * CH);
  const float4* pb = (const float4*)(xnT + (size_t)b * CH);
  float g = 0.f;
#pragma unroll
  for (int q = 0; q < CH / 4; ++q) {
    float4 u = pa[q], v = pb[q];
    g = fmaf(u.x, v.x, g); g = fmaf(u.y, v.y, g);
    g = fmaf(u.z, v.z, g); g = fmaf(u.w, v.w, g);
  }
  float d = s[a] + s[b] - 2.f * g;
  d = d > 0.f ? d : 0.f;
  w[e] = expf(params[0] * d);
}

// ================= weight conversion to bf16 (one launch) =================
__global__ void wcvt_k(const float* __restrict__ K1E, const float* __restrict__ K2E,
                       const float* __restrict__ KE1, const float* __restrict__ KE2,
                       __bf16* __restrict__ K1Eb, __bf16* __restrict__ K2Eb,
                       __bf16* __restrict__ KE1b, __bf16* __restrict__ KE2b)
{
  int id = blockIdx.x * 256 + threadIdx.x;
  if (id < 8192) { K1Eb[id] = (__bf16)K1E[id]; return; }
  id -= 8192;
  if (id < 16384) { K2Eb[id] = (__bf16)K2E[id]; return; }
  id -= 16384;
  if (id < 65536) {
    int l = id >> 14, rem = id & 16383, r = rem >> 7, c = rem & 127;
    KE1b[id] = (__bf16)KE1[(size_t)l * 49152 + r * 384 + 128 + c];
    return;
  }
  id -= 65536;
  if (id < 65536) { KE2b[id] = (__bf16)KE2[id]; return; }
}

// ================= lnres + layout fan-out =================
// xe_new = xe_em + 0.1*((eBT - m)*r); writes xe_em f32, xeT bf16, xe_cm f32 (transposed)
__global__ __launch_bounds__(256) void lnres_k(
    const __bf16* __restrict__ eBT, float* __restrict__ xe_em,
    __bf16* __restrict__ xeT, float* __restrict__ xe_cm,
    const float* __restrict__ p)
{
  __shared__ float st[64 * 129];
  const int e0 = blockIdx.x * 64;
  const int t = threadIdx.x;
  const float m = p[0], r = p[1];
  const int el = t >> 2, c0 = (t & 3) * 32;
  const size_t base = (size_t)(e0 + el) * 128 + c0;
#pragma unroll
  for (int j = 0; j < 8; ++j) {
    bf16x4_t b = *(const bf16x4_t*)(eBT + base + 4 * j);
    float4 x = *(const float4*)(xe_em + base + 4 * j);
    float4 nv;
    nv.x = x.x + 0.1f * (((float)b[0] - m) * r);
    nv.y = x.y + 0.1f * (((float)b[1] - m) * r);
    nv.z = x.z + 0.1f * (((float)b[2] - m) * r);
    nv.w = x.w + 0.1f * (((float)b[3] - m) * r);
    *(float4*)(xe_em + base + 4 * j) = nv;
    bf16x4_t ob;
    ob[0] = (__bf16)nv.x; ob[1] = (__bf16)nv.y; ob[2] = (__bf16)nv.z; ob[3] = (__bf16)nv.w;
    *(bf16x4_t*)(xeT + base + 4 * j) = ob;
    const int cc = c0 + 4 * j;
    st[el * 129 + cc + 0] = nv.x; st[el * 129 + cc + 1] = nv.y;
    st[el * 129 + cc + 2] = nv.z; st[el * 129 + cc + 3] = nv.w;
  }
  __syncthreads();
  const int c = t >> 1, eh = (t & 1) * 32;
#pragma unroll
  for (int j = 0; j < 8; ++j) {
    int ee = eh + 4 * j;
    float4 v = {st[(ee + 0) * 129 + c], st[(ee + 1) * 129 + c],
                st[(ee + 2) * 129 + c], st[(ee + 3) * 129 + c]};
    *(float4*)&xe_cm[(size_t)c * NEDGES + e0 + ee] = v;
  }
}

// ================= scatter via s1/s2 decomposition =================
__global__ __launch_bounds__(1024) void scatter_k(
    const float* __restrict__ xe, const float* __restrict__ w,
    const int* __restrict__ iI, const int* __restrict__ jJ,
    float* __restrict__ cat)
{
  __shared__ float s1[NNODES];
  __shared__ float s2[NNODES];
  const int c = blockIdx.x;
  const int half = blockIdx.y;
  for (int t = threadIdx.x; t < NNODES; t += 1024) { s1[t] = 0.f; s2[t] = 0.f; }
  __syncthreads();
  const int e0 = half * (NEDGES / 2);
  const float* xer = xe + (size_t)c * NEDGES;
  for (int t = threadIdx.x; t < NEDGES / 2; t += 1024) {
    int e = e0 + t;
    float wgv = w[e] * xer[e];
    atomicAdd(&s1[iI[e]], wgv);
    atomicAdd(&s2[jJ[e]], wgv);
  }
  __syncthreads();
  float* cav = cat + (size_t)c * NNODES;
  float* cdv = cat + (size_t)(CH + c) * NNODES;
  for (int t = threadIdx.x; t < NNODES; t += 1024) {
    float a = s1[t], b = s2[t];
    atomicAdd(&cav[t], 0.5f * (a + b));
    atomicAdd(&cdv[t], a - b);
  }
}

// ================= log_softmax rows of [N][1024] =================
__global__ __launch_bounds__(256) void logsoftmax_k(float* __restrict__ out)
{
  __shared__ float red[256];
  const int n = blockIdx.x, tid = threadIdx.x;
  float* row = out + (size_t)n * 1024;
  float v[4];
  float mx = -1e30f;
#pragma unroll
  for (int l = 0; l < 4; ++l) { v[l] = row[tid + 256 * l]; mx = fmaxf(mx, v[l]); }
  red[tid] = mx; __syncthreads();
  for (int s = 128; s > 0; s >>= 1) { if (tid < s) red[tid] = fmaxf(red[tid], red[tid + s]); __syncthreads(); }
  float m = red[0]; __syncthreads();
  float se = 0.f;
#pragma unroll
  for (int l = 0; l < 4; ++l) se += expf(v[l] - m);
  red[tid] = se; __syncthreads();
  for (int s = 128; s > 0; s >>= 1) { if (tid < s) red[tid] += red[tid + s]; __syncthreads(); }
  float L = m + logf(red[0]);
#pragma unroll
  for (int l = 0; l < 4; ++l) row[tid + 256 * l] = v[l] - L;
}

extern "C" void kernel_launch(void* const* d_in, const int* in_sizes, int n_in,
                              void* d_out, int out_size, void* d_ws, size_t ws_size,
                              hipStream_t stream)
{
  (void)in_sizes; (void)n_in; (void)out_size; (void)ws_size;
  const float* xn_in = (const float*)d_in[0];
  const float* xe_in = (const float*)d_in[1];
  const int*   iI    = (const int*)d_in[2];
  const int*   jJ    = (const int*)d_in[3];
  const float* K1N   = (const float*)d_in[4];
  const float* K2N   = (const float*)d_in[5];
  const float* K1E   = (const float*)d_in[6];
  const float* K2E   = (const float*)d_in[7];
  const float* KNc   = (const float*)d_in[8];
  const float* KE1   = (const float*)d_in[9];
  const float* KE2   = (const float*)d_in[10];
  const float* KN1   = (const float*)d_in[11];
  const float* KN2   = (const float*)d_in[12];
  const float* W1    = (const float*)d_in[13];
  const float* b1    = (const float*)d_in[14];
  const float* W2    = (const float*)d_in[15];
  const float* b2    = (const float*)d_in[16];
  float* out = (float*)d_out;

  float* ws = (float*)d_ws;
  size_t off = 0;
  auto alloc = [&](size_t n) { size_t o = off; off += (n + 63) & ~(size_t)63; return o; };
  float* xn    = ws + alloc((size_t)CH * NNODES);
  float* xe_em = ws + alloc((size_t)NEDGES * CH);          // f32 residual, edge-major
  float* xe_cm = ws + alloc((size_t)CH * NEDGES);          // f32 channel-major (scatter)
  __bf16* xeT  = (__bf16*)(ws + alloc((size_t)NEDGES * CH / 2));
  __bf16* eAT  = (__bf16*)(ws + alloc((size_t)NEDGES * CH / 2));
  __bf16* eBT  = (__bf16*)(ws + alloc((size_t)NEDGES * CH / 2));
  float* nA    = ws + alloc((size_t)CH * NNODES);
  float* nB    = ws + alloc((size_t)CH * NNODES);
  float* sbuf  = ws + alloc(NNODES);
  float* wbuf  = ws + alloc(NEDGES);
  float* UV    = ws + alloc((size_t)NNODES * 256);
  float* cat   = ws + alloc((size_t)256 * NNODES);
  float* xnT   = ws + alloc((size_t)NNODES * CH);
  __bf16* xnTb = (__bf16*)(ws + alloc((size_t)NNODES * CH / 2));
  __bf16* K1Eb = (__bf16*)(ws + alloc(8192 / 2));
  __bf16* K2Eb = (__bf16*)(ws + alloc(16384 / 2));
  __bf16* KE1b = (__bf16*)(ws + alloc(65536 / 2));
  __bf16* KE2b = (__bf16*)(ws + alloc(65536 / 2));
  double* partials = (double*)(ws + alloc((size_t)4096 * 2 * 2));
  float* params = ws + alloc(64);
  // aliases (lifetimes disjoint)
  __bf16* xeT64 = (__bf16*)xe_cm;   // opening only; xe_cm first written by layer-0 lnres
  float* l1b = cat;                 // head only; cat last used in layer 3

  const float* NUL = nullptr;
  const int* NULI = nullptr;
  const float Hc = 0.1f;

  // ---- weight conversion ----
  wcvt_k<<<608, 256, 0, stream>>>(K1E, K2E, KE1, KE2, K1Eb, K2Eb, KE1b, KE2b);

  // ---- opening: node double layer (f32) ----
  gemm_k<1, false, false, false><<<dim3(64, 2), 256, 0, stream>>>(K1N, 64, xn_in, NUL, nA, 64, NNODES,
      partials, NUL, nullptr, 0.f, CH, NUL);
  finalize_k<<<1, 256, 0, stream>>>(partials, 128, params, (double)CH * NNODES, 0);
  gemm_k<0, true, false, false><<<dim3(64, 2), 256, 0, stream>>>(K2N, 128, nA, NUL, xn, 128, NNODES,
      nullptr, NUL, nullptr, 0.f, CH, params);

  // ---- opening: edge double layer (MFMA) ----
  etrans_k<<<NEDGES / 64, 256, 0, stream>>>(xe_in, xeT64);
  emfma_k<0, 64><<<NEDGES / 64, 256, 0, stream>>>(K1Eb, xeT64, eAT, nullptr,
      partials, NUL, NUL, NULI, NULI, NUL);
  finalize_k<<<1, 256, 0, stream>>>(partials, 1024, params, (double)CH * NEDGES, 0);
  emfma_k<3, 128><<<NEDGES / 64, 256, 0, stream>>>(K2Eb, eAT, xeT, xe_em,
      nullptr, NUL, NUL, NULI, NULI, params);

  for (int i = 0; i < 4; ++i) {
    const float* KE1i = KE1 + (size_t)i * 128 * 384;
    const float* KN1i = KN1 + (size_t)i * 128 * 384;
    const float* KN2i = KN2 + (size_t)i * 128 * 128;
    const __bf16* KE1bi = KE1b + (size_t)i * 128 * 128;
    const __bf16* KE2bi = KE2b + (size_t)i * 128 * 128;

    // D statistics -> factor = -2/std ; edge weights
    trans_k<<<NNODES / 64, 256, 0, stream>>>(xn, xnT, xnTb, sbuf);
    dstat_k<<<dim3(64, 64), 256, 0, stream>>>(xnTb, sbuf, partials);
    finalize_k<<<1, 256, 0, stream>>>(partials, 4096, params, (double)NNODES * (double)NNODES, 1);
    edge_w_k<<<NEDGES / 256, 256, 0, stream>>>(xnT, sbuf, iI, jJ, params, wbuf);

    // UV = [A1;A2] @ xn stored node-major [n][256]
    gemm_k<6, false, true, false><<<dim3(64, 4), 256, 0, stream>>>(KE1i, 384, xn, NUL, UV, 128, NNODES,
        nullptr, NUL, nullptr, 0.f, 256, NUL);
    // edge pass 1: eA = KE1b @ xe + w*(U_I + V_J), stats
    emfma_k<2, 128><<<NEDGES / 64, 256, 0, stream>>>(KE1bi, xeT, eAT, nullptr,
        partials, UV, wbuf, iI, jJ, NUL);
    finalize_k<<<1, 256, 0, stream>>>(partials, 1024, params, (double)CH * NEDGES, 0);
    // edge pass 2: eB = KE2 @ tanh(ln(eA)), stats
    emfma_k<1, 128><<<NEDGES / 64, 256, 0, stream>>>(KE2bi, eAT, eBT, nullptr,
        partials, NUL, NUL, NULI, NULI, params);
    finalize_k<<<1, 256, 0, stream>>>(partials, 1024, params, (double)CH * NEDGES, 0);
    // xe += 0.1 * ln(eB); fan out layouts
    lnres_k<<<NEDGES / 64, 256, 0, stream>>>(eBT, xe_em, xeT, xe_cm, params);

    // node update
    hipMemsetAsync(cat, 0, (size_t)256 * NNODES * sizeof(float), stream);
    scatter_k<<<dim3(128, 2), 1024, 0, stream>>>(xe_cm, wbuf, iI, jJ, cat);
    gemm_k<1, false, false, true><<<dim3(64, 2), 256, 0, stream>>>(KN1i, 384, cat, xn, nA, 384, NNODES,
        partials, NUL, nullptr, 0.f, CH, NUL);
    finalize_k<<<1, 256, 0, stream>>>(partials, 128, params, (double)CH * NNODES, 0);
    gemm_k<5, true, false, false><<<dim3(64, 2), 256, 0, stream>>>(KN2i, 128, nA, NUL, nB, 128, NNODES,
        nullptr, NUL, xn, Hc, CH, params);
  }

  // ---- close + MLP head ----
  gemm_k<0, false, false, false><<<dim3(64, 2), 256, 0, stream>>>(KNc, 128, xn, NUL, nB, 128, NNODES,
      nullptr, NUL, nullptr, 0.f, CH, NUL);
  gemm_k<3, false, false, false><<<dim3(64, 4), 256, 0, stream>>>(W1, 128, nB, NUL, l1b, 128, NNODES,
      nullptr, b1, nullptr, 0.f, 256, NUL);
  gemm_k<4, false, false, false><<<dim3(64, 16), 256, 0, stream>>>(W2, 256, l1b, NUL, out, 256, NNODES,
      nullptr, b2, nullptr, 0.f, 1024, NUL);
  logsoftmax_k<<<NNODES, 256, 0, stream>>>(out);
}

// Round 4
// 1070.101 us; speedup vs baseline: 2.3898x; 1.2376x over previous
//
#include <hip/hip_runtime.h>

#define NNODES 4096
#define NEDGES 65536
#define CH 128

typedef __bf16 bf16x8_t __attribute__((ext_vector_type(8)));
typedef __bf16 bf16x4_t __attribute__((ext_vector_type(4)));
typedef float f32x4_t __attribute__((ext_vector_type(4)));

// ================= f32 tiled GEMM (node-side) =================
// MODE 0: plain store            MODE 1: store + ln partials
// MODE 5: resid += Hc * val      MODE 6: transposed store, no bias
// XT: x = tanh((x - xprm[0]) * xprm[1]) on X load
// APREP: A is virtual [256][128] from KE1i
// X2F: K-rows >= 256 come from X2
template<int MODE, bool XT, bool APREP, bool X2F>
__global__ __launch_bounds__(256) void gemm_k(
    const float* __restrict__ A, int lda,
    const float* __restrict__ X, const float* __restrict__ X2,
    float* __restrict__ C,
    int K, int NCOLS,
    double* __restrict__ partials,
    float* __restrict__ resid, float Hc, int Mrows,
    const float* __restrict__ xprm)
{
  __shared__ float As[16][64];
  __shared__ float Xs[16][64];
  const int tid = threadIdx.x;
  const int tx = tid & 15, ty = tid >> 4;
  const int n0 = blockIdx.x * 64;
  const int m0 = blockIdx.y * 64;
  const int lm  = tid & 63;
  const int lk4 = (tid >> 6) * 4;
  const int lxk = tid >> 4;
  const int lxm = (tid & 15) * 4;
  float p0 = 0.f, p1 = 0.f;
  if constexpr (XT) { p0 = xprm[0]; p1 = xprm[1]; }
  float acc[4][4] = {};
  for (int k0 = 0; k0 < K; k0 += 16) {
    float4 av;
    if constexpr (APREP) {
      int r = m0 + lm; int o = r & 127; float sg = (r < 128) ? 1.f : -1.f;
      float4 k1 = *(const float4*)&A[(size_t)o * 384 + (k0 + lk4)];
      float4 k3 = *(const float4*)&A[(size_t)o * 384 + 256 + (k0 + lk4)];
      av.x = 0.5f * k1.x + sg * k3.x;
      av.y = 0.5f * k1.y + sg * k3.y;
      av.z = 0.5f * k1.z + sg * k3.z;
      av.w = 0.5f * k1.w + sg * k3.w;
    } else {
      av = *(const float4*)&A[(size_t)(m0 + lm) * lda + (k0 + lk4)];
    }
    const int xk = k0 + lxk;
    float4 xv;
    if constexpr (X2F) {
      xv = (xk >= 256) ? *(const float4*)&X2[(size_t)(xk - 256) * NCOLS + (n0 + lxm)]
                       : *(const float4*)&X[(size_t)xk * NCOLS + (n0 + lxm)];
    } else {
      xv = *(const float4*)&X[(size_t)xk * NCOLS + (n0 + lxm)];
    }
    if constexpr (XT) {
      xv.x = tanhf((xv.x - p0) * p1);
      xv.y = tanhf((xv.y - p0) * p1);
      xv.z = tanhf((xv.z - p0) * p1);
      xv.w = tanhf((xv.w - p0) * p1);
    }
    __syncthreads();
    As[lk4 + 0][lm] = av.x;
    As[lk4 + 1][lm] = av.y;
    As[lk4 + 2][lm] = av.z;
    As[lk4 + 3][lm] = av.w;
    *(float4*)&Xs[lxk][lxm] = xv;
    __syncthreads();
#pragma unroll
    for (int k = 0; k < 16; ++k) {
      float4 ra = *(const float4*)&As[k][ty * 4];
      float4 rx = *(const float4*)&Xs[k][tx * 4];
      float rav[4] = {ra.x, ra.y, ra.z, ra.w};
      float rxv[4] = {rx.x, rx.y, rx.z, rx.w};
#pragma unroll
      for (int a = 0; a < 4; ++a)
#pragma unroll
        for (int b = 0; b < 4; ++b) acc[a][b] = fmaf(rav[a], rxv[b], acc[a][b]);
    }
  }
  double psum = 0.0, psq = 0.0;
  if constexpr (MODE == 6) {
#pragma unroll
    for (int b = 0; b < 4; ++b) {
      const int col = n0 + tx * 4 + b;
      float4 v = {acc[0][b], acc[1][b], acc[2][b], acc[3][b]};
      *(float4*)&C[(size_t)col * Mrows + (m0 + ty * 4)] = v;
    }
  } else {
#pragma unroll
    for (int a = 0; a < 4; ++a) {
      const int row = m0 + ty * 4 + a;
      const int col = n0 + tx * 4;
      float v[4] = {acc[a][0], acc[a][1], acc[a][2], acc[a][3]};
      if constexpr (MODE == 1) {
#pragma unroll
        for (int b = 0; b < 4; ++b) { psum += (double)v[b]; psq += (double)v[b] * (double)v[b]; }
      }
      if constexpr (MODE == 5) {
        float4* rp = (float4*)&resid[(size_t)row * NCOLS + col];
        float4 r = *rp;
        r.x += Hc * v[0]; r.y += Hc * v[1]; r.z += Hc * v[2]; r.w += Hc * v[3];
        *rp = r;
      } else {
        float4 sv = {v[0], v[1], v[2], v[3]};
        *(float4*)&C[(size_t)row * NCOLS + col] = sv;
      }
    }
  }
  if constexpr (MODE == 1) {
    __shared__ double red[256];
    const int pid = blockIdx.y * gridDim.x + blockIdx.x;
    red[tid] = psum; __syncthreads();
    for (int s = 128; s > 0; s >>= 1) { if (tid < s) red[tid] += red[tid + s]; __syncthreads(); }
    if (tid == 0) partials[2 * pid] = red[0];
    __syncthreads();
    red[tid] = psq; __syncthreads();
    for (int s = 128; s > 0; s >>= 1) { if (tid < s) red[tid] += red[tid + s]; __syncthreads(); }
    if (tid == 0) partials[2 * pid + 1] = red[0];
  }
}

// ================= bf16 MFMA edge GEMM: C[E][128] = X[E][K] @ A[128][K]^T =================
// EM 0: plain, stats           EM 2: + w*(U[I]+V[J]), stats
// EM 1: tanh-on-load, stats    EM 3: tanh-on-load, no stats, dual store bf16 + f32
template<int EM, int K>
__global__ __launch_bounds__(256) void emfma_k(
    const __bf16* __restrict__ A, const __bf16* __restrict__ X,
    __bf16* __restrict__ Cb, float* __restrict__ Cf,
    double* __restrict__ partials,
    const float* __restrict__ UV, const float* __restrict__ wg,
    const int* __restrict__ iIe, const int* __restrict__ jIe,
    const float* __restrict__ xprm)
{
  const int tid = threadIdx.x;
  const int wv = tid >> 6, lane = tid & 63;
  const int l15 = lane & 15, ks = lane >> 4;
  const int e = blockIdx.x * 64 + wv * 16 + l15;
  constexpr int KK = K / 32;
  float p0 = 0.f, p1 = 0.f;
  if constexpr (EM == 1 || EM == 3) { p0 = xprm[0]; p1 = xprm[1]; }
  bf16x8_t bq[KK];
  {
    const __bf16* xr = X + (size_t)e * K + ks * 8;
#pragma unroll
    for (int kk = 0; kk < KK; ++kk) {
      bf16x8_t v = *(const bf16x8_t*)(xr + kk * 32);
      if constexpr (EM == 1 || EM == 3) {
#pragma unroll
        for (int j = 0; j < 8; ++j) v[j] = (__bf16)tanhf(((float)v[j] - p0) * p1);
      }
      bq[kk] = v;
    }
  }
  float we = 0.f; int ie = 0, je = 0;
  if constexpr (EM == 2) { we = wg[e]; ie = iIe[e]; je = jIe[e]; }
  double dsum = 0.0, dsq = 0.0;
#pragma unroll
  for (int ob = 0; ob < 8; ++ob) {
    f32x4_t acc = {0.f, 0.f, 0.f, 0.f};
    const __bf16* ar = A + (size_t)(ob * 16 + l15) * K + ks * 8;
#pragma unroll
    for (int kk = 0; kk < KK; ++kk) {
      bf16x8_t a = *(const bf16x8_t*)(ar + kk * 32);
      acc = __builtin_amdgcn_mfma_f32_16x16x32_bf16(a, bq[kk], acc, 0, 0, 0);
    }
    const int ro = ob * 16 + ks * 4;
    float v0 = acc[0], v1 = acc[1], v2 = acc[2], v3 = acc[3];
    if constexpr (EM == 2) {
      float4 u4 = *(const float4*)&UV[(size_t)ie * 256 + ro];
      float4 w4 = *(const float4*)&UV[(size_t)je * 256 + 128 + ro];
      v0 += we * (u4.x + w4.x); v1 += we * (u4.y + w4.y);
      v2 += we * (u4.z + w4.z); v3 += we * (u4.w + w4.w);
    }
    if constexpr (EM != 3) {
      dsum += (double)v0 + (double)v1 + (double)v2 + (double)v3;
      dsq  += (double)v0 * v0 + (double)v1 * v1 + (double)v2 * v2 + (double)v3 * v3;
    }
    bf16x4_t bv;
    bv[0] = (__bf16)v0; bv[1] = (__bf16)v1; bv[2] = (__bf16)v2; bv[3] = (__bf16)v3;
    *(bf16x4_t*)(Cb + (size_t)e * 128 + ro) = bv;
    if constexpr (EM == 3) {
      float4 fv = {v0, v1, v2, v3};
      *(float4*)(Cf + (size_t)e * 128 + ro) = fv;
    }
  }
  if constexpr (EM != 3) {
    __shared__ double red[256];
    red[tid] = dsum; __syncthreads();
    for (int s = 128; s > 0; s >>= 1) { if (tid < s) red[tid] += red[tid + s]; __syncthreads(); }
    if (tid == 0) partials[2 * blockIdx.x] = red[0];
    __syncthreads();
    red[tid] = dsq; __syncthreads();
    for (int s = 128; s > 0; s >>= 1) { if (tid < s) red[tid] += red[tid + s]; __syncthreads(); }
    if (tid == 0) partials[2 * blockIdx.x + 1] = red[0];
  }
}

// ================= bf16 MFMA node GEMM (head): C[N][NOUT] = X[N][K] @ A[NOUT][K]^T =================
// EM 0: bf16 out; 1: +bias, elu, bf16 out; 2: +bias, f32 out
template<int NOUT, int K, int EM>
__global__ __launch_bounds__(256) void nmfma_k(
    const __bf16* __restrict__ A, const __bf16* __restrict__ X,
    __bf16* __restrict__ Cb, float* __restrict__ Cf, const float* __restrict__ bias)
{
  const int tid = threadIdx.x;
  const int wv = tid >> 6, lane = tid & 63;
  const int l15 = lane & 15, ks = lane >> 4;
  const int n = blockIdx.x * 64 + wv * 16 + l15;
  constexpr int KK = K / 32;
  bf16x8_t bq[KK];
  {
    const __bf16* xr = X + (size_t)n * K + ks * 8;
#pragma unroll
    for (int kk = 0; kk < KK; ++kk) bq[kk] = *(const bf16x8_t*)(xr + kk * 32);
  }
#pragma unroll 4
  for (int ob = 0; ob < NOUT / 16; ++ob) {
    f32x4_t acc = {0.f, 0.f, 0.f, 0.f};
    const __bf16* ar = A + (size_t)(ob * 16 + l15) * K + ks * 8;
#pragma unroll
    for (int kk = 0; kk < KK; ++kk) {
      bf16x8_t a = *(const bf16x8_t*)(ar + kk * 32);
      acc = __builtin_amdgcn_mfma_f32_16x16x32_bf16(a, bq[kk], acc, 0, 0, 0);
    }
    const int ro = ob * 16 + ks * 4;
    float v[4] = {acc[0], acc[1], acc[2], acc[3]};
    if constexpr (EM >= 1) {
#pragma unroll
      for (int r = 0; r < 4; ++r) v[r] += bias[ro + r];
    }
    if constexpr (EM == 1) {
#pragma unroll
      for (int r = 0; r < 4; ++r) v[r] = v[r] > 0.f ? v[r] : expm1f(v[r]);
    }
    if constexpr (EM == 2) {
      float4 fv = {v[0], v[1], v[2], v[3]};
      *(float4*)(Cf + (size_t)n * NOUT + ro) = fv;
    } else {
      bf16x4_t bv;
      bv[0] = (__bf16)v[0]; bv[1] = (__bf16)v[1]; bv[2] = (__bf16)v[2]; bv[3] = (__bf16)v[3];
      *(bf16x4_t*)(Cb + (size_t)n * NOUT + ro) = bv;
    }
  }
}

// ================= dstat via MFMA Gram matrix, upper triangle =================
__global__ __launch_bounds__(256) void dstat_k(
    const __bf16* __restrict__ fT, const float* __restrict__ s,
    double* __restrict__ partials)
{
  const int tid = threadIdx.x;
  const int pid = blockIdx.y * gridDim.x + blockIdx.x;
  const int j0 = blockIdx.x * 64, i0 = blockIdx.y * 64;
  if (j0 < i0) { if (tid < 2) partials[2 * pid + tid] = 0.0; return; }
  const double wgt = (j0 > i0) ? 2.0 : 1.0;
  const int wv = tid >> 6, lane = tid & 63, l15 = lane & 15, ks = lane >> 4;
  const int irow = i0 + wv * 16 + l15;
  bf16x8_t aq[4];
  const __bf16* ar = fT + (size_t)irow * 128 + ks * 8;
#pragma unroll
  for (int kk = 0; kk < 4; ++kk) aq[kk] = *(const bf16x8_t*)(ar + kk * 32);
  float si[4];
#pragma unroll
  for (int r = 0; r < 4; ++r) si[r] = s[i0 + wv * 16 + ks * 4 + r];
  double dsum = 0.0, dsq = 0.0;
#pragma unroll
  for (int jb = 0; jb < 4; ++jb) {
    const int jcol = j0 + jb * 16 + l15;
    const __bf16* br = fT + (size_t)jcol * 128 + ks * 8;
    f32x4_t acc = {0.f, 0.f, 0.f, 0.f};
#pragma unroll
    for (int kk = 0; kk < 4; ++kk) {
      bf16x8_t b = *(const bf16x8_t*)(br + kk * 32);
      acc = __builtin_amdgcn_mfma_f32_16x16x32_bf16(aq[kk], b, acc, 0, 0, 0);
    }
    const float sj = s[jcol];
#pragma unroll
    for (int r = 0; r < 4; ++r) {
      float d = si[r] + sj - 2.f * acc[r];
      d = d > 0.f ? d : 0.f;
      dsum += (double)d; dsq += (double)d * (double)d;
    }
  }
  dsum *= wgt; dsq *= wgt;
  __shared__ double red[256];
  red[tid] = dsum; __syncthreads();
  for (int s2 = 128; s2 > 0; s2 >>= 1) { if (tid < s2) red[tid] += red[tid + s2]; __syncthreads(); }
  if (tid == 0) partials[2 * pid] = red[0];
  __syncthreads();
  red[tid] = dsq; __syncthreads();
  for (int s2 = 128; s2 > 0; s2 >>= 1) { if (tid < s2) red[tid] += red[tid + s2]; __syncthreads(); }
  if (tid == 0) partials[2 * pid + 1] = red[0];
}

// ================= finalize: partials -> params =================
__global__ __launch_bounds__(256) void finalize_k(const double* __restrict__ partials, int nblk,
                                                  float* __restrict__ params, double M, int type)
{
  __shared__ double rs[256], rq[256];
  const int tid = threadIdx.x;
  double s = 0.0, q = 0.0;
  for (int i = tid; i < nblk; i += 256) { s += partials[2 * i]; q += partials[2 * i + 1]; }
  rs[tid] = s; rq[tid] = q; __syncthreads();
  for (int st = 128; st > 0; st >>= 1) {
    if (tid < st) { rs[tid] += rs[tid + st]; rq[tid] += rq[tid + st]; }
    __syncthreads();
  }
  if (tid == 0) {
    double S = rs[0], Q = rq[0];
    if (type == 0) {
      double mean = S / M;
      double var = Q / M - mean * mean;
      if (var < 0.0) var = 0.0;
      params[0] = (float)mean;
      params[1] = (float)(1.0 / sqrt(var + 1e-5));
    } else {
      double var = (Q - S * S / M) / (M - 1.0);
      if (var < 1e-30) var = 1e-30;
      params[0] = (float)(-2.0 / sqrt(var));
    }
  }
}

// ================= transpose xn [128][N] -> xnT f32 [N][128] + bf16 + s =================
__global__ __launch_bounds__(256) void trans_k(const float* __restrict__ xn,
    float* __restrict__ xnT, __bf16* __restrict__ xnTb, float* __restrict__ sbuf)
{
  __shared__ float t[64][129];
  const int n0 = blockIdx.x * 64;
  const int tx = threadIdx.x & 63, tw = threadIdx.x >> 6;
  for (int c = tw; c < CH; c += 4)
    t[tx][c] = xn[(size_t)c * NNODES + n0 + tx];
  __syncthreads();
  for (int it = 0; it < 8; ++it) {
    int idx = threadIdx.x + it * 256;
    int n = idx >> 5, cq = (idx & 31) * 4;
    float4 v = {t[n][cq], t[n][cq + 1], t[n][cq + 2], t[n][cq + 3]};
    *(float4*)&xnT[(size_t)(n0 + n) * CH + cq] = v;
    bf16x4_t b;
    b[0] = (__bf16)v.x; b[1] = (__bf16)v.y; b[2] = (__bf16)v.z; b[3] = (__bf16)v.w;
    *(bf16x4_t*)&xnTb[(size_t)(n0 + n) * CH + cq] = b;
  }
  if (threadIdx.x < 64) {
    float a = 0.f;
    for (int c = 0; c < CH; ++c) { float x = t[threadIdx.x][c]; a = fmaf(x, x, a); }
    sbuf[n0 + threadIdx.x] = a;
  }
}

// ================= transpose xe_in [64][E] f32 -> [E][64] bf16 =================
__global__ __launch_bounds__(256) void etrans_k(const float* __restrict__ xe_in,
                                                __bf16* __restrict__ xeT64)
{
  __shared__ float t[64][65];
  const int e0 = blockIdx.x * 64;
  const int tx = threadIdx.x & 63, tw = threadIdx.x >> 6;
  for (int c = tw; c < 64; c += 4)
    t[tx][c] = xe_in[(size_t)c * NEDGES + e0 + tx];
  __syncthreads();
  const int el = threadIdx.x >> 2, c0 = (threadIdx.x & 3) * 16;
  for (int q = 0; q < 4; ++q) {
    int c = c0 + q * 4;
    bf16x4_t b;
    b[0] = (__bf16)t[el][c];     b[1] = (__bf16)t[el][c + 1];
    b[2] = (__bf16)t[el][c + 2]; b[3] = (__bf16)t[el][c + 3];
    *(bf16x4_t*)&xeT64[(size_t)(e0 + el) * 64 + c] = b;
  }
}

// ================= per-edge weight from xnT f32 =================
__global__ void edge_w_k(const float* __restrict__ xnT, const float* __restrict__ s,
                         const int* __restrict__ iI, const int* __restrict__ jJ,
                         const float* __restrict__ params, float* __restrict__ w)
{
  int e = blockIdx.x * 256 + threadIdx.x;
  int a = iI[e], b = jJ[e];
  const float4* pa = (const float4*)(xnT + (size_t)a * CH);
  const float4* pb = (const float4*)(xnT + (size_t)b * CH);
  float g = 0.f;
#pragma unroll
  for (int q = 0; q < CH / 4; ++q) {
    float4 u = pa[q], v = pb[q];
    g = fmaf(u.x, v.x, g); g = fmaf(u.y, v.y, g);
    g = fmaf(u.z, v.z, g); g = fmaf(u.w, v.w, g);
  }
  float d = s[a] + s[b] - 2.f * g;
  d = d > 0.f ? d : 0.f;
  w[e] = expf(params[0] * d);
}

// ================= weight conversion to bf16 =================
__global__ void wcvt_k(const float* __restrict__ K1E, const float* __restrict__ K2E,
                       const float* __restrict__ KE1, const float* __restrict__ KE2,
                       const float* __restrict__ KNc, const float* __restrict__ W1,
                       const float* __restrict__ W2,
                       __bf16* __restrict__ K1Eb, __bf16* __restrict__ K2Eb,
                       __bf16* __restrict__ KE1b, __bf16* __restrict__ KE2b,
                       __bf16* __restrict__ KNcb, __bf16* __restrict__ W1b,
                       __bf16* __restrict__ W2b)
{
  int id = blockIdx.x * 256 + threadIdx.x;
  if (id < 8192) { K1Eb[id] = (__bf16)K1E[id]; return; }
  id -= 8192;
  if (id < 16384) { K2Eb[id] = (__bf16)K2E[id]; return; }
  id -= 16384;
  if (id < 65536) {
    int l = id >> 14, rem = id & 16383, r = rem >> 7, c = rem & 127;
    KE1b[id] = (__bf16)KE1[(size_t)l * 49152 + r * 384 + 128 + c];
    return;
  }
  id -= 65536;
  if (id < 65536) { KE2b[id] = (__bf16)KE2[id]; return; }
  id -= 65536;
  if (id < 16384) { KNcb[id] = (__bf16)KNc[id]; return; }
  id -= 16384;
  if (id < 32768) { W1b[id] = (__bf16)W1[id]; return; }
  id -= 32768;
  if (id < 262144) { W2b[id] = (__bf16)W2[id]; return; }
}

// ================= lnres: xe += 0.1*ln(eB); write f32 + bf16 =================
__global__ void lnres_k(const __bf16* __restrict__ eBT, float* __restrict__ xe_em,
                        __bf16* __restrict__ xeT, const float* __restrict__ p)
{
  size_t i = ((size_t)blockIdx.x * 256 + threadIdx.x) * 8;
  const float m = p[0], r = p[1];
  bf16x8_t b = *(const bf16x8_t*)(eBT + i);
  float4 x0 = *(const float4*)(xe_em + i);
  float4 x1 = *(const float4*)(xe_em + i + 4);
  float nv[8];
  nv[0] = x0.x + 0.1f * (((float)b[0] - m) * r);
  nv[1] = x0.y + 0.1f * (((float)b[1] - m) * r);
  nv[2] = x0.z + 0.1f * (((float)b[2] - m) * r);
  nv[3] = x0.w + 0.1f * (((float)b[3] - m) * r);
  nv[4] = x1.x + 0.1f * (((float)b[4] - m) * r);
  nv[5] = x1.y + 0.1f * (((float)b[5] - m) * r);
  nv[6] = x1.z + 0.1f * (((float)b[6] - m) * r);
  nv[7] = x1.w + 0.1f * (((float)b[7] - m) * r);
  float4 o0 = {nv[0], nv[1], nv[2], nv[3]};
  float4 o1 = {nv[4], nv[5], nv[6], nv[7]};
  *(float4*)(xe_em + i) = o0;
  *(float4*)(xe_em + i + 4) = o1;
  bf16x8_t ob;
#pragma unroll
  for (int j = 0; j < 8; ++j) ob[j] = (__bf16)nv[j];
  *(bf16x8_t*)(xeT + i) = ob;
}

// ================= CSR build =================
__global__ void hist_k(const int* __restrict__ iI, const int* __restrict__ jJ,
                       int* __restrict__ cnt)
{
  int e = blockIdx.x * 256 + threadIdx.x;
  atomicAdd(&cnt[iI[e]], 1);
  atomicAdd(&cnt[jJ[e]], 1);
}

__global__ __launch_bounds__(1024) void scan_k(const int* __restrict__ cnt,
                                               int* __restrict__ offs,
                                               int* __restrict__ cursor)
{
  __shared__ int tmp[1024];
  const int tid = threadIdx.x;
  int4 v = *(const int4*)&cnt[tid * 4];
  int s = v.x + v.y + v.z + v.w;
  tmp[tid] = s; __syncthreads();
  for (int d = 1; d < 1024; d <<= 1) {
    int t = (tid >= d) ? tmp[tid - d] : 0;
    __syncthreads();
    tmp[tid] += t;
    __syncthreads();
  }
  int base = tmp[tid] - s;
  int4 o = {base, base + v.x, base + v.x + v.y, base + v.x + v.y + v.z};
  *(int4*)&offs[tid * 4] = o;
  *(int4*)&cursor[tid * 4] = o;
  if (tid == 1023) offs[4096] = tmp[1023];
}

__global__ void fill_k(const int* __restrict__ iI, const int* __restrict__ jJ,
                       int* __restrict__ cursor, int* __restrict__ list)
{
  int e = blockIdx.x * 256 + threadIdx.x;
  int p1 = atomicAdd(&cursor[iI[e]], 1);
  list[p1] = e;
  int p2 = atomicAdd(&cursor[jJ[e]], 1);
  list[p2] = e | 0x80000000;
}

// ================= gather: ave/div per node from edge-major xe =================
__global__ __launch_bounds__(256) void gather_k(
    const float* __restrict__ xe_em, const float* __restrict__ w,
    const int* __restrict__ offs, const int* __restrict__ list,
    float* __restrict__ cat)
{
  __shared__ float stg[2][128][8];
  const int wv = threadIdx.x >> 6, lane = threadIdx.x & 63;
  const int n0 = blockIdx.x * 8;
  for (int nn = wv; nn < 8; nn += 4) {
    const int n = n0 + nn;
    const int k0 = offs[n], k1 = offs[n + 1];
    float s1a = 0.f, s1b = 0.f, s2a = 0.f, s2b = 0.f;
#pragma unroll 2
    for (int k = k0; k < k1; ++k) {
      int enc = list[k];
      int e = enc & 0x7fffffff;
      float we = w[e];
      float va = xe_em[(size_t)e * 128 + lane] * we;
      float vb = xe_em[(size_t)e * 128 + 64 + lane] * we;
      if (enc >= 0) { s1a += va; s1b += vb; }
      else          { s2a += va; s2b += vb; }
    }
    stg[0][lane][nn]      = 0.5f * (s1a + s2a);
    stg[0][64 + lane][nn] = 0.5f * (s1b + s2b);
    stg[1][lane][nn]      = s1a - s2a;
    stg[1][64 + lane][nn] = s1b - s2b;
  }
  __syncthreads();
  const int row = threadIdx.x;
  const int part = row >> 7, c = row & 127;
  float* dst = cat + (size_t)(part * 128 + c) * NNODES + n0;
  float4 v0 = {stg[part][c][0], stg[part][c][1], stg[part][c][2], stg[part][c][3]};
  float4 v1 = {stg[part][c][4], stg[part][c][5], stg[part][c][6], stg[part][c][7]};
  *(float4*)&dst[0] = v0;
  *(float4*)&dst[4] = v1;
}

// ================= log_softmax rows of [N][1024] =================
__global__ __launch_bounds__(256) void logsoftmax_k(float* __restrict__ out)
{
  __shared__ float red[256];
  const int n = blockIdx.x, tid = threadIdx.x;
  float* row = out + (size_t)n * 1024;
  float v[4];
  float mx = -1e30f;
#pragma unroll
  for (int l = 0; l < 4; ++l) { v[l] = row[tid + 256 * l]; mx = fmaxf(mx, v[l]); }
  red[tid] = mx; __syncthreads();
  for (int s = 128; s > 0; s >>= 1) { if (tid < s) red[tid] = fmaxf(red[tid], red[tid + s]); __syncthreads(); }
  float m = red[0]; __syncthreads();
  float se = 0.f;
#pragma unroll
  for (int l = 0; l < 4; ++l) se += expf(v[l] - m);
  red[tid] = se; __syncthreads();
  for (int s = 128; s > 0; s >>= 1) { if (tid < s) red[tid] += red[tid + s]; __syncthreads(); }
  float L = m + logf(red[0]);
#pragma unroll
  for (int l = 0; l < 4; ++l) row[tid + 256 * l] = v[l] - L;
}

extern "C" void kernel_launch(void* const* d_in, const int* in_sizes, int n_in,
                              void* d_out, int out_size, void* d_ws, size_t ws_size,
                              hipStream_t stream)
{
  (void)in_sizes; (void)n_in; (void)out_size; (void)ws_size;
  const float* xn_in = (const float*)d_in[0];
  const float* xe_in = (const float*)d_in[1];
  const int*   iI    = (const int*)d_in[2];
  const int*   jJ    = (const int*)d_in[3];
  const float* K1N   = (const float*)d_in[4];
  const float* K2N   = (const float*)d_in[5];
  const float* K1E   = (const float*)d_in[6];
  const float* K2E   = (const float*)d_in[7];
  const float* KNc   = (const float*)d_in[8];
  const float* KE1   = (const float*)d_in[9];
  const float* KE2   = (const float*)d_in[10];
  const float* KN1   = (const float*)d_in[11];
  const float* KN2   = (const float*)d_in[12];
  const float* W1    = (const float*)d_in[13];
  const float* b1    = (const float*)d_in[14];
  const float* W2    = (const float*)d_in[15];
  const float* b2    = (const float*)d_in[16];
  float* out = (float*)d_out;

  float* ws = (float*)d_ws;
  size_t off = 0;
  auto alloc = [&](size_t n) { size_t o = off; off += (n + 63) & ~(size_t)63; return o; };
  float* xn    = ws + alloc((size_t)CH * NNODES);
  float* xe_em = ws + alloc((size_t)NEDGES * CH);          // f32 residual, edge-major
  __bf16* xeT  = (__bf16*)(ws + alloc((size_t)NEDGES * CH / 2));
  __bf16* eAT  = (__bf16*)(ws + alloc((size_t)NEDGES * CH / 2));
  __bf16* eBT  = (__bf16*)(ws + alloc((size_t)NEDGES * CH / 2));
  float* nA    = ws + alloc((size_t)CH * NNODES);
  float* nB    = ws + alloc((size_t)CH * NNODES);
  float* sbuf  = ws + alloc(NNODES);
  float* wbuf  = ws + alloc(NEDGES);
  float* UV    = ws + alloc((size_t)NNODES * 256);
  float* cat   = ws + alloc((size_t)256 * NNODES);
  float* xnT   = ws + alloc((size_t)NNODES * CH);
  __bf16* xnTb = (__bf16*)(ws + alloc((size_t)NNODES * CH / 2));
  __bf16* K1Eb = (__bf16*)(ws + alloc(8192 / 2));
  __bf16* K2Eb = (__bf16*)(ws + alloc(16384 / 2));
  __bf16* KE1b = (__bf16*)(ws + alloc(65536 / 2));
  __bf16* KE2b = (__bf16*)(ws + alloc(65536 / 2));
  __bf16* KNcb = (__bf16*)(ws + alloc(16384 / 2));
  __bf16* W1b  = (__bf16*)(ws + alloc(32768 / 2));
  __bf16* W2b  = (__bf16*)(ws + alloc(262144 / 2));
  __bf16* zb   = (__bf16*)(ws + alloc((size_t)NNODES * CH / 2));
  __bf16* l1bb = (__bf16*)(ws + alloc((size_t)NNODES * 256 / 2));
  int* csr_cnt    = (int*)(ws + alloc(4096));
  int* csr_offs   = (int*)(ws + alloc(4160));
  int* csr_cursor = (int*)(ws + alloc(4096));
  int* csr_list   = (int*)(ws + alloc(2 * NEDGES));
  double* partials = (double*)(ws + alloc((size_t)4096 * 2 * 2));
  float* params = ws + alloc(64);
  // alias: xeT64 (opening only) shares eBT (first written in layer-0 edge pass 2)
  __bf16* xeT64 = eBT;

  const float* NUL = nullptr;
  const int* NULI = nullptr;
  const float Hc = 0.1f;

  // ---- weight conversion + CSR build (once) ----
  wcvt_k<<<1824, 256, 0, stream>>>(K1E, K2E, KE1, KE2, KNc, W1, W2,
                                   K1Eb, K2Eb, KE1b, KE2b, KNcb, W1b, W2b);
  hipMemsetAsync(csr_cnt, 0, 4096 * sizeof(int), stream);
  hist_k<<<NEDGES / 256, 256, 0, stream>>>(iI, jJ, csr_cnt);
  scan_k<<<1, 1024, 0, stream>>>(csr_cnt, csr_offs, csr_cursor);
  fill_k<<<NEDGES / 256, 256, 0, stream>>>(iI, jJ, csr_cursor, csr_list);

  // ---- opening: node double layer (f32) ----
  gemm_k<1, false, false, false><<<dim3(64, 2), 256, 0, stream>>>(K1N, 64, xn_in, NUL, nA, 64, NNODES,
      partials, nullptr, 0.f, CH, NUL);
  finalize_k<<<1, 256, 0, stream>>>(partials, 128, params, (double)CH * NNODES, 0);
  gemm_k<0, true, false, false><<<dim3(64, 2), 256, 0, stream>>>(K2N, 128, nA, NUL, xn, 128, NNODES,
      nullptr, nullptr, 0.f, CH, params);

  // ---- opening: edge double layer (MFMA) ----
  etrans_k<<<NEDGES / 64, 256, 0, stream>>>(xe_in, xeT64);
  emfma_k<0, 64><<<NEDGES / 64, 256, 0, stream>>>(K1Eb, xeT64, eAT, nullptr,
      partials, NUL, NUL, NULI, NULI, NUL);
  finalize_k<<<1, 256, 0, stream>>>(partials, 1024, params, (double)CH * NEDGES, 0);
  emfma_k<3, 128><<<NEDGES / 64, 256, 0, stream>>>(K2Eb, eAT, xeT, xe_em,
      nullptr, NUL, NUL, NULI, NULI, params);

  for (int i = 0; i < 4; ++i) {
    const float* KE1i = KE1 + (size_t)i * 128 * 384;
    const float* KN1i = KN1 + (size_t)i * 128 * 384;
    const float* KN2i = KN2 + (size_t)i * 128 * 128;
    const __bf16* KE1bi = KE1b + (size_t)i * 128 * 128;
    const __bf16* KE2bi = KE2b + (size_t)i * 128 * 128;

    // D statistics -> factor = -2/std ; edge weights
    trans_k<<<NNODES / 64, 256, 0, stream>>>(xn, xnT, xnTb, sbuf);
    dstat_k<<<dim3(64, 64), 256, 0, stream>>>(xnTb, sbuf, partials);
    finalize_k<<<1, 256, 0, stream>>>(partials, 4096, params, (double)NNODES * (double)NNODES, 1);
    edge_w_k<<<NEDGES / 256, 256, 0, stream>>>(xnT, sbuf, iI, jJ, params, wbuf);

    // UV = [A1;A2] @ xn stored node-major [n][256]
    gemm_k<6, false, true, false><<<dim3(64, 4), 256, 0, stream>>>(KE1i, 384, xn, NUL, UV, 128, NNODES,
        nullptr, nullptr, 0.f, 256, NUL);
    // edge pass 1: eA = KE1b @ xe + w*(U_I + V_J), stats
    emfma_k<2, 128><<<NEDGES / 64, 256, 0, stream>>>(KE1bi, xeT, eAT, nullptr,
        partials, UV, wbuf, iI, jJ, NUL);
    finalize_k<<<1, 256, 0, stream>>>(partials, 1024, params, (double)CH * NEDGES, 0);
    // edge pass 2: eB = KE2 @ tanh(ln(eA)), stats
    emfma_k<1, 128><<<NEDGES / 64, 256, 0, stream>>>(KE2bi, eAT, eBT, nullptr,
        partials, NUL, NUL, NULI, NULI, params);
    finalize_k<<<1, 256, 0, stream>>>(partials, 1024, params, (double)CH * NEDGES, 0);
    // xe += 0.1 * ln(eB)
    lnres_k<<<(NEDGES * CH) / (256 * 8), 256, 0, stream>>>(eBT, xe_em, xeT, params);

    // node update: gather ave/div, then KN1 (+xn tail) -> tanh(ln) -> xn += H*(KN2@hid)
    gather_k<<<NNODES / 8, 256, 0, stream>>>(xe_em, wbuf, csr_offs, csr_list, cat);
    gemm_k<1, false, false, true><<<dim3(64, 2), 256, 0, stream>>>(KN1i, 384, cat, xn, nA, 384, NNODES,
        partials, nullptr, 0.f, CH, NUL);
    finalize_k<<<1, 256, 0, stream>>>(partials, 128, params, (double)CH * NNODES, 0);
    gemm_k<5, true, false, false><<<dim3(64, 2), 256, 0, stream>>>(KN2i, 128, nA, NUL, nB, 128, NNODES,
        nullptr, xn, Hc, CH, params);
  }

  // ---- close + MLP head (bf16 MFMA, node-major) ----
  trans_k<<<NNODES / 64, 256, 0, stream>>>(xn, xnT, xnTb, sbuf);
  nmfma_k<128, 128, 0><<<NNODES / 64, 256, 0, stream>>>(KNcb, xnTb, zb, nullptr, NUL);
  nmfma_k<256, 128, 1><<<NNODES / 64, 256, 0, stream>>>(W1b, zb, l1bb, nullptr, b1);
  nmfma_k<1024, 256, 2><<<NNODES / 64, 256, 0, stream>>>(W2b, l1bb, nullptr, out, b2);
  logsoftmax_k<<<NNODES, 256, 0, stream>>>(out);
}

// Round 5
// 906.788 us; speedup vs baseline: 2.8202x; 1.1801x over previous
//
#include <hip/hip_runtime.h>

#define NNODES 4096
#define NEDGES 65536
#define CH 128

typedef __bf16 bf16x8_t __attribute__((ext_vector_type(8)));
typedef __bf16 bf16x4_t __attribute__((ext_vector_type(4)));
typedef float f32x4_t __attribute__((ext_vector_type(4)));

// ============ inline params: reduce producer partials -> (mean,rstd) or (factor,0) ============
__device__ __forceinline__ float2 params_inline(const double* __restrict__ pp,
                                                int nblk, double M, int type)
{
  __shared__ double rs[256];
  __shared__ double rq[256];
  __shared__ float pr[2];
  const int tid = threadIdx.x;
  double s = 0.0, q = 0.0;
  for (int i = tid; i < nblk; i += 256) { s += pp[2 * i]; q += pp[2 * i + 1]; }
  rs[tid] = s; rq[tid] = q; __syncthreads();
  for (int st = 128; st > 0; st >>= 1) {
    if (tid < st) { rs[tid] += rs[tid + st]; rq[tid] += rq[tid + st]; }
    __syncthreads();
  }
  if (tid == 0) {
    double S = rs[0], Q = rq[0];
    if (type == 0) {
      double mean = S / M;
      double var = Q / M - mean * mean;
      if (var < 0.0) var = 0.0;
      pr[0] = (float)mean;
      pr[1] = (float)(1.0 / sqrt(var + 1e-5));
    } else {
      double var = (Q - S * S / M) / (M - 1.0);
      if (var < 1e-30) var = 1e-30;
      pr[0] = (float)(-2.0 / sqrt(var));
      pr[1] = 0.f;
    }
  }
  __syncthreads();
  return {pr[0], pr[1]};
}

// ================= f32 tiled GEMM (opening node layer only) =================
// MODE 1: store channel-major + ln partials
// MODE 6: transposed store C[col*Mrows + row]  (-> node-major)
// XT: x = tanh((x - m) * r) on X load, params inline from pp
template<int MODE, bool XT>
__global__ __launch_bounds__(256) void gemm_k(
    const float* __restrict__ A, int lda,
    const float* __restrict__ X,
    float* __restrict__ C,
    int K, int NCOLS,
    double* __restrict__ partials,
    int Mrows,
    const double* __restrict__ pp, int pnblk, double pM)
{
  float p0 = 0.f, p1 = 0.f;
  if constexpr (XT) { float2 pr = params_inline(pp, pnblk, pM, 0); p0 = pr.x; p1 = pr.y; }
  __shared__ float As[16][64];
  __shared__ float Xs[16][64];
  const int tid = threadIdx.x;
  const int tx = tid & 15, ty = tid >> 4;
  const int n0 = blockIdx.x * 64;
  const int m0 = blockIdx.y * 64;
  const int lm  = tid & 63;
  const int lk4 = (tid >> 6) * 4;
  const int lxk = tid >> 4;
  const int lxm = (tid & 15) * 4;
  float acc[4][4] = {};
  for (int k0 = 0; k0 < K; k0 += 16) {
    float4 av = *(const float4*)&A[(size_t)(m0 + lm) * lda + (k0 + lk4)];
    float4 xv = *(const float4*)&X[(size_t)(k0 + lxk) * NCOLS + (n0 + lxm)];
    if constexpr (XT) {
      xv.x = tanhf((xv.x - p0) * p1);
      xv.y = tanhf((xv.y - p0) * p1);
      xv.z = tanhf((xv.z - p0) * p1);
      xv.w = tanhf((xv.w - p0) * p1);
    }
    __syncthreads();
    As[lk4 + 0][lm] = av.x;
    As[lk4 + 1][lm] = av.y;
    As[lk4 + 2][lm] = av.z;
    As[lk4 + 3][lm] = av.w;
    *(float4*)&Xs[lxk][lxm] = xv;
    __syncthreads();
#pragma unroll
    for (int k = 0; k < 16; ++k) {
      float4 ra = *(const float4*)&As[k][ty * 4];
      float4 rx = *(const float4*)&Xs[k][tx * 4];
      float rav[4] = {ra.x, ra.y, ra.z, ra.w};
      float rxv[4] = {rx.x, rx.y, rx.z, rx.w};
#pragma unroll
      for (int a = 0; a < 4; ++a)
#pragma unroll
        for (int b = 0; b < 4; ++b) acc[a][b] = fmaf(rav[a], rxv[b], acc[a][b]);
    }
  }
  double psum = 0.0, psq = 0.0;
  if constexpr (MODE == 6) {
#pragma unroll
    for (int b = 0; b < 4; ++b) {
      const int col = n0 + tx * 4 + b;
      float4 v = {acc[0][b], acc[1][b], acc[2][b], acc[3][b]};
      *(float4*)&C[(size_t)col * Mrows + (m0 + ty * 4)] = v;
    }
  } else {
#pragma unroll
    for (int a = 0; a < 4; ++a) {
      const int row = m0 + ty * 4 + a;
      const int col = n0 + tx * 4;
      float v[4] = {acc[a][0], acc[a][1], acc[a][2], acc[a][3]};
#pragma unroll
      for (int b = 0; b < 4; ++b) { psum += (double)v[b]; psq += (double)v[b] * (double)v[b]; }
      float4 sv = {v[0], v[1], v[2], v[3]};
      *(float4*)&C[(size_t)row * NCOLS + col] = sv;
    }
  }
  if constexpr (MODE == 1) {
    __shared__ double red[256];
    const int pid = blockIdx.y * gridDim.x + blockIdx.x;
    red[tid] = psum; __syncthreads();
    for (int s = 128; s > 0; s >>= 1) { if (tid < s) red[tid] += red[tid + s]; __syncthreads(); }
    if (tid == 0) partials[2 * pid] = red[0];
    __syncthreads();
    red[tid] = psq; __syncthreads();
    for (int s = 128; s > 0; s >>= 1) { if (tid < s) red[tid] += red[tid + s]; __syncthreads(); }
    if (tid == 0) partials[2 * pid + 1] = red[0];
  }
}

// ================= bf16 MFMA edge GEMM: C[E][128] = X[E][K] @ A[128][K]^T =================
// EM 0: plain, stats           EM 2: + w*(U[I]+V[J]), stats
// EM 1: tanh-on-load, stats    EM 3: tanh-on-load, no stats, dual store bf16 + f32
template<int EM, int K>
__global__ __launch_bounds__(256) void emfma_k(
    const __bf16* __restrict__ A, const __bf16* __restrict__ X,
    __bf16* __restrict__ Cb, float* __restrict__ Cf,
    double* __restrict__ partials,
    const float* __restrict__ UV, const float* __restrict__ wg,
    const int* __restrict__ iIe, const int* __restrict__ jIe,
    const double* __restrict__ pp, int pnblk, double pM)
{
  float p0 = 0.f, p1 = 0.f;
  if constexpr (EM == 1 || EM == 3) {
    float2 pr = params_inline(pp, pnblk, pM, 0); p0 = pr.x; p1 = pr.y;
  }
  const int tid = threadIdx.x;
  const int wv = tid >> 6, lane = tid & 63;
  const int l15 = lane & 15, ks = lane >> 4;
  const int e = blockIdx.x * 64 + wv * 16 + l15;
  constexpr int KK = K / 32;
  bf16x8_t bq[KK];
  {
    const __bf16* xr = X + (size_t)e * K + ks * 8;
#pragma unroll
    for (int kk = 0; kk < KK; ++kk) {
      bf16x8_t v = *(const bf16x8_t*)(xr + kk * 32);
      if constexpr (EM == 1 || EM == 3) {
#pragma unroll
        for (int j = 0; j < 8; ++j) v[j] = (__bf16)tanhf(((float)v[j] - p0) * p1);
      }
      bq[kk] = v;
    }
  }
  float we = 0.f; int ie = 0, je = 0;
  if constexpr (EM == 2) { we = wg[e]; ie = iIe[e]; je = jIe[e]; }
  double dsum = 0.0, dsq = 0.0;
#pragma unroll
  for (int ob = 0; ob < 8; ++ob) {
    f32x4_t acc = {0.f, 0.f, 0.f, 0.f};
    const __bf16* ar = A + (size_t)(ob * 16 + l15) * K + ks * 8;
#pragma unroll
    for (int kk = 0; kk < KK; ++kk) {
      bf16x8_t a = *(const bf16x8_t*)(ar + kk * 32);
      acc = __builtin_amdgcn_mfma_f32_16x16x32_bf16(a, bq[kk], acc, 0, 0, 0);
    }
    const int ro = ob * 16 + ks * 4;
    float v0 = acc[0], v1 = acc[1], v2 = acc[2], v3 = acc[3];
    if constexpr (EM == 2) {
      float4 u4 = *(const float4*)&UV[(size_t)ie * 256 + ro];
      float4 w4 = *(const float4*)&UV[(size_t)je * 256 + 128 + ro];
      v0 += we * (u4.x + w4.x); v1 += we * (u4.y + w4.y);
      v2 += we * (u4.z + w4.z); v3 += we * (u4.w + w4.w);
    }
    if constexpr (EM != 3) {
      dsum += (double)v0 + (double)v1 + (double)v2 + (double)v3;
      dsq  += (double)v0 * v0 + (double)v1 * v1 + (double)v2 * v2 + (double)v3 * v3;
    }
    bf16x4_t bv;
    bv[0] = (__bf16)v0; bv[1] = (__bf16)v1; bv[2] = (__bf16)v2; bv[3] = (__bf16)v3;
    *(bf16x4_t*)(Cb + (size_t)e * 128 + ro) = bv;
    if constexpr (EM == 3) {
      float4 fv = {v0, v1, v2, v3};
      *(float4*)(Cf + (size_t)e * 128 + ro) = fv;
    }
  }
  if constexpr (EM != 3) {
    __shared__ double red[256];
    red[tid] = dsum; __syncthreads();
    for (int s = 128; s > 0; s >>= 1) { if (tid < s) red[tid] += red[tid + s]; __syncthreads(); }
    if (tid == 0) partials[2 * blockIdx.x] = red[0];
    __syncthreads();
    red[tid] = dsq; __syncthreads();
    for (int s = 128; s > 0; s >>= 1) { if (tid < s) red[tid] += red[tid + s]; __syncthreads(); }
    if (tid == 0) partials[2 * blockIdx.x + 1] = red[0];
  }
}

// ================= bf16 MFMA node GEMM, col-tiled: C[n][*] = X[n][K] @ A[*][K]^T =================
// grid (N/64, NOUTtot/64); each y-block does 64 output cols.
// OM 0: bf16 out; 1: +bias elu bf16 out; 2: +bias f32 out; 3: f32 out; 4: resid[n][128] += 0.1*v
// XSPLIT: K rows 0..255 from X (stride 256), 256.. from X2 (stride 128)
// XT: tanh((x-m)*r) on X load (params inline); STATS: write f64 partials
template<int K, bool XSPLIT, bool XT, bool STATS, int OM>
__global__ __launch_bounds__(256) void nmfma_k(
    const __bf16* __restrict__ A, const __bf16* __restrict__ X,
    const __bf16* __restrict__ X2,
    __bf16* __restrict__ Cb, float* __restrict__ Cf, float* __restrict__ resid,
    const float* __restrict__ bias, int nout_stride,
    double* __restrict__ partials,
    const double* __restrict__ pp, int pnblk, double pM)
{
  float p0 = 0.f, p1 = 0.f;
  if constexpr (XT) { float2 pr = params_inline(pp, pnblk, pM, 0); p0 = pr.x; p1 = pr.y; }
  const int tid = threadIdx.x;
  const int wv = tid >> 6, lane = tid & 63;
  const int l15 = lane & 15, ks = lane >> 4;
  const int n = blockIdx.x * 64 + wv * 16 + l15;
  constexpr int KK = K / 32;
  bf16x8_t bq[KK];
  if constexpr (XSPLIT) {
    const __bf16* xr  = X  + (size_t)n * 256 + ks * 8;
    const __bf16* xr2 = X2 + (size_t)n * 128 + ks * 8;
#pragma unroll
    for (int kk = 0; kk < 8; ++kk) bq[kk] = *(const bf16x8_t*)(xr + kk * 32);
#pragma unroll
    for (int kk = 8; kk < KK; ++kk) bq[kk] = *(const bf16x8_t*)(xr2 + (kk - 8) * 32);
  } else {
    const __bf16* xr = X + (size_t)n * K + ks * 8;
#pragma unroll
    for (int kk = 0; kk < KK; ++kk) {
      bf16x8_t v = *(const bf16x8_t*)(xr + kk * 32);
      if constexpr (XT) {
#pragma unroll
        for (int j = 0; j < 8; ++j) v[j] = (__bf16)tanhf(((float)v[j] - p0) * p1);
      }
      bq[kk] = v;
    }
  }
  double dsum = 0.0, dsq = 0.0;
  const int ob0 = blockIdx.y * 4;
#pragma unroll
  for (int obb = 0; obb < 4; ++obb) {
    const int ob = ob0 + obb;
    f32x4_t acc = {0.f, 0.f, 0.f, 0.f};
    const __bf16* ar = A + (size_t)(ob * 16 + l15) * K + ks * 8;
#pragma unroll
    for (int kk = 0; kk < KK; ++kk) {
      bf16x8_t a = *(const bf16x8_t*)(ar + kk * 32);
      acc = __builtin_amdgcn_mfma_f32_16x16x32_bf16(a, bq[kk], acc, 0, 0, 0);
    }
    const int ro = ob * 16 + ks * 4;
    float v[4] = {acc[0], acc[1], acc[2], acc[3]};
    if constexpr (OM == 1 || OM == 2) {
#pragma unroll
      for (int r = 0; r < 4; ++r) v[r] += bias[ro + r];
    }
    if constexpr (OM == 1) {
#pragma unroll
      for (int r = 0; r < 4; ++r) v[r] = v[r] > 0.f ? v[r] : expm1f(v[r]);
    }
    if constexpr (STATS) {
#pragma unroll
      for (int r = 0; r < 4; ++r) { dsum += (double)v[r]; dsq += (double)v[r] * (double)v[r]; }
    }
    if constexpr (OM == 4) {
      float4* rp = (float4*)&resid[(size_t)n * 128 + ro];
      float4 rr = *rp;
      rr.x += 0.1f * v[0]; rr.y += 0.1f * v[1]; rr.z += 0.1f * v[2]; rr.w += 0.1f * v[3];
      *rp = rr;
    } else if constexpr (OM == 2 || OM == 3) {
      float4 fv = {v[0], v[1], v[2], v[3]};
      *(float4*)(Cf + (size_t)n * nout_stride + ro) = fv;
    } else {
      bf16x4_t bv;
      bv[0] = (__bf16)v[0]; bv[1] = (__bf16)v[1]; bv[2] = (__bf16)v[2]; bv[3] = (__bf16)v[3];
      *(bf16x4_t*)(Cb + (size_t)n * nout_stride + ro) = bv;
    }
  }
  if constexpr (STATS) {
    __shared__ double red[256];
    const int pid = blockIdx.y * gridDim.x + blockIdx.x;
    red[tid] = dsum; __syncthreads();
    for (int s = 128; s > 0; s >>= 1) { if (tid < s) red[tid] += red[tid + s]; __syncthreads(); }
    if (tid == 0) partials[2 * pid] = red[0];
    __syncthreads();
    red[tid] = dsq; __syncthreads();
    for (int s = 128; s > 0; s >>= 1) { if (tid < s) red[tid] += red[tid + s]; __syncthreads(); }
    if (tid == 0) partials[2 * pid + 1] = red[0];
  }
}

// ================= dstat via MFMA Gram matrix, upper triangle =================
__global__ __launch_bounds__(256) void dstat_k(
    const __bf16* __restrict__ fT, const float* __restrict__ s,
    double* __restrict__ partials)
{
  const int tid = threadIdx.x;
  const int pid = blockIdx.y * gridDim.x + blockIdx.x;
  const int j0 = blockIdx.x * 64, i0 = blockIdx.y * 64;
  if (j0 < i0) { if (tid < 2) partials[2 * pid + tid] = 0.0; return; }
  const double wgt = (j0 > i0) ? 2.0 : 1.0;
  const int wv = tid >> 6, lane = tid & 63, l15 = lane & 15, ks = lane >> 4;
  const int irow = i0 + wv * 16 + l15;
  bf16x8_t aq[4];
  const __bf16* ar = fT + (size_t)irow * 128 + ks * 8;
#pragma unroll
  for (int kk = 0; kk < 4; ++kk) aq[kk] = *(const bf16x8_t*)(ar + kk * 32);
  float si[4];
#pragma unroll
  for (int r = 0; r < 4; ++r) si[r] = s[i0 + wv * 16 + ks * 4 + r];
  double dsum = 0.0, dsq = 0.0;
#pragma unroll
  for (int jb = 0; jb < 4; ++jb) {
    const int jcol = j0 + jb * 16 + l15;
    const __bf16* br = fT + (size_t)jcol * 128 + ks * 8;
    f32x4_t acc = {0.f, 0.f, 0.f, 0.f};
#pragma unroll
    for (int kk = 0; kk < 4; ++kk) {
      bf16x8_t b = *(const bf16x8_t*)(br + kk * 32);
      acc = __builtin_amdgcn_mfma_f32_16x16x32_bf16(aq[kk], b, acc, 0, 0, 0);
    }
    const float sj = s[jcol];
#pragma unroll
    for (int r = 0; r < 4; ++r) {
      float d = si[r] + sj - 2.f * acc[r];
      d = d > 0.f ? d : 0.f;
      dsum += (double)d; dsq += (double)d * (double)d;
    }
  }
  dsum *= wgt; dsq *= wgt;
  __shared__ double red[256];
  red[tid] = dsum; __syncthreads();
  for (int s2 = 128; s2 > 0; s2 >>= 1) { if (tid < s2) red[tid] += red[tid + s2]; __syncthreads(); }
  if (tid == 0) partials[2 * pid] = red[0];
  __syncthreads();
  red[tid] = dsq; __syncthreads();
  for (int s2 = 128; s2 > 0; s2 >>= 1) { if (tid < s2) red[tid] += red[tid + s2]; __syncthreads(); }
  if (tid == 0) partials[2 * pid + 1] = red[0];
}

// ================= bcvt: xnN f32 [n][128] -> bf16 + per-node sqnorm =================
__global__ __launch_bounds__(256) void bcvt_k(const float* __restrict__ xnN,
                                              __bf16* __restrict__ xnNb,
                                              float* __restrict__ sbuf)
{
  const int n = blockIdx.x * 64 + (threadIdx.x >> 2);
  const int q = (threadIdx.x & 3) * 32;
  const float* src = xnN + (size_t)n * 128 + q;
  __bf16* dst = xnNb + (size_t)n * 128 + q;
  float ss = 0.f;
#pragma unroll
  for (int j = 0; j < 8; ++j) {
    float4 v = *(const float4*)(src + 4 * j);
    ss += v.x * v.x + v.y * v.y + v.z * v.z + v.w * v.w;
    bf16x4_t b;
    b[0] = (__bf16)v.x; b[1] = (__bf16)v.y; b[2] = (__bf16)v.z; b[3] = (__bf16)v.w;
    *(bf16x4_t*)(dst + 4 * j) = b;
  }
  ss += __shfl_xor(ss, 1);
  ss += __shfl_xor(ss, 2);
  if ((threadIdx.x & 3) == 0) sbuf[n] = ss;
}

// ================= transpose xe_in [64][E] f32 -> [E][64] bf16 =================
__global__ __launch_bounds__(256) void etrans_k(const float* __restrict__ xe_in,
                                                __bf16* __restrict__ xeT64)
{
  __shared__ float t[64][65];
  const int e0 = blockIdx.x * 64;
  const int tx = threadIdx.x & 63, tw = threadIdx.x >> 6;
  for (int c = tw; c < 64; c += 4)
    t[tx][c] = xe_in[(size_t)c * NEDGES + e0 + tx];
  __syncthreads();
  const int el = threadIdx.x >> 2, c0 = (threadIdx.x & 3) * 16;
  for (int q = 0; q < 4; ++q) {
    int c = c0 + q * 4;
    bf16x4_t b;
    b[0] = (__bf16)t[el][c];     b[1] = (__bf16)t[el][c + 1];
    b[2] = (__bf16)t[el][c + 2]; b[3] = (__bf16)t[el][c + 3];
    *(bf16x4_t*)&xeT64[(size_t)(e0 + el) * 64 + c] = b;
  }
}

// ================= per-edge weight from node-major xnN f32 =================
__global__ __launch_bounds__(256) void edge_w_k(
    const float* __restrict__ xnN, const float* __restrict__ s,
    const int* __restrict__ iI, const int* __restrict__ jJ,
    const double* __restrict__ pp, float* __restrict__ w)
{
  float2 pr = params_inline(pp, 4096, (double)NNODES * (double)NNODES, 1);
  const float factor = pr.x;
  int e = blockIdx.x * 256 + threadIdx.x;
  int a = iI[e], b = jJ[e];
  const float4* pa = (const float4*)(xnN + (size_t)a * CH);
  const float4* pb = (const float4*)(xnN + (size_t)b * CH);
  float g = 0.f;
#pragma unroll
  for (int q = 0; q < CH / 4; ++q) {
    float4 u = pa[q], v = pb[q];
    g = fmaf(u.x, v.x, g); g = fmaf(u.y, v.y, g);
    g = fmaf(u.z, v.z, g); g = fmaf(u.w, v.w, g);
  }
  float d = s[a] + s[b] - 2.f * g;
  d = d > 0.f ? d : 0.f;
  w[e] = expf(factor * d);
}

// ================= weight conversion to bf16 (one launch) =================
__global__ void wcvt_k(const float* __restrict__ K1E, const float* __restrict__ K2E,
                       const float* __restrict__ KE1, const float* __restrict__ KE2,
                       const float* __restrict__ KNc, const float* __restrict__ W1,
                       const float* __restrict__ W2, const float* __restrict__ KN1,
                       const float* __restrict__ KN2,
                       __bf16* __restrict__ K1Eb, __bf16* __restrict__ K2Eb,
                       __bf16* __restrict__ KE1b, __bf16* __restrict__ KE2b,
                       __bf16* __restrict__ KNcb, __bf16* __restrict__ W1b,
                       __bf16* __restrict__ W2b, __bf16* __restrict__ KN1b,
                       __bf16* __restrict__ KN2b, __bf16* __restrict__ a1a2b)
{
  int id = blockIdx.x * 256 + threadIdx.x;
  if (id < 8192) { K1Eb[id] = (__bf16)K1E[id]; return; }
  id -= 8192;
  if (id < 16384) { K2Eb[id] = (__bf16)K2E[id]; return; }
  id -= 16384;
  if (id < 65536) {
    int l = id >> 14, rem = id & 16383, r = rem >> 7, c = rem & 127;
    KE1b[id] = (__bf16)KE1[(size_t)l * 49152 + r * 384 + 128 + c];
    return;
  }
  id -= 65536;
  if (id < 65536) { KE2b[id] = (__bf16)KE2[id]; return; }
  id -= 65536;
  if (id < 16384) { KNcb[id] = (__bf16)KNc[id]; return; }
  id -= 16384;
  if (id < 32768) { W1b[id] = (__bf16)W1[id]; return; }
  id -= 32768;
  if (id < 262144) { W2b[id] = (__bf16)W2[id]; return; }
  id -= 262144;
  if (id < 196608) { KN1b[id] = (__bf16)KN1[id]; return; }
  id -= 196608;
  if (id < 65536) { KN2b[id] = (__bf16)KN2[id]; return; }
  id -= 65536;
  if (id < 131072) {
    int l = id >> 15, rem = id & 32767, r = rem >> 7, c = rem & 127;
    int o = r & 127;
    float k1 = KE1[(size_t)l * 49152 + o * 384 + c];
    float k3 = KE1[(size_t)l * 49152 + o * 384 + 256 + c];
    a1a2b[id] = (__bf16)((r < 128) ? (0.5f * k1 + k3) : (0.5f * k1 - k3));
    return;
  }
}

// ================= lnres: xe += 0.1*ln(eB); write f32 + bf16 =================
__global__ __launch_bounds__(256) void lnres_k(
    const __bf16* __restrict__ eBT, float* __restrict__ xe_em,
    __bf16* __restrict__ xeT, const double* __restrict__ pp)
{
  float2 pr = params_inline(pp, 1024, (double)CH * NEDGES, 0);
  const float m = pr.x, r = pr.y;
  const size_t base = (size_t)blockIdx.x * (256 * 32);
  for (int it = 0; it < 4; ++it) {
    size_t i = base + (size_t)it * 2048 + (size_t)threadIdx.x * 8;
    bf16x8_t b = *(const bf16x8_t*)(eBT + i);
    float4 x0 = *(const float4*)(xe_em + i);
    float4 x1 = *(const float4*)(xe_em + i + 4);
    float nv[8];
    nv[0] = x0.x + 0.1f * (((float)b[0] - m) * r);
    nv[1] = x0.y + 0.1f * (((float)b[1] - m) * r);
    nv[2] = x0.z + 0.1f * (((float)b[2] - m) * r);
    nv[3] = x0.w + 0.1f * (((float)b[3] - m) * r);
    nv[4] = x1.x + 0.1f * (((float)b[4] - m) * r);
    nv[5] = x1.y + 0.1f * (((float)b[5] - m) * r);
    nv[6] = x1.z + 0.1f * (((float)b[6] - m) * r);
    nv[7] = x1.w + 0.1f * (((float)b[7] - m) * r);
    float4 o0 = {nv[0], nv[1], nv[2], nv[3]};
    float4 o1 = {nv[4], nv[5], nv[6], nv[7]};
    *(float4*)(xe_em + i) = o0;
    *(float4*)(xe_em + i + 4) = o1;
    bf16x8_t ob;
#pragma unroll
    for (int j = 0; j < 8; ++j) ob[j] = (__bf16)nv[j];
    *(bf16x8_t*)(xeT + i) = ob;
  }
}

// ================= CSR build =================
__global__ void hist_k(const int* __restrict__ iI, const int* __restrict__ jJ,
                       int* __restrict__ cnt)
{
  int e = blockIdx.x * 256 + threadIdx.x;
  atomicAdd(&cnt[iI[e]], 1);
  atomicAdd(&cnt[jJ[e]], 1);
}

__global__ __launch_bounds__(1024) void scan_k(const int* __restrict__ cnt,
                                               int* __restrict__ offs,
                                               int* __restrict__ cursor)
{
  __shared__ int tmp[1024];
  const int tid = threadIdx.x;
  int4 v = *(const int4*)&cnt[tid * 4];
  int s = v.x + v.y + v.z + v.w;
  tmp[tid] = s; __syncthreads();
  for (int d = 1; d < 1024; d <<= 1) {
    int t = (tid >= d) ? tmp[tid - d] : 0;
    __syncthreads();
    tmp[tid] += t;
    __syncthreads();
  }
  int base = tmp[tid] - s;
  int4 o = {base, base + v.x, base + v.x + v.y, base + v.x + v.y + v.z};
  *(int4*)&offs[tid * 4] = o;
  *(int4*)&cursor[tid * 4] = o;
  if (tid == 1023) offs[4096] = tmp[1023];
}

__global__ void fill_k(const int* __restrict__ iI, const int* __restrict__ jJ,
                       int* __restrict__ cursor, int* __restrict__ list)
{
  int e = blockIdx.x * 256 + threadIdx.x;
  int p1 = atomicAdd(&cursor[iI[e]], 1);
  list[p1] = e;
  int p2 = atomicAdd(&cursor[jJ[e]], 1);
  list[p2] = e | 0x80000000;
}

// ================= gather: ave/div per node -> catb bf16 [n][256] =================
__global__ __launch_bounds__(256) void gather_k(
    const float* __restrict__ xe_em, const float* __restrict__ w,
    const int* __restrict__ offs, const int* __restrict__ list,
    __bf16* __restrict__ catb)
{
  const int wv = threadIdx.x >> 6, lane = threadIdx.x & 63;
  const int n = blockIdx.x * 4 + wv;
  const int k0 = offs[n], k1 = offs[n + 1];
  float s1a = 0.f, s1b = 0.f, s2a = 0.f, s2b = 0.f;
  for (int k = k0; k < k1; ++k) {
    int enc = list[k];
    int e = enc & 0x7fffffff;
    float we = w[e];
    float va = xe_em[(size_t)e * 128 + lane] * we;
    float vb = xe_em[(size_t)e * 128 + 64 + lane] * we;
    if (enc >= 0) { s1a += va; s1b += vb; }
    else          { s2a += va; s2b += vb; }
  }
  __bf16* row = catb + (size_t)n * 256;
  row[lane]       = (__bf16)(0.5f * (s1a + s2a));
  row[64 + lane]  = (__bf16)(0.5f * (s1b + s2b));
  row[128 + lane] = (__bf16)(s1a - s2a);
  row[192 + lane] = (__bf16)(s1b - s2b);
}

// ================= log_softmax rows of [N][1024] =================
__global__ __launch_bounds__(256) void logsoftmax_k(float* __restrict__ out)
{
  __shared__ float red[256];
  const int n = blockIdx.x, tid = threadIdx.x;
  float* row = out + (size_t)n * 1024;
  float v[4];
  float mx = -1e30f;
#pragma unroll
  for (int l = 0; l < 4; ++l) { v[l] = row[tid + 256 * l]; mx = fmaxf(mx, v[l]); }
  red[tid] = mx; __syncthreads();
  for (int s = 128; s > 0; s >>= 1) { if (tid < s) red[tid] = fmaxf(red[tid], red[tid + s]); __syncthreads(); }
  float m = red[0]; __syncthreads();
  float se = 0.f;
#pragma unroll
  for (int l = 0; l < 4; ++l) se += expf(v[l] - m);
  red[tid] = se; __syncthreads();
  for (int s = 128; s > 0; s >>= 1) { if (tid < s) red[tid] += red[tid + s]; __syncthreads(); }
  float L = m + logf(red[0]);
#pragma unroll
  for (int l = 0; l < 4; ++l) row[tid + 256 * l] = v[l] - L;
}

extern "C" void kernel_launch(void* const* d_in, const int* in_sizes, int n_in,
                              void* d_out, int out_size, void* d_ws, size_t ws_size,
                              hipStream_t stream)
{
  (void)in_sizes; (void)n_in; (void)out_size; (void)ws_size;
  const float* xn_in = (const float*)d_in[0];
  const float* xe_in = (const float*)d_in[1];
  const int*   iI    = (const int*)d_in[2];
  const int*   jJ    = (const int*)d_in[3];
  const float* K1N   = (const float*)d_in[4];
  const float* K2N   = (const float*)d_in[5];
  const float* K1E   = (const float*)d_in[6];
  const float* K2E   = (const float*)d_in[7];
  const float* KNc   = (const float*)d_in[8];
  const float* KE1   = (const float*)d_in[9];
  const float* KE2   = (const float*)d_in[10];
  const float* KN1   = (const float*)d_in[11];
  const float* KN2   = (const float*)d_in[12];
  const float* W1    = (const float*)d_in[13];
  const float* b1    = (const float*)d_in[14];
  const float* W2    = (const float*)d_in[15];
  const float* b2    = (const float*)d_in[16];
  float* out = (float*)d_out;

  float* ws = (float*)d_ws;
  size_t off = 0;
  auto alloc = [&](size_t n) { size_t o = off; off += (n + 63) & ~(size_t)63; return o; };
  float* xnN   = ws + alloc((size_t)NNODES * CH);           // f32 node-major master
  float* xe_em = ws + alloc((size_t)NEDGES * CH);           // f32 residual, edge-major
  __bf16* xeT  = (__bf16*)(ws + alloc((size_t)NEDGES * CH / 2));
  __bf16* eAT  = (__bf16*)(ws + alloc((size_t)NEDGES * CH / 2));
  __bf16* eBT  = (__bf16*)(ws + alloc((size_t)NEDGES * CH / 2));
  float* nA    = ws + alloc((size_t)CH * NNODES);           // opening ch-major temp
  float* sbuf  = ws + alloc(NNODES);
  float* wbuf  = ws + alloc(NEDGES);
  float* UV    = ws + alloc((size_t)NNODES * 256);
  __bf16* xnNb = (__bf16*)(ws + alloc((size_t)NNODES * CH / 2));
  __bf16* catb = (__bf16*)(ws + alloc((size_t)NNODES * 256 / 2));
  __bf16* nAb  = (__bf16*)(ws + alloc((size_t)NNODES * CH / 2));
  __bf16* zb   = (__bf16*)(ws + alloc((size_t)NNODES * CH / 2));
  __bf16* l1bb = (__bf16*)(ws + alloc((size_t)NNODES * 256 / 2));
  __bf16* K1Eb = (__bf16*)(ws + alloc(8192 / 2));
  __bf16* K2Eb = (__bf16*)(ws + alloc(16384 / 2));
  __bf16* KE1b = (__bf16*)(ws + alloc(65536 / 2));
  __bf16* KE2b = (__bf16*)(ws + alloc(65536 / 2));
  __bf16* KNcb = (__bf16*)(ws + alloc(16384 / 2));
  __bf16* W1b  = (__bf16*)(ws + alloc(32768 / 2));
  __bf16* W2b  = (__bf16*)(ws + alloc(262144 / 2));
  __bf16* KN1b = (__bf16*)(ws + alloc(196608 / 2));
  __bf16* KN2b = (__bf16*)(ws + alloc(65536 / 2));
  __bf16* a1a2b= (__bf16*)(ws + alloc(131072 / 2));
  int* csr_cnt    = (int*)(ws + alloc(4096));
  int* csr_offs   = (int*)(ws + alloc(4160));
  int* csr_cursor = (int*)(ws + alloc(4096));
  int* csr_list   = (int*)(ws + alloc(2 * NEDGES));
  double* pA = (double*)(ws + alloc((size_t)4096 * 2 * 2));
  double* pB = (double*)(ws + alloc((size_t)4096 * 2 * 2));
  // alias: opening-only [E][64] bf16 input shares eBT (first written layer-0 pass 2)
  __bf16* xeT64 = eBT;

  const __bf16* BNUL = nullptr;
  const float* NUL = nullptr;
  const int* NULI = nullptr;
  const double* DNUL = nullptr;

  // ---- weight conversion + CSR build (once) ----
  wcvt_k<<<3360, 256, 0, stream>>>(K1E, K2E, KE1, KE2, KNc, W1, W2, KN1, KN2,
                                   K1Eb, K2Eb, KE1b, KE2b, KNcb, W1b, W2b, KN1b, KN2b, a1a2b);
  hipMemsetAsync(csr_cnt, 0, 4096 * sizeof(int), stream);
  hist_k<<<NEDGES / 256, 256, 0, stream>>>(iI, jJ, csr_cnt);
  scan_k<<<1, 1024, 0, stream>>>(csr_cnt, csr_offs, csr_cursor);
  fill_k<<<NEDGES / 256, 256, 0, stream>>>(iI, jJ, csr_cursor, csr_list);

  // ---- opening: node double layer (f32), ends node-major ----
  gemm_k<1, false><<<dim3(64, 2), 256, 0, stream>>>(K1N, 64, xn_in, nA, 64, NNODES,
      pA, CH, DNUL, 0, 0.0);
  gemm_k<6, true><<<dim3(64, 2), 256, 0, stream>>>(K2N, 128, nA, xnN, 128, NNODES,
      nullptr, CH, pA, 128, (double)CH * NNODES);

  // ---- opening: edge double layer (MFMA) ----
  etrans_k<<<NEDGES / 64, 256, 0, stream>>>(xe_in, xeT64);
  emfma_k<0, 64><<<NEDGES / 64, 256, 0, stream>>>(K1Eb, xeT64, eAT, nullptr,
      pA, NUL, NUL, NULI, NULI, DNUL, 0, 0.0);
  emfma_k<3, 128><<<NEDGES / 64, 256, 0, stream>>>(K2Eb, eAT, xeT, xe_em,
      nullptr, NUL, NUL, NULI, NULI, pA, 1024, (double)CH * NEDGES);

  for (int i = 0; i < 4; ++i) {
    const __bf16* KE1bi = KE1b + (size_t)i * 128 * 128;
    const __bf16* KE2bi = KE2b + (size_t)i * 128 * 128;
    const __bf16* KN1bi = KN1b + (size_t)i * 128 * 384;
    const __bf16* KN2bi = KN2b + (size_t)i * 128 * 128;
    const __bf16* a1a2i = a1a2b + (size_t)i * 256 * 128;

    // D statistics -> factor = -2/std ; edge weights
    bcvt_k<<<NNODES / 64, 256, 0, stream>>>(xnN, xnNb, sbuf);
    dstat_k<<<dim3(64, 64), 256, 0, stream>>>(xnNb, sbuf, pA);
    edge_w_k<<<NEDGES / 256, 256, 0, stream>>>(xnN, sbuf, iI, jJ, pA, wbuf);

    // UV[n][256] = xnNb @ a1a2^T (f32 out)
    nmfma_k<128, false, false, false, 3><<<dim3(64, 4), 256, 0, stream>>>(
        a1a2i, xnNb, BNUL, nullptr, UV, nullptr, NUL, 256, nullptr, DNUL, 0, 0.0);
    // edge pass 1: eA = xe @ KE1^T + w*(U_I + V_J), stats -> pB
    emfma_k<2, 128><<<NEDGES / 64, 256, 0, stream>>>(KE1bi, xeT, eAT, nullptr,
        pB, UV, wbuf, iI, jJ, DNUL, 0, 0.0);
    // edge pass 2: eB = tanh(ln(eA)) @ KE2^T, params<-pB, stats -> pA
    emfma_k<1, 128><<<NEDGES / 64, 256, 0, stream>>>(KE2bi, eAT, eBT, nullptr,
        pA, NUL, NUL, NULI, NULI, pB, 1024, (double)CH * NEDGES);
    // xe += 0.1 * ln(eB), params<-pA
    lnres_k<<<1024, 256, 0, stream>>>(eBT, xe_em, xeT, pA);

    // node update: gather -> catb; KN1 (split cat+xn) stats -> pB; KN2 tanh + resid
    gather_k<<<NNODES / 4, 256, 0, stream>>>(xe_em, wbuf, csr_offs, csr_list, catb);
    nmfma_k<384, true, false, true, 0><<<dim3(64, 2), 256, 0, stream>>>(
        KN1bi, catb, xnNb, nAb, nullptr, nullptr, NUL, 128, pB, DNUL, 0, 0.0);
    nmfma_k<128, false, true, false, 4><<<dim3(64, 2), 256, 0, stream>>>(
        KN2bi, nAb, BNUL, nullptr, nullptr, xnN, NUL, 128, nullptr,
        pB, 128, (double)CH * NNODES);
  }

  // ---- close + MLP head (bf16 MFMA, node-major) ----
  bcvt_k<<<NNODES / 64, 256, 0, stream>>>(xnN, xnNb, sbuf);
  nmfma_k<128, false, false, false, 0><<<dim3(64, 2), 256, 0, stream>>>(
      KNcb, xnNb, BNUL, zb, nullptr, nullptr, NUL, 128, nullptr, DNUL, 0, 0.0);
  nmfma_k<128, false, false, false, 1><<<dim3(64, 4), 256, 0, stream>>>(
      W1b, zb, BNUL, l1bb, nullptr, nullptr, b1, 256, nullptr, DNUL, 0, 0.0);
  nmfma_k<256, false, false, false, 2><<<dim3(64, 16), 256, 0, stream>>>(
      W2b, l1bb, BNUL, nullptr, out, nullptr, b2, 1024, nullptr, DNUL, 0, 0.0);
  logsoftmax_k<<<NNODES, 256, 0, stream>>>(out);
}

// Round 6
// 861.889 us; speedup vs baseline: 2.9671x; 1.0521x over previous
//
#include <hip/hip_runtime.h>

#define NNODES 4096
#define NEDGES 65536
#define CH 128

typedef __bf16 bf16x8_t __attribute__((ext_vector_type(8)));
typedef __bf16 bf16x4_t __attribute__((ext_vector_type(4)));
typedef __bf16 bf16x2_t __attribute__((ext_vector_type(2)));
typedef float f32x4_t __attribute__((ext_vector_type(4)));

// ============ inline params: reduce producer partials -> (mean,rstd) or (factor,0) ============
__device__ __forceinline__ float2 params_inline(const double* __restrict__ pp,
                                                int nblk, double M, int type)
{
  __shared__ double rs[256];
  __shared__ double rq[256];
  __shared__ float pr[2];
  const int tid = threadIdx.x;
  double s = 0.0, q = 0.0;
  for (int i = tid; i < nblk; i += 256) { s += pp[2 * i]; q += pp[2 * i + 1]; }
  rs[tid] = s; rq[tid] = q; __syncthreads();
  for (int st = 128; st > 0; st >>= 1) {
    if (tid < st) { rs[tid] += rs[tid + st]; rq[tid] += rq[tid + st]; }
    __syncthreads();
  }
  if (tid == 0) {
    double S = rs[0], Q = rq[0];
    if (type == 0) {
      double mean = S / M;
      double var = Q / M - mean * mean;
      if (var < 0.0) var = 0.0;
      pr[0] = (float)mean;
      pr[1] = (float)(1.0 / sqrt(var + 1e-5));
    } else {
      double var = (Q - S * S / M) / (M - 1.0);
      if (var < 1e-30) var = 1e-30;
      pr[0] = (float)(-2.0 / sqrt(var));
      pr[1] = 0.f;
    }
  }
  __syncthreads();
  return {pr[0], pr[1]};
}

// ================= bf16 MFMA edge GEMM: C[E][128] = X[E][K] @ A[128][K]^T =================
// EM 0: plain, stats                 EM 2: + w*(U[I]+V[J]) (bf16 UV), stats
// EM 1: tanh-on-load, stats          EM 3: tanh-on-load, no stats, bf16 store only
template<int EM, int K>
__global__ __launch_bounds__(256) void emfma_k(
    const __bf16* __restrict__ A, const __bf16* __restrict__ X,
    __bf16* __restrict__ Cb,
    double* __restrict__ partials,
    const __bf16* __restrict__ UVb, const float* __restrict__ wg,
    const int* __restrict__ iIe, const int* __restrict__ jIe,
    const double* __restrict__ pp, int pnblk, double pM)
{
  float p0 = 0.f, p1 = 0.f;
  if constexpr (EM == 1 || EM == 3) {
    float2 pr = params_inline(pp, pnblk, pM, 0); p0 = pr.x; p1 = pr.y;
  }
  const int tid = threadIdx.x;
  const int wv = tid >> 6, lane = tid & 63;
  const int l15 = lane & 15, ks = lane >> 4;
  const int e = blockIdx.x * 64 + wv * 16 + l15;
  constexpr int KK = K / 32;
  bf16x8_t bq[KK];
  {
    const __bf16* xr = X + (size_t)e * K + ks * 8;
#pragma unroll
    for (int kk = 0; kk < KK; ++kk) {
      bf16x8_t v = *(const bf16x8_t*)(xr + kk * 32);
      if constexpr (EM == 1 || EM == 3) {
#pragma unroll
        for (int j = 0; j < 8; ++j) v[j] = (__bf16)tanhf(((float)v[j] - p0) * p1);
      }
      bq[kk] = v;
    }
  }
  float we = 0.f; int ie = 0, je = 0;
  if constexpr (EM == 2) { we = wg[e]; ie = iIe[e]; je = jIe[e]; }
  double dsum = 0.0, dsq = 0.0;
#pragma unroll
  for (int ob = 0; ob < 8; ++ob) {
    f32x4_t acc = {0.f, 0.f, 0.f, 0.f};
    const __bf16* ar = A + (size_t)(ob * 16 + l15) * K + ks * 8;
#pragma unroll
    for (int kk = 0; kk < KK; ++kk) {
      bf16x8_t a = *(const bf16x8_t*)(ar + kk * 32);
      acc = __builtin_amdgcn_mfma_f32_16x16x32_bf16(a, bq[kk], acc, 0, 0, 0);
    }
    const int ro = ob * 16 + ks * 4;
    float v0 = acc[0], v1 = acc[1], v2 = acc[2], v3 = acc[3];
    if constexpr (EM == 2) {
      bf16x4_t u4 = *(const bf16x4_t*)&UVb[(size_t)ie * 256 + ro];
      bf16x4_t w4 = *(const bf16x4_t*)&UVb[(size_t)je * 256 + 128 + ro];
      v0 += we * ((float)u4[0] + (float)w4[0]);
      v1 += we * ((float)u4[1] + (float)w4[1]);
      v2 += we * ((float)u4[2] + (float)w4[2]);
      v3 += we * ((float)u4[3] + (float)w4[3]);
    }
    if constexpr (EM != 3) {
      dsum += (double)v0 + (double)v1 + (double)v2 + (double)v3;
      dsq  += (double)v0 * v0 + (double)v1 * v1 + (double)v2 * v2 + (double)v3 * v3;
    }
    bf16x4_t bv;
    bv[0] = (__bf16)v0; bv[1] = (__bf16)v1; bv[2] = (__bf16)v2; bv[3] = (__bf16)v3;
    *(bf16x4_t*)(Cb + (size_t)e * 128 + ro) = bv;
  }
  if constexpr (EM != 3) {
    __shared__ double red[256];
    red[tid] = dsum; __syncthreads();
    for (int s = 128; s > 0; s >>= 1) { if (tid < s) red[tid] += red[tid + s]; __syncthreads(); }
    if (tid == 0) partials[2 * blockIdx.x] = red[0];
    __syncthreads();
    red[tid] = dsq; __syncthreads();
    for (int s = 128; s > 0; s >>= 1) { if (tid < s) red[tid] += red[tid + s]; __syncthreads(); }
    if (tid == 0) partials[2 * blockIdx.x + 1] = red[0];
  }
}

// ================= bf16 MFMA node GEMM, col-tiled =================
// OM 0: bf16 out; 1: +bias elu bf16 out; 2: +bias f32 out; 3: f32 out; 4: resid[n][128] += 0.1*v
// XSPLIT: K 0..255 from X (stride 256), rest from X2 (stride 128)
// XT: tanh((x-m)*r) on X load; STATS: write f64 partials
template<int K, bool XSPLIT, bool XT, bool STATS, int OM>
__global__ __launch_bounds__(256) void nmfma_k(
    const __bf16* __restrict__ A, const __bf16* __restrict__ X,
    const __bf16* __restrict__ X2,
    __bf16* __restrict__ Cb, float* __restrict__ Cf, float* __restrict__ resid,
    const float* __restrict__ bias, int nout_stride,
    double* __restrict__ partials,
    const double* __restrict__ pp, int pnblk, double pM)
{
  float p0 = 0.f, p1 = 0.f;
  if constexpr (XT) { float2 pr = params_inline(pp, pnblk, pM, 0); p0 = pr.x; p1 = pr.y; }
  const int tid = threadIdx.x;
  const int wv = tid >> 6, lane = tid & 63;
  const int l15 = lane & 15, ks = lane >> 4;
  const int n = blockIdx.x * 64 + wv * 16 + l15;
  constexpr int KK = K / 32;
  bf16x8_t bq[KK];
  if constexpr (XSPLIT) {
    const __bf16* xr  = X  + (size_t)n * 256 + ks * 8;
    const __bf16* xr2 = X2 + (size_t)n * 128 + ks * 8;
#pragma unroll
    for (int kk = 0; kk < 8; ++kk) bq[kk] = *(const bf16x8_t*)(xr + kk * 32);
#pragma unroll
    for (int kk = 8; kk < KK; ++kk) bq[kk] = *(const bf16x8_t*)(xr2 + (kk - 8) * 32);
  } else {
    const __bf16* xr = X + (size_t)n * K + ks * 8;
#pragma unroll
    for (int kk = 0; kk < KK; ++kk) {
      bf16x8_t v = *(const bf16x8_t*)(xr + kk * 32);
      if constexpr (XT) {
#pragma unroll
        for (int j = 0; j < 8; ++j) v[j] = (__bf16)tanhf(((float)v[j] - p0) * p1);
      }
      bq[kk] = v;
    }
  }
  double dsum = 0.0, dsq = 0.0;
  const int ob0 = blockIdx.y * 4;
#pragma unroll
  for (int obb = 0; obb < 4; ++obb) {
    const int ob = ob0 + obb;
    f32x4_t acc = {0.f, 0.f, 0.f, 0.f};
    const __bf16* ar = A + (size_t)(ob * 16 + l15) * K + ks * 8;
#pragma unroll
    for (int kk = 0; kk < KK; ++kk) {
      bf16x8_t a = *(const bf16x8_t*)(ar + kk * 32);
      acc = __builtin_amdgcn_mfma_f32_16x16x32_bf16(a, bq[kk], acc, 0, 0, 0);
    }
    const int ro = ob * 16 + ks * 4;
    float v[4] = {acc[0], acc[1], acc[2], acc[3]};
    if constexpr (OM == 1 || OM == 2) {
#pragma unroll
      for (int r = 0; r < 4; ++r) v[r] += bias[ro + r];
    }
    if constexpr (OM == 1) {
#pragma unroll
      for (int r = 0; r < 4; ++r) v[r] = v[r] > 0.f ? v[r] : expm1f(v[r]);
    }
    if constexpr (STATS) {
#pragma unroll
      for (int r = 0; r < 4; ++r) { dsum += (double)v[r]; dsq += (double)v[r] * (double)v[r]; }
    }
    if constexpr (OM == 4) {
      float4* rp = (float4*)&resid[(size_t)n * 128 + ro];
      float4 rr = *rp;
      rr.x += 0.1f * v[0]; rr.y += 0.1f * v[1]; rr.z += 0.1f * v[2]; rr.w += 0.1f * v[3];
      *rp = rr;
    } else if constexpr (OM == 2 || OM == 3) {
      float4 fv = {v[0], v[1], v[2], v[3]};
      *(float4*)(Cf + (size_t)n * nout_stride + ro) = fv;
    } else {
      bf16x4_t bv;
      bv[0] = (__bf16)v[0]; bv[1] = (__bf16)v[1]; bv[2] = (__bf16)v[2]; bv[3] = (__bf16)v[3];
      *(bf16x4_t*)(Cb + (size_t)n * nout_stride + ro) = bv;
    }
  }
  if constexpr (STATS) {
    __shared__ double red[256];
    const int pid = blockIdx.y * gridDim.x + blockIdx.x;
    red[tid] = dsum; __syncthreads();
    for (int s = 128; s > 0; s >>= 1) { if (tid < s) red[tid] += red[tid + s]; __syncthreads(); }
    if (tid == 0) partials[2 * pid] = red[0];
    __syncthreads();
    red[tid] = dsq; __syncthreads();
    for (int s = 128; s > 0; s >>= 1) { if (tid < s) red[tid] += red[tid + s]; __syncthreads(); }
    if (tid == 0) partials[2 * pid + 1] = red[0];
  }
}

// ================= dstat via MFMA Gram matrix, upper triangle =================
__global__ __launch_bounds__(256) void dstat_k(
    const __bf16* __restrict__ fT, const float* __restrict__ s,
    double* __restrict__ partials)
{
  const int tid = threadIdx.x;
  const int pid = blockIdx.y * gridDim.x + blockIdx.x;
  const int j0 = blockIdx.x * 64, i0 = blockIdx.y * 64;
  if (j0 < i0) { if (tid < 2) partials[2 * pid + tid] = 0.0; return; }
  const double wgt = (j0 > i0) ? 2.0 : 1.0;
  const int wv = tid >> 6, lane = tid & 63, l15 = lane & 15, ks = lane >> 4;
  const int irow = i0 + wv * 16 + l15;
  bf16x8_t aq[4];
  const __bf16* ar = fT + (size_t)irow * 128 + ks * 8;
#pragma unroll
  for (int kk = 0; kk < 4; ++kk) aq[kk] = *(const bf16x8_t*)(ar + kk * 32);
  float si[4];
#pragma unroll
  for (int r = 0; r < 4; ++r) si[r] = s[i0 + wv * 16 + ks * 4 + r];
  double dsum = 0.0, dsq = 0.0;
#pragma unroll
  for (int jb = 0; jb < 4; ++jb) {
    const int jcol = j0 + jb * 16 + l15;
    const __bf16* br = fT + (size_t)jcol * 128 + ks * 8;
    f32x4_t acc = {0.f, 0.f, 0.f, 0.f};
#pragma unroll
    for (int kk = 0; kk < 4; ++kk) {
      bf16x8_t b = *(const bf16x8_t*)(br + kk * 32);
      acc = __builtin_amdgcn_mfma_f32_16x16x32_bf16(aq[kk], b, acc, 0, 0, 0);
    }
    const float sj = s[jcol];
#pragma unroll
    for (int r = 0; r < 4; ++r) {
      float d = si[r] + sj - 2.f * acc[r];
      d = d > 0.f ? d : 0.f;
      dsum += (double)d; dsq += (double)d * (double)d;
    }
  }
  dsum *= wgt; dsq *= wgt;
  __shared__ double red[256];
  red[tid] = dsum; __syncthreads();
  for (int s2 = 128; s2 > 0; s2 >>= 1) { if (tid < s2) red[tid] += red[tid + s2]; __syncthreads(); }
  if (tid == 0) partials[2 * pid] = red[0];
  __syncthreads();
  red[tid] = dsq; __syncthreads();
  for (int s2 = 128; s2 > 0; s2 >>= 1) { if (tid < s2) red[tid] += red[tid + s2]; __syncthreads(); }
  if (tid == 0) partials[2 * pid + 1] = red[0];
}

// ================= bcvt: xnN f32 [n][128] -> bf16 + per-node sqnorm (of bf16 values) =================
__global__ __launch_bounds__(256) void bcvt_k(const float* __restrict__ xnN,
                                              __bf16* __restrict__ xnNb,
                                              float* __restrict__ sbuf)
{
  const int n = blockIdx.x * 64 + (threadIdx.x >> 2);
  const int q = (threadIdx.x & 3) * 32;
  const float* src = xnN + (size_t)n * 128 + q;
  __bf16* dst = xnNb + (size_t)n * 128 + q;
  float ss = 0.f;
#pragma unroll
  for (int j = 0; j < 8; ++j) {
    float4 v = *(const float4*)(src + 4 * j);
    bf16x4_t b;
    b[0] = (__bf16)v.x; b[1] = (__bf16)v.y; b[2] = (__bf16)v.z; b[3] = (__bf16)v.w;
    float f0 = (float)b[0], f1 = (float)b[1], f2 = (float)b[2], f3 = (float)b[3];
    ss += f0 * f0 + f1 * f1 + f2 * f2 + f3 * f3;
    *(bf16x4_t*)(dst + 4 * j) = b;
  }
  ss += __shfl_xor(ss, 1);
  ss += __shfl_xor(ss, 2);
  if ((threadIdx.x & 3) == 0) sbuf[n] = ss;
}

// ================= transpose src [64][ncols] f32 -> dst [ncols][64] bf16 =================
__global__ __launch_bounds__(256) void etrans_k(const float* __restrict__ src,
                                                __bf16* __restrict__ dst, int ncols)
{
  __shared__ float t[64][65];
  const int e0 = blockIdx.x * 64;
  const int tx = threadIdx.x & 63, tw = threadIdx.x >> 6;
  for (int c = tw; c < 64; c += 4)
    t[tx][c] = src[(size_t)c * ncols + e0 + tx];
  __syncthreads();
  const int el = threadIdx.x >> 2, c0 = (threadIdx.x & 3) * 16;
  for (int q = 0; q < 4; ++q) {
    int c = c0 + q * 4;
    bf16x4_t b;
    b[0] = (__bf16)t[el][c];     b[1] = (__bf16)t[el][c + 1];
    b[2] = (__bf16)t[el][c + 2]; b[3] = (__bf16)t[el][c + 3];
    *(bf16x4_t*)&dst[(size_t)(e0 + el) * 64 + c] = b;
  }
}

// ================= per-edge weight from node-major xnNb bf16 =================
__global__ __launch_bounds__(256) void edge_w_k(
    const __bf16* __restrict__ xnNb, const float* __restrict__ s,
    const int* __restrict__ iI, const int* __restrict__ jJ,
    const double* __restrict__ pp, float* __restrict__ w)
{
  float2 pr = params_inline(pp, 4096, (double)NNODES * (double)NNODES, 1);
  const float factor = pr.x;
  int e = blockIdx.x * 256 + threadIdx.x;
  int a = iI[e], b = jJ[e];
  const bf16x8_t* pa = (const bf16x8_t*)(xnNb + (size_t)a * CH);
  const bf16x8_t* pb = (const bf16x8_t*)(xnNb + (size_t)b * CH);
  float g = 0.f;
#pragma unroll
  for (int q = 0; q < CH / 8; ++q) {
    bf16x8_t u = pa[q], v = pb[q];
#pragma unroll
    for (int j = 0; j < 8; ++j) g = fmaf((float)u[j], (float)v[j], g);
  }
  float d = s[a] + s[b] - 2.f * g;
  d = d > 0.f ? d : 0.f;
  w[e] = expf(factor * d);
}

// ================= weight conversion to bf16 (one launch) =================
__global__ void wcvt_k(const float* __restrict__ K1E, const float* __restrict__ K2E,
                       const float* __restrict__ KE1, const float* __restrict__ KE2,
                       const float* __restrict__ KNc, const float* __restrict__ W1,
                       const float* __restrict__ W2, const float* __restrict__ KN1,
                       const float* __restrict__ KN2, const float* __restrict__ K1N,
                       const float* __restrict__ K2N,
                       __bf16* __restrict__ K1Eb, __bf16* __restrict__ K2Eb,
                       __bf16* __restrict__ KE1b, __bf16* __restrict__ KE2b,
                       __bf16* __restrict__ KNcb, __bf16* __restrict__ W1b,
                       __bf16* __restrict__ W2b, __bf16* __restrict__ KN1b,
                       __bf16* __restrict__ KN2b, __bf16* __restrict__ a1a2b,
                       __bf16* __restrict__ K1Nb, __bf16* __restrict__ K2Nb)
{
  int id = blockIdx.x * 256 + threadIdx.x;
  if (id < 8192) { K1Eb[id] = (__bf16)K1E[id]; return; }
  id -= 8192;
  if (id < 16384) { K2Eb[id] = (__bf16)K2E[id]; return; }
  id -= 16384;
  if (id < 65536) {
    int l = id >> 14, rem = id & 16383, r = rem >> 7, c = rem & 127;
    KE1b[id] = (__bf16)KE1[(size_t)l * 49152 + r * 384 + 128 + c];
    return;
  }
  id -= 65536;
  if (id < 65536) { KE2b[id] = (__bf16)KE2[id]; return; }
  id -= 65536;
  if (id < 16384) { KNcb[id] = (__bf16)KNc[id]; return; }
  id -= 16384;
  if (id < 32768) { W1b[id] = (__bf16)W1[id]; return; }
  id -= 32768;
  if (id < 262144) { W2b[id] = (__bf16)W2[id]; return; }
  id -= 262144;
  if (id < 196608) { KN1b[id] = (__bf16)KN1[id]; return; }
  id -= 196608;
  if (id < 65536) { KN2b[id] = (__bf16)KN2[id]; return; }
  id -= 65536;
  if (id < 131072) {
    int l = id >> 15, rem = id & 32767, r = rem >> 7, c = rem & 127;
    int o = r & 127;
    float k1 = KE1[(size_t)l * 49152 + o * 384 + c];
    float k3 = KE1[(size_t)l * 49152 + o * 384 + 256 + c];
    a1a2b[id] = (__bf16)((r < 128) ? (0.5f * k1 + k3) : (0.5f * k1 - k3));
    return;
  }
  id -= 131072;
  if (id < 8192) { K1Nb[id] = (__bf16)K1N[id]; return; }
  id -= 8192;
  if (id < 16384) { K2Nb[id] = (__bf16)K2N[id]; return; }
}

// ================= lnres: xeT = bf16(f32(xeT) + 0.1*ln(eB)) =================
__global__ __launch_bounds__(256) void lnres_k(
    const __bf16* __restrict__ eBT, __bf16* __restrict__ xeT,
    const double* __restrict__ pp)
{
  float2 pr = params_inline(pp, 1024, (double)CH * NEDGES, 0);
  const float m = pr.x, r = pr.y;
  const size_t base = (size_t)blockIdx.x * (256 * 32);
  for (int it = 0; it < 4; ++it) {
    size_t i = base + (size_t)it * 2048 + (size_t)threadIdx.x * 8;
    bf16x8_t b = *(const bf16x8_t*)(eBT + i);
    bf16x8_t x = *(const bf16x8_t*)(xeT + i);
    bf16x8_t ob;
#pragma unroll
    for (int j = 0; j < 8; ++j)
      ob[j] = (__bf16)((float)x[j] + 0.1f * (((float)b[j] - m) * r));
    *(bf16x8_t*)(xeT + i) = ob;
  }
}

// ================= CSR build =================
__global__ void hist_k(const int* __restrict__ iI, const int* __restrict__ jJ,
                       int* __restrict__ cnt)
{
  int e = blockIdx.x * 256 + threadIdx.x;
  atomicAdd(&cnt[iI[e]], 1);
  atomicAdd(&cnt[jJ[e]], 1);
}

__global__ __launch_bounds__(1024) void scan_k(const int* __restrict__ cnt,
                                               int* __restrict__ offs,
                                               int* __restrict__ cursor)
{
  __shared__ int tmp[1024];
  const int tid = threadIdx.x;
  int4 v = *(const int4*)&cnt[tid * 4];
  int s = v.x + v.y + v.z + v.w;
  tmp[tid] = s; __syncthreads();
  for (int d = 1; d < 1024; d <<= 1) {
    int t = (tid >= d) ? tmp[tid - d] : 0;
    __syncthreads();
    tmp[tid] += t;
    __syncthreads();
  }
  int base = tmp[tid] - s;
  int4 o = {base, base + v.x, base + v.x + v.y, base + v.x + v.y + v.z};
  *(int4*)&offs[tid * 4] = o;
  *(int4*)&cursor[tid * 4] = o;
  if (tid == 1023) offs[4096] = tmp[1023];
}

__global__ void fill_k(const int* __restrict__ iI, const int* __restrict__ jJ,
                       int* __restrict__ cursor, int* __restrict__ list)
{
  int e = blockIdx.x * 256 + threadIdx.x;
  int p1 = atomicAdd(&cursor[iI[e]], 1);
  list[p1] = e;
  int p2 = atomicAdd(&cursor[jJ[e]], 1);
  list[p2] = e | 0x80000000;
}

// ================= gather: ave/div per node from bf16 xeT -> catb bf16 [n][256] =================
__global__ __launch_bounds__(256) void gather_k(
    const __bf16* __restrict__ xeT, const float* __restrict__ w,
    const int* __restrict__ offs, const int* __restrict__ list,
    __bf16* __restrict__ catb)
{
  const int wv = threadIdx.x >> 6, lane = threadIdx.x & 63;
  const int n = blockIdx.x * 4 + wv;
  const int k0 = offs[n], k1 = offs[n + 1];
  float s1a = 0.f, s1b = 0.f, s2a = 0.f, s2b = 0.f;
#pragma unroll 2
  for (int k = k0; k < k1; ++k) {
    int enc = list[k];
    int e = enc & 0x7fffffff;
    float we = w[e];
    bf16x2_t xv = *(const bf16x2_t*)&xeT[(size_t)e * 128 + lane * 2];
    float va = (float)xv[0] * we;
    float vb = (float)xv[1] * we;
    if (enc >= 0) { s1a += va; s1b += vb; }
    else          { s2a += va; s2b += vb; }
  }
  __bf16* row = catb + (size_t)n * 256;
  bf16x2_t av, dv;
  av[0] = (__bf16)(0.5f * (s1a + s2a)); av[1] = (__bf16)(0.5f * (s1b + s2b));
  dv[0] = (__bf16)(s1a - s2a);          dv[1] = (__bf16)(s1b - s2b);
  *(bf16x2_t*)&row[lane * 2] = av;
  *(bf16x2_t*)&row[128 + lane * 2] = dv;
}

// ================= log_softmax rows of [N][1024] =================
__global__ __launch_bounds__(256) void logsoftmax_k(float* __restrict__ out)
{
  __shared__ float red[256];
  const int n = blockIdx.x, tid = threadIdx.x;
  float* row = out + (size_t)n * 1024;
  float v[4];
  float mx = -1e30f;
#pragma unroll
  for (int l = 0; l < 4; ++l) { v[l] = row[tid + 256 * l]; mx = fmaxf(mx, v[l]); }
  red[tid] = mx; __syncthreads();
  for (int s = 128; s > 0; s >>= 1) { if (tid < s) red[tid] = fmaxf(red[tid], red[tid + s]); __syncthreads(); }
  float m = red[0]; __syncthreads();
  float se = 0.f;
#pragma unroll
  for (int l = 0; l < 4; ++l) se += expf(v[l] - m);
  red[tid] = se; __syncthreads();
  for (int s = 128; s > 0; s >>= 1) { if (tid < s) red[tid] += red[tid + s]; __syncthreads(); }
  float L = m + logf(red[0]);
#pragma unroll
  for (int l = 0; l < 4; ++l) row[tid + 256 * l] = v[l] - L;
}

extern "C" void kernel_launch(void* const* d_in, const int* in_sizes, int n_in,
                              void* d_out, int out_size, void* d_ws, size_t ws_size,
                              hipStream_t stream)
{
  (void)in_sizes; (void)n_in; (void)out_size; (void)ws_size;
  const float* xn_in = (const float*)d_in[0];
  const float* xe_in = (const float*)d_in[1];
  const int*   iI    = (const int*)d_in[2];
  const int*   jJ    = (const int*)d_in[3];
  const float* K1N   = (const float*)d_in[4];
  const float* K2N   = (const float*)d_in[5];
  const float* K1E   = (const float*)d_in[6];
  const float* K2E   = (const float*)d_in[7];
  const float* KNc   = (const float*)d_in[8];
  const float* KE1   = (const float*)d_in[9];
  const float* KE2   = (const float*)d_in[10];
  const float* KN1   = (const float*)d_in[11];
  const float* KN2   = (const float*)d_in[12];
  const float* W1    = (const float*)d_in[13];
  const float* b1    = (const float*)d_in[14];
  const float* W2    = (const float*)d_in[15];
  const float* b2    = (const float*)d_in[16];
  float* out = (float*)d_out;

  float* ws = (float*)d_ws;
  size_t off = 0;
  auto alloc = [&](size_t n) { size_t o = off; off += (n + 63) & ~(size_t)63; return o; };
  float* xnN   = ws + alloc((size_t)NNODES * CH);           // f32 node-major master
  __bf16* xeT  = (__bf16*)(ws + alloc((size_t)NEDGES * CH / 2));   // bf16 edge state
  __bf16* eAT  = (__bf16*)(ws + alloc((size_t)NEDGES * CH / 2));
  __bf16* eBT  = (__bf16*)(ws + alloc((size_t)NEDGES * CH / 2));
  float* sbuf  = ws + alloc(NNODES);
  float* wbuf  = ws + alloc(NEDGES);
  __bf16* UVb  = (__bf16*)(ws + alloc((size_t)NNODES * 256 / 2));
  __bf16* xnNb = (__bf16*)(ws + alloc((size_t)NNODES * CH / 2));
  __bf16* catb = (__bf16*)(ws + alloc((size_t)NNODES * 256 / 2));
  __bf16* nAb  = (__bf16*)(ws + alloc((size_t)NNODES * CH / 2));
  __bf16* zb   = (__bf16*)(ws + alloc((size_t)NNODES * CH / 2));
  __bf16* l1bb = (__bf16*)(ws + alloc((size_t)NNODES * 256 / 2));
  __bf16* K1Eb = (__bf16*)(ws + alloc(8192 / 2));
  __bf16* K2Eb = (__bf16*)(ws + alloc(16384 / 2));
  __bf16* KE1b = (__bf16*)(ws + alloc(65536 / 2));
  __bf16* KE2b = (__bf16*)(ws + alloc(65536 / 2));
  __bf16* KNcb = (__bf16*)(ws + alloc(16384 / 2));
  __bf16* W1b  = (__bf16*)(ws + alloc(32768 / 2));
  __bf16* W2b  = (__bf16*)(ws + alloc(262144 / 2));
  __bf16* KN1b = (__bf16*)(ws + alloc(196608 / 2));
  __bf16* KN2b = (__bf16*)(ws + alloc(65536 / 2));
  __bf16* a1a2b= (__bf16*)(ws + alloc(131072 / 2));
  __bf16* K1Nb = (__bf16*)(ws + alloc(8192 / 2));
  __bf16* K2Nb = (__bf16*)(ws + alloc(16384 / 2));
  int* csr_cnt    = (int*)(ws + alloc(4096));
  int* csr_offs   = (int*)(ws + alloc(4160));
  int* csr_cursor = (int*)(ws + alloc(4096));
  int* csr_list   = (int*)(ws + alloc(2 * NEDGES));
  double* pA = (double*)(ws + alloc((size_t)4096 * 2 * 2));
  double* pB = (double*)(ws + alloc((size_t)4096 * 2 * 2));
  // aliases (lifetimes disjoint): opening-only transposed inputs
  __bf16* xeT64  = eBT;               // [E][64], eBT first written layer-0 emfma<1>
  __bf16* xnT64b = UVb;               // [N][64], UVb first written layer-0 UV kernel

  const __bf16* BNUL = nullptr;
  const float* NUL = nullptr;
  const int* NULI = nullptr;
  const double* DNUL = nullptr;

  // ---- weight conversion + CSR build (once) ----
  wcvt_k<<<3456, 256, 0, stream>>>(K1E, K2E, KE1, KE2, KNc, W1, W2, KN1, KN2, K1N, K2N,
                                   K1Eb, K2Eb, KE1b, KE2b, KNcb, W1b, W2b, KN1b, KN2b,
                                   a1a2b, K1Nb, K2Nb);
  hipMemsetAsync(csr_cnt, 0, 4096 * sizeof(int), stream);
  hist_k<<<NEDGES / 256, 256, 0, stream>>>(iI, jJ, csr_cnt);
  scan_k<<<1, 1024, 0, stream>>>(csr_cnt, csr_offs, csr_cursor);
  fill_k<<<NEDGES / 256, 256, 0, stream>>>(iI, jJ, csr_cursor, csr_list);

  // ---- opening: node double layer (MFMA, node-major) ----
  etrans_k<<<NNODES / 64, 256, 0, stream>>>(xn_in, xnT64b, NNODES);
  nmfma_k<64, false, false, true, 0><<<dim3(64, 2), 256, 0, stream>>>(
      K1Nb, xnT64b, BNUL, nAb, nullptr, nullptr, NUL, 128, pA, DNUL, 0, 0.0);
  nmfma_k<128, false, true, false, 3><<<dim3(64, 2), 256, 0, stream>>>(
      K2Nb, nAb, BNUL, nullptr, xnN, nullptr, NUL, 128, nullptr,
      pA, 128, (double)CH * NNODES);

  // ---- opening: edge double layer (MFMA) ----
  etrans_k<<<NEDGES / 64, 256, 0, stream>>>(xe_in, xeT64, NEDGES);
  emfma_k<0, 64><<<NEDGES / 64, 256, 0, stream>>>(K1Eb, xeT64, eAT,
      pA, BNUL, NUL, NULI, NULI, DNUL, 0, 0.0);
  emfma_k<3, 128><<<NEDGES / 64, 256, 0, stream>>>(K2Eb, eAT, xeT,
      nullptr, BNUL, NUL, NULI, NULI, pA, 1024, (double)CH * NEDGES);

  for (int i = 0; i < 4; ++i) {
    const __bf16* KE1bi = KE1b + (size_t)i * 128 * 128;
    const __bf16* KE2bi = KE2b + (size_t)i * 128 * 128;
    const __bf16* KN1bi = KN1b + (size_t)i * 128 * 384;
    const __bf16* KN2bi = KN2b + (size_t)i * 128 * 128;
    const __bf16* a1a2i = a1a2b + (size_t)i * 256 * 128;

    // D statistics -> factor = -2/std ; edge weights
    bcvt_k<<<NNODES / 64, 256, 0, stream>>>(xnN, xnNb, sbuf);
    dstat_k<<<dim3(64, 64), 256, 0, stream>>>(xnNb, sbuf, pA);
    edge_w_k<<<NEDGES / 256, 256, 0, stream>>>(xnNb, sbuf, iI, jJ, pA, wbuf);

    // UVb[n][256] = xnNb @ a1a2^T (bf16 out)
    nmfma_k<128, false, false, false, 0><<<dim3(64, 4), 256, 0, stream>>>(
        a1a2i, xnNb, BNUL, UVb, nullptr, nullptr, NUL, 256, nullptr, DNUL, 0, 0.0);
    // edge pass 1: eA = xe @ KE1^T + w*(U_I + V_J), stats -> pB
    emfma_k<2, 128><<<NEDGES / 64, 256, 0, stream>>>(KE1bi, xeT, eAT,
        pB, UVb, wbuf, iI, jJ, DNUL, 0, 0.0);
    // edge pass 2: eB = tanh(ln(eA)) @ KE2^T, params<-pB, stats -> pA
    emfma_k<1, 128><<<NEDGES / 64, 256, 0, stream>>>(KE2bi, eAT, eBT,
        pA, BNUL, NUL, NULI, NULI, pB, 1024, (double)CH * NEDGES);
    // xe += 0.1 * ln(eB), params<-pA (bf16 RMW)
    lnres_k<<<1024, 256, 0, stream>>>(eBT, xeT, pA);

    // node update: gather -> catb; KN1 (split cat+xn) stats -> pB; KN2 tanh + resid
    gather_k<<<NNODES / 4, 256, 0, stream>>>(xeT, wbuf, csr_offs, csr_list, catb);
    nmfma_k<384, true, false, true, 0><<<dim3(64, 2), 256, 0, stream>>>(
        KN1bi, catb, xnNb, nAb, nullptr, nullptr, NUL, 128, pB, DNUL, 0, 0.0);
    nmfma_k<128, false, true, false, 4><<<dim3(64, 2), 256, 0, stream>>>(
        KN2bi, nAb, BNUL, nullptr, nullptr, xnN, NUL, 128, nullptr,
        pB, 128, (double)CH * NNODES);
  }

  // ---- close + MLP head (bf16 MFMA, node-major) ----
  bcvt_k<<<NNODES / 64, 256, 0, stream>>>(xnN, xnNb, sbuf);
  nmfma_k<128, false, false, false, 0><<<dim3(64, 2), 256, 0, stream>>>(
      KNcb, xnNb, BNUL, zb, nullptr, nullptr, NUL, 128, nullptr, DNUL, 0, 0.0);
  nmfma_k<128, false, false, false, 1><<<dim3(64, 4), 256, 0, stream>>>(
      W1b, zb, BNUL, l1bb, nullptr, nullptr, b1, 256, nullptr, DNUL, 0, 0.0);
  nmfma_k<256, false, false, false, 2><<<dim3(64, 16), 256, 0, stream>>>(
      W2b, l1bb, BNUL, nullptr, out, nullptr, b2, 1024, nullptr, DNUL, 0, 0.0);
  logsoftmax_k<<<NNODES, 256, 0, stream>>>(out);
}

// Round 7
// 698.232 us; speedup vs baseline: 3.6625x; 1.2344x over previous
//
#include <hip/hip_runtime.h>

#define NNODES 4096
#define NEDGES 65536
#define CH 128

typedef __bf16 bf16x8_t __attribute__((ext_vector_type(8)));
typedef __bf16 bf16x4_t __attribute__((ext_vector_type(4)));
typedef __bf16 bf16x2_t __attribute__((ext_vector_type(2)));
typedef float f32x4_t __attribute__((ext_vector_type(4)));

// ---- fast tanh: (e^{2x}-1)/(e^{2x}+1) via hw exp2/rcp; inf-safe, NaN-propagating ----
__device__ __forceinline__ float fast_tanh(float x)
{
  float t = __builtin_amdgcn_exp2f(x * 2.885390081777927f);   // 2*log2(e)
  return 1.f - 2.f * __builtin_amdgcn_rcpf(t + 1.f);
}

// ---- block stats writer: f32 wave shfl-reduce, one float2 per block ----
__device__ __forceinline__ void write_stats(float s, float q, float2* __restrict__ partials,
                                            int pid, int tid, int nwaves)
{
#pragma unroll
  for (int d = 1; d < 64; d <<= 1) { s += __shfl_xor(s, d); q += __shfl_xor(q, d); }
  __shared__ float rs[8][2];
  const int wv = tid >> 6, lane = tid & 63;
  if (lane == 0) { rs[wv][0] = s; rs[wv][1] = q; }
  __syncthreads();
  if (tid == 0) {
    float S = 0.f, Q = 0.f;
    for (int i = 0; i < nwaves; ++i) { S += rs[i][0]; Q += rs[i][1]; }
    partials[pid] = {S, Q};
  }
}

// ---- inline params: f64 cross-block reduce of f32 partials -> (mean,rstd) or (factor,0) ----
__device__ __forceinline__ float2 params_inline(const float2* __restrict__ pp,
                                                int nblk, double M, int type)
{
  const int tid = threadIdx.x;
  double s = 0.0, q = 0.0;
  for (int i = tid; i < nblk; i += 256) { float2 v = pp[i]; s += (double)v.x; q += (double)v.y; }
#pragma unroll
  for (int d = 1; d < 64; d <<= 1) { s += __shfl_xor(s, d); q += __shfl_xor(q, d); }
  __shared__ double rs4[4], rq4[4];
  __shared__ float pr[2];
  const int wv = tid >> 6, lane = tid & 63;
  if (lane == 0) { rs4[wv] = s; rq4[wv] = q; }
  __syncthreads();
  if (tid == 0) {
    double S = rs4[0] + rs4[1] + rs4[2] + rs4[3];
    double Q = rq4[0] + rq4[1] + rq4[2] + rq4[3];
    if (type == 0) {
      double mean = S / M;
      double var = Q / M - mean * mean;
      if (var < 0.0) var = 0.0;
      pr[0] = (float)mean;
      pr[1] = (float)(1.0 / sqrt(var + 1e-5));
    } else {
      double var = (Q - S * S / M) / (M - 1.0);
      if (var < 1e-30) var = 1e-30;
      pr[0] = (float)(-2.0 / sqrt(var));
      pr[1] = 0.f;
    }
  }
  __syncthreads();
  return {pr[0], pr[1]};
}

// ================= bf16 MFMA edge GEMM (ob-split): C[E][128] = X[E][K] @ A[128][K]^T =================
// grid (E/64, 2): blockIdx.y picks output half (4 ob tiles of 16).
// EM 0: plain, stats     EM 2: + w*(U[I]+V[J]), stats     EM 1: tanh-on-load, stats
// EM 3: tanh-on-load, no stats
template<int EM, int K>
__global__ __launch_bounds__(256) void emfma_k(
    const __bf16* __restrict__ A, const __bf16* __restrict__ X,
    __bf16* __restrict__ Cb,
    float2* __restrict__ partials,
    const __bf16* __restrict__ UVb, const float* __restrict__ wg,
    const int* __restrict__ iIe, const int* __restrict__ jIe,
    const float2* __restrict__ pp, int pnblk, double pM)
{
  float p0 = 0.f, p1 = 0.f;
  if constexpr (EM == 1 || EM == 3) {
    float2 pr = params_inline(pp, pnblk, pM, 0); p0 = pr.x; p1 = pr.y;
  }
  const int tid = threadIdx.x;
  const int wv = tid >> 6, lane = tid & 63;
  const int l15 = lane & 15, ks = lane >> 4;
  const int e = blockIdx.x * 64 + wv * 16 + l15;
  constexpr int KK = K / 32;
  bf16x8_t bq[KK];
  {
    const __bf16* xr = X + (size_t)e * K + ks * 8;
#pragma unroll
    for (int kk = 0; kk < KK; ++kk) {
      bf16x8_t v = *(const bf16x8_t*)(xr + kk * 32);
      if constexpr (EM == 1 || EM == 3) {
#pragma unroll
        for (int j = 0; j < 8; ++j) v[j] = (__bf16)fast_tanh(((float)v[j] - p0) * p1);
      }
      bq[kk] = v;
    }
  }
  float we = 0.f; int ie = 0, je = 0;
  if constexpr (EM == 2) { we = wg[e]; ie = iIe[e]; je = jIe[e]; }
  float dsum = 0.f, dsq = 0.f;
  const int ob0 = blockIdx.y * 4;
#pragma unroll
  for (int obb = 0; obb < 4; ++obb) {
    const int ob = ob0 + obb;
    f32x4_t acc = {0.f, 0.f, 0.f, 0.f};
    const __bf16* ar = A + (size_t)(ob * 16 + l15) * K + ks * 8;
#pragma unroll
    for (int kk = 0; kk < KK; ++kk) {
      bf16x8_t a = *(const bf16x8_t*)(ar + kk * 32);
      acc = __builtin_amdgcn_mfma_f32_16x16x32_bf16(a, bq[kk], acc, 0, 0, 0);
    }
    const int ro = ob * 16 + ks * 4;
    float v0 = acc[0], v1 = acc[1], v2 = acc[2], v3 = acc[3];
    if constexpr (EM == 2) {
      bf16x4_t u4 = *(const bf16x4_t*)&UVb[(size_t)ie * 256 + ro];
      bf16x4_t w4 = *(const bf16x4_t*)&UVb[(size_t)je * 256 + 128 + ro];
      v0 += we * ((float)u4[0] + (float)w4[0]);
      v1 += we * ((float)u4[1] + (float)w4[1]);
      v2 += we * ((float)u4[2] + (float)w4[2]);
      v3 += we * ((float)u4[3] + (float)w4[3]);
    }
    if constexpr (EM != 3) {
      dsum += v0 + v1 + v2 + v3;
      dsq  += v0 * v0 + v1 * v1 + v2 * v2 + v3 * v3;
    }
    bf16x4_t bv;
    bv[0] = (__bf16)v0; bv[1] = (__bf16)v1; bv[2] = (__bf16)v2; bv[3] = (__bf16)v3;
    *(bf16x4_t*)(Cb + (size_t)e * 128 + ro) = bv;
  }
  if constexpr (EM != 3)
    write_stats(dsum, dsq, partials, blockIdx.y * gridDim.x + blockIdx.x, tid, 4);
}

// ================= bf16 MFMA node GEMM, col-tiled =================
// OM 0: bf16 out; 1: +bias elu bf16 out; 2: +bias f32 out; 3: f32 out; 4: resid[n][128] += 0.1*v
// XSPLIT: K 0..255 from X (stride 256), rest from X2 (stride 128)
// XT: fast_tanh((x-m)*r) on X load; STATS: write float2 partials
template<int K, bool XSPLIT, bool XT, bool STATS, int OM>
__global__ __launch_bounds__(256) void nmfma_k(
    const __bf16* __restrict__ A, const __bf16* __restrict__ X,
    const __bf16* __restrict__ X2,
    __bf16* __restrict__ Cb, float* __restrict__ Cf, float* __restrict__ resid,
    const float* __restrict__ bias, int nout_stride,
    float2* __restrict__ partials,
    const float2* __restrict__ pp, int pnblk, double pM)
{
  float p0 = 0.f, p1 = 0.f;
  if constexpr (XT) { float2 pr = params_inline(pp, pnblk, pM, 0); p0 = pr.x; p1 = pr.y; }
  const int tid = threadIdx.x;
  const int wv = tid >> 6, lane = tid & 63;
  const int l15 = lane & 15, ks = lane >> 4;
  const int n = blockIdx.x * 64 + wv * 16 + l15;
  constexpr int KK = K / 32;
  bf16x8_t bq[KK];
  if constexpr (XSPLIT) {
    const __bf16* xr  = X  + (size_t)n * 256 + ks * 8;
    const __bf16* xr2 = X2 + (size_t)n * 128 + ks * 8;
#pragma unroll
    for (int kk = 0; kk < 8; ++kk) bq[kk] = *(const bf16x8_t*)(xr + kk * 32);
#pragma unroll
    for (int kk = 8; kk < KK; ++kk) bq[kk] = *(const bf16x8_t*)(xr2 + (kk - 8) * 32);
  } else {
    const __bf16* xr = X + (size_t)n * K + ks * 8;
#pragma unroll
    for (int kk = 0; kk < KK; ++kk) {
      bf16x8_t v = *(const bf16x8_t*)(xr + kk * 32);
      if constexpr (XT) {
#pragma unroll
        for (int j = 0; j < 8; ++j) v[j] = (__bf16)fast_tanh(((float)v[j] - p0) * p1);
      }
      bq[kk] = v;
    }
  }
  float dsum = 0.f, dsq = 0.f;
  const int ob0 = blockIdx.y * 4;
#pragma unroll
  for (int obb = 0; obb < 4; ++obb) {
    const int ob = ob0 + obb;
    f32x4_t acc = {0.f, 0.f, 0.f, 0.f};
    const __bf16* ar = A + (size_t)(ob * 16 + l15) * K + ks * 8;
#pragma unroll
    for (int kk = 0; kk < KK; ++kk) {
      bf16x8_t a = *(const bf16x8_t*)(ar + kk * 32);
      acc = __builtin_amdgcn_mfma_f32_16x16x32_bf16(a, bq[kk], acc, 0, 0, 0);
    }
    const int ro = ob * 16 + ks * 4;
    float v[4] = {acc[0], acc[1], acc[2], acc[3]};
    if constexpr (OM == 1 || OM == 2) {
#pragma unroll
      for (int r = 0; r < 4; ++r) v[r] += bias[ro + r];
    }
    if constexpr (OM == 1) {
#pragma unroll
      for (int r = 0; r < 4; ++r) v[r] = v[r] > 0.f ? v[r] : expm1f(v[r]);
    }
    if constexpr (STATS) {
#pragma unroll
      for (int r = 0; r < 4; ++r) { dsum += v[r]; dsq += v[r] * v[r]; }
    }
    if constexpr (OM == 4) {
      float4* rp = (float4*)&resid[(size_t)n * 128 + ro];
      float4 rr = *rp;
      rr.x += 0.1f * v[0]; rr.y += 0.1f * v[1]; rr.z += 0.1f * v[2]; rr.w += 0.1f * v[3];
      *rp = rr;
    } else if constexpr (OM == 2 || OM == 3) {
      float4 fv = {v[0], v[1], v[2], v[3]};
      *(float4*)(Cf + (size_t)n * nout_stride + ro) = fv;
    } else {
      bf16x4_t bv;
      bv[0] = (__bf16)v[0]; bv[1] = (__bf16)v[1]; bv[2] = (__bf16)v[2]; bv[3] = (__bf16)v[3];
      *(bf16x4_t*)(Cb + (size_t)n * nout_stride + ro) = bv;
    }
  }
  if constexpr (STATS)
    write_stats(dsum, dsq, partials, blockIdx.y * gridDim.x + blockIdx.x, tid, 4);
}

// ================= dstat via MFMA Gram matrix, triangular 1-D grid (2080 blocks) =================
__global__ __launch_bounds__(256) void dstat_k(
    const __bf16* __restrict__ fT, const float* __restrict__ s,
    float2* __restrict__ partials)
{
  int rem = blockIdx.x, i0t = 0;
  while (rem >= 64 - i0t) { rem -= 64 - i0t; ++i0t; }
  const int i0 = i0t * 64, j0 = (i0t + rem) * 64;
  const float wgt = (j0 > i0) ? 2.f : 1.f;
  const int tid = threadIdx.x;
  const int wv = tid >> 6, lane = tid & 63, l15 = lane & 15, ks = lane >> 4;
  const int irow = i0 + wv * 16 + l15;
  bf16x8_t aq[4];
  const __bf16* ar = fT + (size_t)irow * 128 + ks * 8;
#pragma unroll
  for (int kk = 0; kk < 4; ++kk) aq[kk] = *(const bf16x8_t*)(ar + kk * 32);
  float si[4];
#pragma unroll
  for (int r = 0; r < 4; ++r) si[r] = s[i0 + wv * 16 + ks * 4 + r];
  float dsum = 0.f, dsq = 0.f;
#pragma unroll
  for (int jb = 0; jb < 4; ++jb) {
    const int jcol = j0 + jb * 16 + l15;
    const __bf16* br = fT + (size_t)jcol * 128 + ks * 8;
    f32x4_t acc = {0.f, 0.f, 0.f, 0.f};
#pragma unroll
    for (int kk = 0; kk < 4; ++kk) {
      bf16x8_t b = *(const bf16x8_t*)(br + kk * 32);
      acc = __builtin_amdgcn_mfma_f32_16x16x32_bf16(aq[kk], b, acc, 0, 0, 0);
    }
    const float sj = s[jcol];
#pragma unroll
    for (int r = 0; r < 4; ++r) {
      float d = si[r] + sj - 2.f * acc[r];
      d = d > 0.f ? d : 0.f;
      dsum += d; dsq += d * d;
    }
  }
  write_stats(dsum * wgt, dsq * wgt, partials, blockIdx.x, tid, 4);
}

// ================= bcvt: xnN f32 [n][128] -> bf16 + per-node sqnorm (of bf16 values) =================
__global__ __launch_bounds__(256) void bcvt_k(const float* __restrict__ xnN,
                                              __bf16* __restrict__ xnNb,
                                              float* __restrict__ sbuf)
{
  const int n = blockIdx.x * 64 + (threadIdx.x >> 2);
  const int q = (threadIdx.x & 3) * 32;
  const float* src = xnN + (size_t)n * 128 + q;
  __bf16* dst = xnNb + (size_t)n * 128 + q;
  float ss = 0.f;
#pragma unroll
  for (int j = 0; j < 8; ++j) {
    float4 v = *(const float4*)(src + 4 * j);
    bf16x4_t b;
    b[0] = (__bf16)v.x; b[1] = (__bf16)v.y; b[2] = (__bf16)v.z; b[3] = (__bf16)v.w;
    float f0 = (float)b[0], f1 = (float)b[1], f2 = (float)b[2], f3 = (float)b[3];
    ss += f0 * f0 + f1 * f1 + f2 * f2 + f3 * f3;
    *(bf16x4_t*)(dst + 4 * j) = b;
  }
  ss += __shfl_xor(ss, 1);
  ss += __shfl_xor(ss, 2);
  if ((threadIdx.x & 3) == 0) sbuf[n] = ss;
}

// ================= transpose src [64][ncols] f32 -> dst [ncols][64] bf16 =================
__global__ __launch_bounds__(256) void etrans_k(const float* __restrict__ src,
                                                __bf16* __restrict__ dst, int ncols)
{
  __shared__ float t[64][65];
  const int e0 = blockIdx.x * 64;
  const int tx = threadIdx.x & 63, tw = threadIdx.x >> 6;
  for (int c = tw; c < 64; c += 4)
    t[tx][c] = src[(size_t)c * ncols + e0 + tx];
  __syncthreads();
  const int el = threadIdx.x >> 2, c0 = (threadIdx.x & 3) * 16;
  for (int q = 0; q < 4; ++q) {
    int c = c0 + q * 4;
    bf16x4_t b;
    b[0] = (__bf16)t[el][c];     b[1] = (__bf16)t[el][c + 1];
    b[2] = (__bf16)t[el][c + 2]; b[3] = (__bf16)t[el][c + 3];
    *(bf16x4_t*)&dst[(size_t)(e0 + el) * 64 + c] = b;
  }
}

// ================= per-edge weight from node-major xnNb bf16 =================
__global__ __launch_bounds__(256) void edge_w_k(
    const __bf16* __restrict__ xnNb, const float* __restrict__ s,
    const int* __restrict__ iI, const int* __restrict__ jJ,
    const float2* __restrict__ pp, float* __restrict__ w)
{
  float2 pr = params_inline(pp, 2080, (double)NNODES * (double)NNODES, 1);
  const float factor = pr.x;
  int e = blockIdx.x * 256 + threadIdx.x;
  int a = iI[e], b = jJ[e];
  const bf16x8_t* pa = (const bf16x8_t*)(xnNb + (size_t)a * CH);
  const bf16x8_t* pb = (const bf16x8_t*)(xnNb + (size_t)b * CH);
  float g = 0.f;
#pragma unroll
  for (int q = 0; q < CH / 8; ++q) {
    bf16x8_t u = pa[q], v = pb[q];
#pragma unroll
    for (int j = 0; j < 8; ++j) g = fmaf((float)u[j], (float)v[j], g);
  }
  float d = s[a] + s[b] - 2.f * g;
  d = d > 0.f ? d : 0.f;
  w[e] = __builtin_amdgcn_exp2f(factor * d * 1.4426950408889634f);
}

// ================= weight conversion to bf16 (one launch) =================
__global__ void wcvt_k(const float* __restrict__ K1E, const float* __restrict__ K2E,
                       const float* __restrict__ KE1, const float* __restrict__ KE2,
                       const float* __restrict__ KNc, const float* __restrict__ W1,
                       const float* __restrict__ W2, const float* __restrict__ KN1,
                       const float* __restrict__ KN2, const float* __restrict__ K1N,
                       const float* __restrict__ K2N,
                       __bf16* __restrict__ K1Eb, __bf16* __restrict__ K2Eb,
                       __bf16* __restrict__ KE1b, __bf16* __restrict__ KE2b,
                       __bf16* __restrict__ KNcb, __bf16* __restrict__ W1b,
                       __bf16* __restrict__ W2b, __bf16* __restrict__ KN1b,
                       __bf16* __restrict__ KN2b, __bf16* __restrict__ a1a2b,
                       __bf16* __restrict__ K1Nb, __bf16* __restrict__ K2Nb)
{
  int id = blockIdx.x * 256 + threadIdx.x;
  if (id < 8192) { K1Eb[id] = (__bf16)K1E[id]; return; }
  id -= 8192;
  if (id < 16384) { K2Eb[id] = (__bf16)K2E[id]; return; }
  id -= 16384;
  if (id < 65536) {
    int l = id >> 14, rem = id & 16383, r = rem >> 7, c = rem & 127;
    KE1b[id] = (__bf16)KE1[(size_t)l * 49152 + r * 384 + 128 + c];
    return;
  }
  id -= 65536;
  if (id < 65536) { KE2b[id] = (__bf16)KE2[id]; return; }
  id -= 65536;
  if (id < 16384) { KNcb[id] = (__bf16)KNc[id]; return; }
  id -= 16384;
  if (id < 32768) { W1b[id] = (__bf16)W1[id]; return; }
  id -= 32768;
  if (id < 262144) { W2b[id] = (__bf16)W2[id]; return; }
  id -= 262144;
  if (id < 196608) { KN1b[id] = (__bf16)KN1[id]; return; }
  id -= 196608;
  if (id < 65536) { KN2b[id] = (__bf16)KN2[id]; return; }
  id -= 65536;
  if (id < 131072) {
    int l = id >> 15, rem = id & 32767, r = rem >> 7, c = rem & 127;
    int o = r & 127;
    float k1 = KE1[(size_t)l * 49152 + o * 384 + c];
    float k3 = KE1[(size_t)l * 49152 + o * 384 + 256 + c];
    a1a2b[id] = (__bf16)((r < 128) ? (0.5f * k1 + k3) : (0.5f * k1 - k3));
    return;
  }
  id -= 131072;
  if (id < 8192) { K1Nb[id] = (__bf16)K1N[id]; return; }
  id -= 8192;
  if (id < 16384) { K2Nb[id] = (__bf16)K2N[id]; return; }
}

// ================= lnres: xeT = bf16(f32(xeT) + 0.1*ln(eB)) =================
__global__ __launch_bounds__(256) void lnres_k(
    const __bf16* __restrict__ eBT, __bf16* __restrict__ xeT,
    const float2* __restrict__ pp)
{
  float2 pr = params_inline(pp, 2048, (double)CH * NEDGES, 0);
  const float m = pr.x, r = pr.y;
  const size_t base = (size_t)blockIdx.x * (256 * 16);
  for (int it = 0; it < 2; ++it) {
    size_t i = base + (size_t)it * 2048 + (size_t)threadIdx.x * 8;
    bf16x8_t b = *(const bf16x8_t*)(eBT + i);
    bf16x8_t x = *(const bf16x8_t*)(xeT + i);
    bf16x8_t ob;
#pragma unroll
    for (int j = 0; j < 8; ++j)
      ob[j] = (__bf16)((float)x[j] + 0.1f * (((float)b[j] - m) * r));
    *(bf16x8_t*)(xeT + i) = ob;
  }
}

// ================= CSR build =================
__global__ void hist_k(const int* __restrict__ iI, const int* __restrict__ jJ,
                       int* __restrict__ cnt)
{
  int e = blockIdx.x * 256 + threadIdx.x;
  atomicAdd(&cnt[iI[e]], 1);
  atomicAdd(&cnt[jJ[e]], 1);
}

__global__ __launch_bounds__(1024) void scan_k(const int* __restrict__ cnt,
                                               int* __restrict__ offs,
                                               int* __restrict__ cursor)
{
  __shared__ int tmp[1024];
  const int tid = threadIdx.x;
  int4 v = *(const int4*)&cnt[tid * 4];
  int s = v.x + v.y + v.z + v.w;
  tmp[tid] = s; __syncthreads();
  for (int d = 1; d < 1024; d <<= 1) {
    int t = (tid >= d) ? tmp[tid - d] : 0;
    __syncthreads();
    tmp[tid] += t;
    __syncthreads();
  }
  int base = tmp[tid] - s;
  int4 o = {base, base + v.x, base + v.x + v.y, base + v.x + v.y + v.z};
  *(int4*)&offs[tid * 4] = o;
  *(int4*)&cursor[tid * 4] = o;
  if (tid == 1023) offs[4096] = tmp[1023];
}

__global__ void fill_k(const int* __restrict__ iI, const int* __restrict__ jJ,
                       int* __restrict__ cursor, int* __restrict__ list)
{
  int e = blockIdx.x * 256 + threadIdx.x;
  int p1 = atomicAdd(&cursor[iI[e]], 1);
  list[p1] = e;
  int p2 = atomicAdd(&cursor[jJ[e]], 1);
  list[p2] = e | 0x80000000;
}

// ================= gather: 8 waves, 2 per node (incidence-split) -> catb bf16 [n][256] =================
__global__ __launch_bounds__(512) void gather_k(
    const __bf16* __restrict__ xeT, const float* __restrict__ w,
    const int* __restrict__ offs, const int* __restrict__ list,
    __bf16* __restrict__ catb)
{
  __shared__ float comb[4][4][64];
  const int wv = threadIdx.x >> 6, lane = threadIdx.x & 63;
  const int nn = wv >> 1, half = wv & 1;
  const int n = blockIdx.x * 4 + nn;
  const int k0 = offs[n], k1 = offs[n + 1];
  float s1a = 0.f, s1b = 0.f, s2a = 0.f, s2b = 0.f;
#pragma unroll 2
  for (int k = k0 + half; k < k1; k += 2) {
    int enc = list[k];
    int e = enc & 0x7fffffff;
    float we = w[e];
    bf16x2_t xv = *(const bf16x2_t*)&xeT[(size_t)e * 128 + lane * 2];
    float va = (float)xv[0] * we;
    float vb = (float)xv[1] * we;
    if (enc >= 0) { s1a += va; s1b += vb; }
    else          { s2a += va; s2b += vb; }
  }
  if (half == 1) {
    comb[nn][0][lane] = s1a; comb[nn][1][lane] = s1b;
    comb[nn][2][lane] = s2a; comb[nn][3][lane] = s2b;
  }
  __syncthreads();
  if (half == 0) {
    s1a += comb[nn][0][lane]; s1b += comb[nn][1][lane];
    s2a += comb[nn][2][lane]; s2b += comb[nn][3][lane];
    __bf16* row = catb + (size_t)n * 256;
    bf16x2_t av, dv;
    av[0] = (__bf16)(0.5f * (s1a + s2a)); av[1] = (__bf16)(0.5f * (s1b + s2b));
    dv[0] = (__bf16)(s1a - s2a);          dv[1] = (__bf16)(s1b - s2b);
    *(bf16x2_t*)&row[lane * 2] = av;
    *(bf16x2_t*)&row[128 + lane * 2] = dv;
  }
}

// ================= log_softmax rows of [N][1024] =================
__global__ __launch_bounds__(256) void logsoftmax_k(float* __restrict__ out)
{
  __shared__ float red[256];
  const int n = blockIdx.x, tid = threadIdx.x;
  float* row = out + (size_t)n * 1024;
  float v[4];
  float mx = -1e30f;
#pragma unroll
  for (int l = 0; l < 4; ++l) { v[l] = row[tid + 256 * l]; mx = fmaxf(mx, v[l]); }
  red[tid] = mx; __syncthreads();
  for (int s = 128; s > 0; s >>= 1) { if (tid < s) red[tid] = fmaxf(red[tid], red[tid + s]); __syncthreads(); }
  float m = red[0]; __syncthreads();
  float se = 0.f;
#pragma unroll
  for (int l = 0; l < 4; ++l) se += expf(v[l] - m);
  red[tid] = se; __syncthreads();
  for (int s = 128; s > 0; s >>= 1) { if (tid < s) red[tid] += red[tid + s]; __syncthreads(); }
  float L = m + logf(red[0]);
#pragma unroll
  for (int l = 0; l < 4; ++l) row[tid + 256 * l] = v[l] - L;
}

extern "C" void kernel_launch(void* const* d_in, const int* in_sizes, int n_in,
                              void* d_out, int out_size, void* d_ws, size_t ws_size,
                              hipStream_t stream)
{
  (void)in_sizes; (void)n_in; (void)out_size; (void)ws_size;
  const float* xn_in = (const float*)d_in[0];
  const float* xe_in = (const float*)d_in[1];
  const int*   iI    = (const int*)d_in[2];
  const int*   jJ    = (const int*)d_in[3];
  const float* K1N   = (const float*)d_in[4];
  const float* K2N   = (const float*)d_in[5];
  const float* K1E   = (const float*)d_in[6];
  const float* K2E   = (const float*)d_in[7];
  const float* KNc   = (const float*)d_in[8];
  const float* KE1   = (const float*)d_in[9];
  const float* KE2   = (const float*)d_in[10];
  const float* KN1   = (const float*)d_in[11];
  const float* KN2   = (const float*)d_in[12];
  const float* W1    = (const float*)d_in[13];
  const float* b1    = (const float*)d_in[14];
  const float* W2    = (const float*)d_in[15];
  const float* b2    = (const float*)d_in[16];
  float* out = (float*)d_out;

  float* ws = (float*)d_ws;
  size_t off = 0;
  auto alloc = [&](size_t n) { size_t o = off; off += (n + 63) & ~(size_t)63; return o; };
  float* xnN   = ws + alloc((size_t)NNODES * CH);                  // f32 node-major master
  __bf16* xeT  = (__bf16*)(ws + alloc((size_t)NEDGES * CH / 2));   // bf16 edge state
  __bf16* eAT  = (__bf16*)(ws + alloc((size_t)NEDGES * CH / 2));
  __bf16* eBT  = (__bf16*)(ws + alloc((size_t)NEDGES * CH / 2));
  float* sbuf  = ws + alloc(NNODES);
  float* wbuf  = ws + alloc(NEDGES);
  __bf16* UVb  = (__bf16*)(ws + alloc((size_t)NNODES * 256 / 2));
  __bf16* xnNb = (__bf16*)(ws + alloc((size_t)NNODES * CH / 2));
  __bf16* catb = (__bf16*)(ws + alloc((size_t)NNODES * 256 / 2));
  __bf16* nAb  = (__bf16*)(ws + alloc((size_t)NNODES * CH / 2));
  __bf16* zb   = (__bf16*)(ws + alloc((size_t)NNODES * CH / 2));
  __bf16* l1bb = (__bf16*)(ws + alloc((size_t)NNODES * 256 / 2));
  __bf16* K1Eb = (__bf16*)(ws + alloc(8192 / 2));
  __bf16* K2Eb = (__bf16*)(ws + alloc(16384 / 2));
  __bf16* KE1b = (__bf16*)(ws + alloc(65536 / 2));
  __bf16* KE2b = (__bf16*)(ws + alloc(65536 / 2));
  __bf16* KNcb = (__bf16*)(ws + alloc(16384 / 2));
  __bf16* W1b  = (__bf16*)(ws + alloc(32768 / 2));
  __bf16* W2b  = (__bf16*)(ws + alloc(262144 / 2));
  __bf16* KN1b = (__bf16*)(ws + alloc(196608 / 2));
  __bf16* KN2b = (__bf16*)(ws + alloc(65536 / 2));
  __bf16* a1a2b= (__bf16*)(ws + alloc(131072 / 2));
  __bf16* K1Nb = (__bf16*)(ws + alloc(8192 / 2));
  __bf16* K2Nb = (__bf16*)(ws + alloc(16384 / 2));
  int* csr_cnt    = (int*)(ws + alloc(4096));
  int* csr_offs   = (int*)(ws + alloc(4160));
  int* csr_cursor = (int*)(ws + alloc(4096));
  int* csr_list   = (int*)(ws + alloc(2 * NEDGES));
  float2* pA = (float2*)(ws + alloc((size_t)4096 * 2));
  float2* pB = (float2*)(ws + alloc((size_t)4096 * 2));
  // aliases (lifetimes disjoint): opening-only transposed inputs
  __bf16* xeT64  = eBT;               // [E][64], eBT first written layer-0 emfma<1>
  __bf16* xnT64b = UVb;               // [N][64], UVb first written layer-0 UV kernel

  const __bf16* BNUL = nullptr;
  const float* NUL = nullptr;
  const int* NULI = nullptr;
  const float2* PNUL = nullptr;

  // ---- weight conversion + CSR build (once) ----
  wcvt_k<<<3456, 256, 0, stream>>>(K1E, K2E, KE1, KE2, KNc, W1, W2, KN1, KN2, K1N, K2N,
                                   K1Eb, K2Eb, KE1b, KE2b, KNcb, W1b, W2b, KN1b, KN2b,
                                   a1a2b, K1Nb, K2Nb);
  hipMemsetAsync(csr_cnt, 0, 4096 * sizeof(int), stream);
  hist_k<<<NEDGES / 256, 256, 0, stream>>>(iI, jJ, csr_cnt);
  scan_k<<<1, 1024, 0, stream>>>(csr_cnt, csr_offs, csr_cursor);
  fill_k<<<NEDGES / 256, 256, 0, stream>>>(iI, jJ, csr_cursor, csr_list);

  // ---- opening: node double layer (MFMA, node-major) ----
  etrans_k<<<NNODES / 64, 256, 0, stream>>>(xn_in, xnT64b, NNODES);
  nmfma_k<64, false, false, true, 0><<<dim3(64, 2), 256, 0, stream>>>(
      K1Nb, xnT64b, BNUL, nAb, nullptr, nullptr, NUL, 128, pA, PNUL, 0, 0.0);
  nmfma_k<128, false, true, false, 3><<<dim3(64, 2), 256, 0, stream>>>(
      K2Nb, nAb, BNUL, nullptr, xnN, nullptr, NUL, 128, nullptr,
      pA, 128, (double)CH * NNODES);

  // ---- opening: edge double layer (MFMA, ob-split) ----
  etrans_k<<<NEDGES / 64, 256, 0, stream>>>(xe_in, xeT64, NEDGES);
  emfma_k<0, 64><<<dim3(NEDGES / 64, 2), 256, 0, stream>>>(K1Eb, xeT64, eAT,
      pA, BNUL, NUL, NULI, NULI, PNUL, 0, 0.0);
  emfma_k<3, 128><<<dim3(NEDGES / 64, 2), 256, 0, stream>>>(K2Eb, eAT, xeT,
      nullptr, BNUL, NUL, NULI, NULI, pA, 2048, (double)CH * NEDGES);

  for (int i = 0; i < 4; ++i) {
    const __bf16* KE1bi = KE1b + (size_t)i * 128 * 128;
    const __bf16* KE2bi = KE2b + (size_t)i * 128 * 128;
    const __bf16* KN1bi = KN1b + (size_t)i * 128 * 384;
    const __bf16* KN2bi = KN2b + (size_t)i * 128 * 128;
    const __bf16* a1a2i = a1a2b + (size_t)i * 256 * 128;

    // D statistics -> factor = -2/std ; edge weights
    bcvt_k<<<NNODES / 64, 256, 0, stream>>>(xnN, xnNb, sbuf);
    dstat_k<<<2080, 256, 0, stream>>>(xnNb, sbuf, pA);
    edge_w_k<<<NEDGES / 256, 256, 0, stream>>>(xnNb, sbuf, iI, jJ, pA, wbuf);

    // UVb[n][256] = xnNb @ a1a2^T (bf16 out)
    nmfma_k<128, false, false, false, 0><<<dim3(64, 4), 256, 0, stream>>>(
        a1a2i, xnNb, BNUL, UVb, nullptr, nullptr, NUL, 256, nullptr, PNUL, 0, 0.0);
    // edge pass 1: eA = xe @ KE1^T + w*(U_I + V_J), stats -> pB
    emfma_k<2, 128><<<dim3(NEDGES / 64, 2), 256, 0, stream>>>(KE1bi, xeT, eAT,
        pB, UVb, wbuf, iI, jJ, PNUL, 0, 0.0);
    // edge pass 2: eB = tanh(ln(eA)) @ KE2^T, params<-pB, stats -> pA
    emfma_k<1, 128><<<dim3(NEDGES / 64, 2), 256, 0, stream>>>(KE2bi, eAT, eBT,
        pA, BNUL, NUL, NULI, NULI, pB, 2048, (double)CH * NEDGES);
    // xe += 0.1 * ln(eB), params<-pA (bf16 RMW)
    lnres_k<<<2048, 256, 0, stream>>>(eBT, xeT, pA);

    // node update: gather -> catb; KN1 (split cat+xn) stats -> pB; KN2 tanh + resid
    gather_k<<<NNODES / 4, 512, 0, stream>>>(xeT, wbuf, csr_offs, csr_list, catb);
    nmfma_k<384, true, false, true, 0><<<dim3(64, 2), 256, 0, stream>>>(
        KN1bi, catb, xnNb, nAb, nullptr, nullptr, NUL, 128, pB, PNUL, 0, 0.0);
    nmfma_k<128, false, true, false, 4><<<dim3(64, 2), 256, 0, stream>>>(
        KN2bi, nAb, BNUL, nullptr, nullptr, xnN, NUL, 128, nullptr,
        pB, 128, (double)CH * NNODES);
  }

  // ---- close + MLP head (bf16 MFMA, node-major) ----
  bcvt_k<<<NNODES / 64, 256, 0, stream>>>(xnN, xnNb, sbuf);
  nmfma_k<128, false, false, false, 0><<<dim3(64, 2), 256, 0, stream>>>(
      KNcb, xnNb, BNUL, zb, nullptr, nullptr, NUL, 128, nullptr, PNUL, 0, 0.0);
  nmfma_k<128, false, false, false, 1><<<dim3(64, 4), 256, 0, stream>>>(
      W1b, zb, BNUL, l1bb, nullptr, nullptr, b1, 256, nullptr, PNUL, 0, 0.0);
  nmfma_k<256, false, false, false, 2><<<dim3(64, 16), 256, 0, stream>>>(
      W2b, l1bb, BNUL, nullptr, out, nullptr, b2, 1024, nullptr, PNUL, 0, 0.0);
  logsoftmax_k<<<NNODES, 256, 0, stream>>>(out);
}